// Round 1
// baseline (1551.469 us; speedup 1.0000x reference)
//
#include <hip/hip_runtime.h>
#include <stdint.h>
#include <math.h>

#define NLVL 5
#define NIMG 4
#define M_TOT 4768
#define POST_K 1000
#define NEGV  (-1e9f)
#define SORT_N 8192
#define CAP 2048

__constant__ int c_hwa[NLVL]  = {196608, 49152, 12288, 3072, 768};
__constant__ int c_k[NLVL]    = {1000, 1000, 1000, 1000, 768};
__constant__ int c_base[NLVL] = {0, 1000, 2000, 3000, 4000};

struct Ptrs {
    const float* logits[NLVL];
    const float* deltas[NLVL];
    const float* anchors[NLVL];
};

// float -> sortable uint32 (ascending order preserved)
__device__ __forceinline__ uint32_t flipf(float f) {
    uint32_t b = __float_as_uint(f);
    return (b & 0x80000000u) ? ~b : (b | 0x80000000u);
}

// ---------------------------------------------------------------------------
// Kernel A: per (image, level) — exact top-k select (radix-select + rank) and
// box decode/clip/min-size filter. Writes cand_box[img][slot][4], cand_score.
// ---------------------------------------------------------------------------
__global__ void kTopkDecode(Ptrs p, float* __restrict__ cand_box,
                            float* __restrict__ cand_score) {
    #pragma clang fp contract(off)
    const int blk = blockIdx.x;
    const int img = blk / NLVL;
    const int lvl = blk % NLVL;
    const int n    = c_hwa[lvl];
    const int k    = c_k[lvl];
    const int base = c_base[lvl];
    const float* lg = p.logits[lvl] + (size_t)img * n;

    __shared__ uint32_t hist[256];
    __shared__ uint32_t sh_pre, sh_rem, sh_cnt;
    __shared__ uint32_t bk[CAP];
    __shared__ uint32_t bi[CAP];

    const int tid = threadIdx.x, bs = blockDim.x;
    if (tid == 0) { sh_pre = 0u; sh_rem = (uint32_t)k; }

    // ---- MSB-first radix select: find threshold key T (k-th largest) ----
    for (int pass = 0; pass < 4; ++pass) {
        for (int i = tid; i < 256; i += bs) hist[i] = 0u;
        __syncthreads();
        const int shift = 24 - 8 * pass;
        const uint32_t pre = sh_pre;
        for (int i = tid; i < n; i += bs) {
            uint32_t key = flipf(lg[i]);
            if (pass == 0 || (key >> (shift + 8)) == pre)
                atomicAdd(&hist[(key >> shift) & 255u], 1u);
        }
        __syncthreads();
        if (tid == 0) {
            uint32_t rem = sh_rem;
            int d = 255;
            for (; d > 0; --d) {
                uint32_t c = hist[d];
                if (rem <= c) break;
                rem -= c;
            }
            sh_rem = rem;
            sh_pre = (pre << 8) | (uint32_t)d;
        }
        __syncthreads();
    }
    const uint32_t T = sh_pre;  // full 32-bit threshold key

    // ---- compact all elements with key >= T into LDS ----
    if (tid == 0) sh_cnt = 0u;
    __syncthreads();
    for (int i = tid; i < n; i += bs) {
        uint32_t key = flipf(lg[i]);
        if (key >= T) {
            uint32_t pos = atomicAdd(&sh_cnt, 1u);
            if (pos < CAP) { bk[pos] = key; bi[pos] = (uint32_t)i; }
        }
    }
    __syncthreads();
    const int cc = (int)min(sh_cnt, (uint32_t)CAP);

    // ---- exact rank (value desc, index asc) among candidates; emit if <k ----
    for (int c = tid; c < cc; c += bs) {
        const uint32_t kc = bk[c];
        const uint32_t ic = bi[c];
        int r = 0;
        for (int j = 0; j < cc; ++j) {
            uint32_t kj = bk[j], ij = bi[j];
            r += (int)((kj > kc) || (kj == kc && ij < ic));
        }
        if (r < k) {
            const float* an = p.anchors[lvl] + (size_t)ic * 4;
            const float* dl = p.deltas[lvl] + ((size_t)img * n + ic) * 4;
            float a0 = an[0], a1 = an[1], a2 = an[2], a3 = an[3];
            float wa = a2 - a0, ha = a3 - a1;
            float cxa = a0 + 0.5f * wa, cya = a1 + 0.5f * ha;
            float dx = dl[0], dy = dl[1], dw = dl[2], dh = dl[3];
            const float SC = (float)4.135166556742356;  // log(1000/16)
            dw = fminf(dw, SC);
            dh = fminf(dh, SC);
            float cx = dx * wa + cxa, cy = dy * ha + cya;
            float w = wa * expf(dw), h = ha * expf(dh);
            float x1 = cx - 0.5f * w, y1 = cy - 0.5f * h;
            float x2 = cx + 0.5f * w, y2 = cy + 0.5f * h;
            x1 = fminf(fmaxf(x1, 0.0f), 1024.0f);
            y1 = fminf(fmaxf(y1, 0.0f), 1024.0f);
            x2 = fminf(fmaxf(x2, 0.0f), 1024.0f);
            y2 = fminf(fmaxf(y2, 0.0f), 1024.0f);
            float bw = x2 - x1, bh = y2 - y1;
            float score = (bw > 0.0f && bh > 0.0f) ? lg[ic] : NEGV;
            const int slot = base + r;
            float* ob = cand_box + ((size_t)img * M_TOT + slot) * 4;
            ob[0] = x1; ob[1] = y1; ob[2] = x2; ob[3] = y2;
            cand_score[(size_t)img * M_TOT + slot] = score;
        }
    }
}

// ---------------------------------------------------------------------------
// Kernel B1: per image — exact global sort by (score desc, slot asc).
// Bitonic sort of 8192 packed 64-bit keys in LDS. Writes sorted_slot.
// ---------------------------------------------------------------------------
__global__ void kSort(const float* __restrict__ cand_score,
                      uint32_t* __restrict__ sorted_slot) {
    const int img = blockIdx.x;
    __shared__ uint64_t keys[SORT_N];
    const int tid = threadIdx.x, bs = blockDim.x;

    for (int i = tid; i < SORT_N; i += bs) {
        uint64_t kk;
        if (i < M_TOT) {
            float s = cand_score[(size_t)img * M_TOT + i];
            kk = ((uint64_t)(~flipf(s)) << 32) | (uint32_t)i;
        } else {
            kk = ~0ULL;
        }
        keys[i] = kk;
    }
    __syncthreads();

    for (int size = 2; size <= SORT_N; size <<= 1) {
        for (int stride = size >> 1; stride > 0; stride >>= 1) {
            for (int i = tid; i < SORT_N; i += bs) {
                int j = i ^ stride;
                if (j > i) {
                    uint64_t a = keys[i], b = keys[j];
                    bool asc = ((i & size) == 0);
                    if ((a > b) == asc) { keys[i] = b; keys[j] = a; }
                }
            }
            __syncthreads();
        }
    }

    for (int i = tid; i < M_TOT; i += bs)
        sorted_slot[(size_t)img * M_TOT + i] = (uint32_t)(keys[i] & 0xFFFFFFFFu);
}

// ---------------------------------------------------------------------------
// Kernel B2: per (image, level) — greedy NMS in per-level rank order.
// Cross-level IoU is always 0 (lvl*2048 offset), so levels are independent,
// and within a level score-desc order == rank order (invalid rows skipped).
// Writes kept[img][slot] = valid && !suppressed.
// ---------------------------------------------------------------------------
__global__ void kNms(const float* __restrict__ cand_box,
                     const float* __restrict__ cand_score,
                     uint32_t* __restrict__ kept) {
    #pragma clang fp contract(off)
    const int blk = blockIdx.x;
    const int img = blk / NLVL;
    const int lvl = blk % NLVL;
    const int k    = c_k[lvl];
    const int base = c_base[lvl];

    __shared__ float ox1[1000], oy1[1000], ox2[1000], oy2[1000], ar[1000];
    __shared__ int supp[1000];

    const int tid = threadIdx.x, bs = blockDim.x;
    const float lo = (float)lvl * 2048.0f;

    for (int r = tid; r < k; r += bs) {
        const float* b = cand_box + ((size_t)img * M_TOT + base + r) * 4;
        float x1 = b[0] + lo, y1 = b[1] + lo;
        float x2 = b[2] + lo, y2 = b[3] + lo;
        ox1[r] = x1; oy1[r] = y1; ox2[r] = x2; oy2[r] = y2;
        ar[r] = (x2 - x1) * (y2 - y1);  // area from OFFSET coords, like the ref
        float s = cand_score[(size_t)img * M_TOT + base + r];
        supp[r] = (s > -5e8f) ? 0 : 1;  // invalid rows pre-suppressed (never suppress others)
    }
    __syncthreads();

    for (int r = 0; r < k; ++r) {
        if (supp[r] == 0) {  // uniform read (LDS broadcast)
            const float rx1 = ox1[r], ry1 = oy1[r];
            const float rx2 = ox2[r], ry2 = oy2[r], ra = ar[r];
            for (int j = r + 1 + tid; j < k; j += bs) {
                float ltx = fmaxf(rx1, ox1[j]);
                float lty = fmaxf(ry1, oy1[j]);
                float rbx = fminf(rx2, ox2[j]);
                float rby = fminf(ry2, oy2[j]);
                float wx = fmaxf(rbx - ltx, 0.0f);
                float wy = fmaxf(rby - lty, 0.0f);
                float inter = wx * wy;
                float denom = ((ra + ar[j]) - inter) + 1e-9f;
                if (inter / denom > 0.7f) supp[j] = 1;
            }
        }
        __syncthreads();
    }

    for (int r = tid; r < k; r += bs)
        kept[(size_t)img * M_TOT + base + r] = (supp[r] == 0) ? 1u : 0u;
}

// ---------------------------------------------------------------------------
// Kernel C: per image — stable partition of globally-sorted candidates by
// kept flag (== top_k(kept_scores) semantics), write first 1000 boxes+scores.
// ---------------------------------------------------------------------------
__global__ void kOutput(const float* __restrict__ cand_box,
                        const float* __restrict__ cand_score,
                        const uint32_t* __restrict__ sorted_slot,
                        const uint32_t* __restrict__ kept,
                        float* __restrict__ out) {
    const int img = blockIdx.x;
    const int tid = threadIdx.x;  // 1024 threads
    const int PT = 5;             // 5 * 1024 = 5120 >= 4768

    __shared__ int ssum[1024];

    const int pos0 = tid * PT;
    int flags[PT];
    uint32_t slots[PT];
    int lsum = 0;
    #pragma unroll
    for (int q = 0; q < PT; ++q) {
        int p = pos0 + q;
        int kf = 0; uint32_t sl = 0;
        if (p < M_TOT) {
            sl = sorted_slot[(size_t)img * M_TOT + p];
            kf = (int)kept[(size_t)img * M_TOT + sl];
        }
        flags[q] = kf; slots[q] = sl; lsum += kf;
    }
    ssum[tid] = lsum;
    __syncthreads();
    // Hillis-Steele inclusive scan over 1024 per-thread sums
    for (int off = 1; off < 1024; off <<= 1) {
        int v = (tid >= off) ? ssum[tid - off] : 0;
        __syncthreads();
        ssum[tid] += v;
        __syncthreads();
    }
    const int excl = ssum[tid] - lsum;
    const int total = ssum[1023];

    int run = 0;
    #pragma unroll
    for (int q = 0; q < PT; ++q) {
        int p = pos0 + q;
        if (p >= M_TOT) break;
        int kf = flags[q];
        int kbefore = excl + run;  // kept entries strictly before p
        run += kf;
        int oidx = kf ? kbefore : (total + (p - kbefore));
        if (oidx < POST_K) {
            uint32_t sl = slots[q];
            const float* b = cand_box + ((size_t)img * M_TOT + sl) * 4;
            float* ob = out + ((size_t)img * POST_K + oidx) * 4;
            ob[0] = b[0]; ob[1] = b[1]; ob[2] = b[2]; ob[3] = b[3];
            out[NIMG * POST_K * 4 + (size_t)img * POST_K + oidx] =
                kf ? cand_score[(size_t)img * M_TOT + sl] : NEGV;
        }
    }
}

extern "C" void kernel_launch(void* const* d_in, const int* in_sizes, int n_in,
                              void* d_out, int out_size, void* d_ws, size_t ws_size,
                              hipStream_t stream) {
    Ptrs p;
    for (int l = 0; l < NLVL; ++l) {
        p.logits[l]  = (const float*)d_in[3 * l + 0];
        p.deltas[l]  = (const float*)d_in[3 * l + 1];
        p.anchors[l] = (const float*)d_in[3 * l + 2];
    }

    // workspace layout (~534 KB total)
    float* cand_box   = (float*)d_ws;                       // NIMG*M_TOT*4 floats
    float* cand_score = cand_box + (size_t)NIMG * M_TOT * 4; // NIMG*M_TOT floats
    uint32_t* sorted_slot = (uint32_t*)(cand_score + (size_t)NIMG * M_TOT);
    uint32_t* kept        = sorted_slot + (size_t)NIMG * M_TOT;

    kTopkDecode<<<NIMG * NLVL, 256, 0, stream>>>(p, cand_box, cand_score);
    kSort<<<NIMG, 1024, 0, stream>>>(cand_score, sorted_slot);
    kNms<<<NIMG * NLVL, 256, 0, stream>>>(cand_box, cand_score, kept);
    kOutput<<<NIMG, 1024, 0, stream>>>(cand_box, cand_score, sorted_slot, kept,
                                       (float*)d_out);
}

// Round 2
// 901.479 us; speedup vs baseline: 1.7210x; 1.7210x over previous
//
#include <hip/hip_runtime.h>
#include <stdint.h>
#include <math.h>

#define NLVL 5
#define NIMG 4
#define NGRP (NIMG * NLVL)
#define M_TOT 4768
#define POST_K 1000
#define NEGV  (-1e9f)
#define SORT_N 8192
#define CAP 2048
#define NBIN 4096
#define BPI 65          // data-pass blocks per image

__constant__ int c_hwa[NLVL]  = {196608, 49152, 12288, 3072, 768};
__constant__ int c_k[NLVL]    = {1000, 1000, 1000, 1000, 768};
__constant__ int c_base[NLVL] = {0, 1000, 2000, 3000, 4000};
__constant__ int c_cnt[NLVL]  = {4096, 4096, 4096, 3072, 768};

struct Ptrs {
    const float* logits[NLVL];
    const float* deltas[NLVL];
    const float* anchors[NLVL];
};

__device__ __forceinline__ uint32_t flipf(float f) {
    uint32_t b = __float_as_uint(f);
    return (b & 0x80000000u) ? ~b : (b | 0x80000000u);
}
__device__ __forceinline__ float unflipf(uint32_t key) {
    uint32_t b = (key & 0x80000000u) ? (key & 0x7FFFFFFFu) : ~key;
    return __uint_as_float(b);
}

__device__ __forceinline__ void grp_decompose(int g, int& img, int& lvl, int& off, int& cnt) {
    img = g / BPI;
    int r = g % BPI;
    if (r < 48)      { lvl = 0; off = r * 4096; }
    else if (r < 60) { lvl = 1; off = (r - 48) * 4096; }
    else if (r < 63) { lvl = 2; off = (r - 60) * 4096; }
    else if (r < 64) { lvl = 3; off = 0; }
    else             { lvl = 4; off = 0; }
    cnt = c_cnt[lvl];
}

// ---------------------------------------------------------------------------
// Pass 1: 4096-bin histogram of top-12 key bits, per (img,lvl) group.
// ---------------------------------------------------------------------------
__global__ void kHist(Ptrs p, uint32_t* __restrict__ ghist) {
    __shared__ uint32_t lh[NBIN];
    int img, lvl, off, cnt;
    grp_decompose(blockIdx.x, img, lvl, off, cnt);
    const int tid = threadIdx.x;
    const float* lg = p.logits[lvl] + (size_t)img * c_hwa[lvl] + off;

    for (int b = tid; b < NBIN; b += 256) lh[b] = 0u;
    __syncthreads();

    const int nvec = cnt >> 2;
    const float4* lg4 = (const float4*)lg;
    for (int v = tid; v < nvec; v += 256) {
        float4 x = lg4[v];
        atomicAdd(&lh[flipf(x.x) >> 20], 1u);
        atomicAdd(&lh[flipf(x.y) >> 20], 1u);
        atomicAdd(&lh[flipf(x.z) >> 20], 1u);
        atomicAdd(&lh[flipf(x.w) >> 20], 1u);
    }
    __syncthreads();

    uint32_t* gh = ghist + (size_t)(img * NLVL + lvl) * NBIN;
    for (int b = tid; b < NBIN; b += 256)
        if (lh[b]) atomicAdd(&gh[b], lh[b]);
}

// ---------------------------------------------------------------------------
// Pass 2: per group, find threshold bucket d: count(>d) < k <= count(>=d).
// ---------------------------------------------------------------------------
__global__ void kSelect(const uint32_t* __restrict__ ghist, uint32_t* __restrict__ thr) {
    const int grp = blockIdx.x;
    const int k = c_k[grp % NLVL];
    __shared__ uint32_t h[NBIN];
    __shared__ uint32_t ss[256];
    const int tid = threadIdx.x;
    const uint32_t* gh = ghist + (size_t)grp * NBIN;

    for (int b = tid; b < NBIN; b += 256) h[b] = gh[b];
    __syncthreads();

    uint32_t s = 0;
    #pragma unroll
    for (int b = 0; b < 16; ++b) s += h[tid * 16 + b];
    ss[tid] = s;
    __syncthreads();
    for (int off = 1; off < 256; off <<= 1) {
        uint32_t v = (tid + off < 256) ? ss[tid + off] : 0u;
        __syncthreads();
        ss[tid] += v;
        __syncthreads();
    }
    uint32_t running = (tid == 255) ? 0u : ss[tid + 1];
    for (int b = 15; b >= 0; --b) {
        uint32_t c = h[tid * 16 + b];
        running += c;
        if ((running >= (uint32_t)k) && (running - c < (uint32_t)k)) {
            thr[grp] = (uint32_t)(tid * 16 + b) << 20;
        }
    }
}

// ---------------------------------------------------------------------------
// Pass 3: compact keys >= T into per-group packed candidate list.
// ---------------------------------------------------------------------------
__global__ void kCompact(Ptrs p, const uint32_t* __restrict__ thr,
                         uint32_t* __restrict__ cand_cnt,
                         uint64_t* __restrict__ cand_pk) {
    int img, lvl, off, cnt;
    grp_decompose(blockIdx.x, img, lvl, off, cnt);
    const int grp = img * NLVL + lvl;
    const int tid = threadIdx.x;
    const float* lg = p.logits[lvl] + (size_t)img * c_hwa[lvl] + off;
    const uint32_t T = thr[grp];
    uint64_t* pk = cand_pk + (size_t)grp * CAP;

    const int nvec = cnt >> 2;
    const float4* lg4 = (const float4*)lg;
    for (int v = tid; v < nvec; v += 256) {
        float4 x = lg4[v];
        float xs[4] = {x.x, x.y, x.z, x.w};
        #pragma unroll
        for (int c = 0; c < 4; ++c) {
            uint32_t key = flipf(xs[c]);
            if (key >= T) {
                uint32_t pos = atomicAdd(&cand_cnt[grp], 1u);
                if (pos < CAP) {
                    uint32_t eidx = (uint32_t)(off + 4 * v + c);
                    pk[pos] = ((uint64_t)key << 32) | (uint32_t)(~eidx);
                }
            }
        }
    }
}

// ---------------------------------------------------------------------------
// Pass 4: exact rank among candidates; decode boxes for rank < k.
// ---------------------------------------------------------------------------
__global__ void kRankDecode(Ptrs p, const uint32_t* __restrict__ cand_cnt,
                            const uint64_t* __restrict__ cand_pk,
                            float* __restrict__ cand_box,
                            float* __restrict__ cand_score) {
    #pragma clang fp contract(off)
    const int grp = blockIdx.x;
    const int img = grp / NLVL;
    const int lvl = grp % NLVL;
    const int n    = c_hwa[lvl];
    const int k    = c_k[lvl];
    const int base = c_base[lvl];
    const int tid = threadIdx.x;

    __shared__ uint64_t K[CAP];
    const int cc = (int)min(cand_cnt[grp], (uint32_t)CAP);
    const uint64_t* pk = cand_pk + (size_t)grp * CAP;
    for (int i = tid; i < cc; i += 256) K[i] = pk[i];
    __syncthreads();

    uint64_t myK[8];
    int myR[8];
    #pragma unroll
    for (int q = 0; q < 8; ++q) {
        int c = tid + q * 256;
        myK[q] = (c < cc) ? K[c] : 0ULL;
        myR[q] = 0;
    }
    for (int j = 0; j < cc; ++j) {
        uint64_t Kj = K[j];
        #pragma unroll
        for (int q = 0; q < 8; ++q) myR[q] += (int)(Kj > myK[q]);
    }

    #pragma unroll
    for (int q = 0; q < 8; ++q) {
        int c = tid + q * 256;
        if (c >= cc) continue;
        int r = myR[q];
        if (r >= k) continue;
        uint32_t key = (uint32_t)(myK[q] >> 32);
        uint32_t ic  = ~(uint32_t)(myK[q] & 0xFFFFFFFFu);
        const float* an = p.anchors[lvl] + (size_t)ic * 4;
        const float* dl = p.deltas[lvl] + ((size_t)img * n + ic) * 4;
        float a0 = an[0], a1 = an[1], a2 = an[2], a3 = an[3];
        float wa = a2 - a0, ha = a3 - a1;
        float cxa = a0 + 0.5f * wa, cya = a1 + 0.5f * ha;
        float dx = dl[0], dy = dl[1], dw = dl[2], dh = dl[3];
        const float SC = (float)4.135166556742356;  // log(1000/16)
        dw = fminf(dw, SC);
        dh = fminf(dh, SC);
        float cx = dx * wa + cxa, cy = dy * ha + cya;
        float w = wa * expf(dw), h = ha * expf(dh);
        float x1 = cx - 0.5f * w, y1 = cy - 0.5f * h;
        float x2 = cx + 0.5f * w, y2 = cy + 0.5f * h;
        x1 = fminf(fmaxf(x1, 0.0f), 1024.0f);
        y1 = fminf(fmaxf(y1, 0.0f), 1024.0f);
        x2 = fminf(fmaxf(x2, 0.0f), 1024.0f);
        y2 = fminf(fmaxf(y2, 0.0f), 1024.0f);
        float bw = x2 - x1, bh = y2 - y1;
        float score = (bw > 0.0f && bh > 0.0f) ? unflipf(key) : NEGV;
        const int slot = base + r;
        float* ob = cand_box + ((size_t)img * M_TOT + slot) * 4;
        ob[0] = x1; ob[1] = y1; ob[2] = x2; ob[3] = y2;
        cand_score[(size_t)img * M_TOT + slot] = score;
    }
}

// ---------------------------------------------------------------------------
// Per image: exact global sort by (score desc, slot asc). Bitonic 8192 in LDS.
// ---------------------------------------------------------------------------
__global__ void kSort(const float* __restrict__ cand_score,
                      uint32_t* __restrict__ sorted_slot) {
    const int img = blockIdx.x;
    __shared__ uint64_t keys[SORT_N];
    const int tid = threadIdx.x, bs = blockDim.x;

    for (int i = tid; i < SORT_N; i += bs) {
        uint64_t kk;
        if (i < M_TOT) {
            float s = cand_score[(size_t)img * M_TOT + i];
            kk = ((uint64_t)(~flipf(s)) << 32) | (uint32_t)i;
        } else {
            kk = ~0ULL;
        }
        keys[i] = kk;
    }
    __syncthreads();

    for (int size = 2; size <= SORT_N; size <<= 1) {
        for (int stride = size >> 1; stride > 0; stride >>= 1) {
            for (int i = tid; i < SORT_N; i += bs) {
                int j = i ^ stride;
                if (j > i) {
                    uint64_t a = keys[i], b = keys[j];
                    bool asc = ((i & size) == 0);
                    if ((a > b) == asc) { keys[i] = b; keys[j] = a; }
                }
            }
            __syncthreads();
        }
    }

    for (int i = tid; i < M_TOT; i += bs)
        sorted_slot[(size_t)img * M_TOT + i] = (uint32_t)(keys[i] & 0xFFFFFFFFu);
}

// ---------------------------------------------------------------------------
// Greedy NMS per (img,lvl) in rank order (levels independent via lvl offset).
// ---------------------------------------------------------------------------
__global__ void kNms(const float* __restrict__ cand_box,
                     const float* __restrict__ cand_score,
                     uint32_t* __restrict__ kept) {
    #pragma clang fp contract(off)
    const int blk = blockIdx.x;
    const int img = blk / NLVL;
    const int lvl = blk % NLVL;
    const int k    = c_k[lvl];
    const int base = c_base[lvl];

    __shared__ float ox1[1000], oy1[1000], ox2[1000], oy2[1000], ar[1000];
    __shared__ int supp[1000];

    const int tid = threadIdx.x, bs = blockDim.x;
    const float lo = (float)lvl * 2048.0f;

    for (int r = tid; r < k; r += bs) {
        const float* b = cand_box + ((size_t)img * M_TOT + base + r) * 4;
        float x1 = b[0] + lo, y1 = b[1] + lo;
        float x2 = b[2] + lo, y2 = b[3] + lo;
        ox1[r] = x1; oy1[r] = y1; ox2[r] = x2; oy2[r] = y2;
        ar[r] = (x2 - x1) * (y2 - y1);
        float s = cand_score[(size_t)img * M_TOT + base + r];
        supp[r] = (s > -5e8f) ? 0 : 1;
    }
    __syncthreads();

    for (int r = 0; r < k; ++r) {
        if (supp[r] == 0) {
            const float rx1 = ox1[r], ry1 = oy1[r];
            const float rx2 = ox2[r], ry2 = oy2[r], ra = ar[r];
            for (int j = r + 1 + tid; j < k; j += bs) {
                float ltx = fmaxf(rx1, ox1[j]);
                float lty = fmaxf(ry1, oy1[j]);
                float rbx = fminf(rx2, ox2[j]);
                float rby = fminf(ry2, oy2[j]);
                float wx = fmaxf(rbx - ltx, 0.0f);
                float wy = fmaxf(rby - lty, 0.0f);
                float inter = wx * wy;
                float denom = ((ra + ar[j]) - inter) + 1e-9f;
                if (inter / denom > 0.7f) supp[j] = 1;
            }
        }
        __syncthreads();
    }

    for (int r = tid; r < k; r += bs)
        kept[(size_t)img * M_TOT + base + r] = (supp[r] == 0) ? 1u : 0u;
}

// ---------------------------------------------------------------------------
// Stable partition of globally-sorted candidates by kept flag → output.
// ---------------------------------------------------------------------------
__global__ void kOutput(const float* __restrict__ cand_box,
                        const float* __restrict__ cand_score,
                        const uint32_t* __restrict__ sorted_slot,
                        const uint32_t* __restrict__ kept,
                        float* __restrict__ out) {
    const int img = blockIdx.x;
    const int tid = threadIdx.x;  // 1024 threads
    const int PT = 5;

    __shared__ int ssum[1024];

    const int pos0 = tid * PT;
    int flags[PT];
    uint32_t slots[PT];
    int lsum = 0;
    #pragma unroll
    for (int q = 0; q < PT; ++q) {
        int p = pos0 + q;
        int kf = 0; uint32_t sl = 0;
        if (p < M_TOT) {
            sl = sorted_slot[(size_t)img * M_TOT + p];
            kf = (int)kept[(size_t)img * M_TOT + sl];
        }
        flags[q] = kf; slots[q] = sl; lsum += kf;
    }
    ssum[tid] = lsum;
    __syncthreads();
    for (int off = 1; off < 1024; off <<= 1) {
        int v = (tid >= off) ? ssum[tid - off] : 0;
        __syncthreads();
        ssum[tid] += v;
        __syncthreads();
    }
    const int excl = ssum[tid] - lsum;
    const int total = ssum[1023];

    int run = 0;
    #pragma unroll
    for (int q = 0; q < PT; ++q) {
        int p = pos0 + q;
        if (p >= M_TOT) break;
        int kf = flags[q];
        int kbefore = excl + run;
        run += kf;
        int oidx = kf ? kbefore : (total + (p - kbefore));
        if (oidx < POST_K) {
            uint32_t sl = slots[q];
            const float* b = cand_box + ((size_t)img * M_TOT + sl) * 4;
            float* ob = out + ((size_t)img * POST_K + oidx) * 4;
            ob[0] = b[0]; ob[1] = b[1]; ob[2] = b[2]; ob[3] = b[3];
            out[NIMG * POST_K * 4 + (size_t)img * POST_K + oidx] =
                kf ? cand_score[(size_t)img * M_TOT + sl] : NEGV;
        }
    }
}

extern "C" void kernel_launch(void* const* d_in, const int* in_sizes, int n_in,
                              void* d_out, int out_size, void* d_ws, size_t ws_size,
                              hipStream_t stream) {
    Ptrs p;
    for (int l = 0; l < NLVL; ++l) {
        p.logits[l]  = (const float*)d_in[3 * l + 0];
        p.deltas[l]  = (const float*)d_in[3 * l + 1];
        p.anchors[l] = (const float*)d_in[3 * l + 2];
    }

    // workspace layout (~1.2 MB)
    char* w = (char*)d_ws;
    float* cand_box   = (float*)w;        w += (size_t)NIMG * M_TOT * 4 * sizeof(float);
    float* cand_score = (float*)w;        w += (size_t)NIMG * M_TOT * sizeof(float);
    uint32_t* sorted_slot = (uint32_t*)w; w += (size_t)NIMG * M_TOT * sizeof(uint32_t);
    uint32_t* kept        = (uint32_t*)w; w += (size_t)NIMG * M_TOT * sizeof(uint32_t);
    uint32_t* ghist       = (uint32_t*)w; w += (size_t)NGRP * NBIN * sizeof(uint32_t);
    uint32_t* cand_cnt    = (uint32_t*)w; w += 128;   // 20 u32 counters (padded)
    uint32_t* thr         = (uint32_t*)w; w += 128;   // 20 u32 thresholds (padded)
    uint64_t* cand_pk     = (uint64_t*)w; w += (size_t)NGRP * CAP * sizeof(uint64_t);

    // zero ghist + cand_cnt + thr (one contiguous region)
    hipMemsetAsync(ghist, 0, (size_t)NGRP * NBIN * sizeof(uint32_t) + 256, stream);

    kHist      <<<NIMG * BPI, 256, 0, stream>>>(p, ghist);
    kSelect    <<<NGRP,       256, 0, stream>>>(ghist, thr);
    kCompact   <<<NIMG * BPI, 256, 0, stream>>>(p, thr, cand_cnt, cand_pk);
    kRankDecode<<<NGRP,       256, 0, stream>>>(p, cand_cnt, cand_pk, cand_box, cand_score);
    kSort      <<<NIMG,      1024, 0, stream>>>(cand_score, sorted_slot);
    kNms       <<<NGRP,       256, 0, stream>>>(cand_box, cand_score, kept);
    kOutput    <<<NIMG,      1024, 0, stream>>>(cand_box, cand_score, sorted_slot, kept,
                                                (float*)d_out);
}

// Round 3
// 470.101 us; speedup vs baseline: 3.3003x; 1.9176x over previous
//
#include <hip/hip_runtime.h>
#include <stdint.h>
#include <math.h>

#define NLVL 5
#define NIMG 4
#define NGRP (NIMG * NLVL)
#define M_TOT 4768
#define POST_K 1000
#define NEGV  (-1e9f)
#define SORT_N 8192
#define CAP 2048
#define NBIN 4096
#define BPI 65          // data-pass blocks per image
#define TRI_W 7680      // upper-triangular word count per group (k<=1000, 16 words)

__constant__ int c_hwa[NLVL]  = {196608, 49152, 12288, 3072, 768};
__constant__ int c_k[NLVL]    = {1000, 1000, 1000, 1000, 768};
__constant__ int c_base[NLVL] = {0, 1000, 2000, 3000, 4000};
__constant__ int c_cnt[NLVL]  = {4096, 4096, 4096, 3072, 768};

struct Ptrs {
    const float* logits[NLVL];
    const float* deltas[NLVL];
    const float* anchors[NLVL];
};

__device__ __forceinline__ uint32_t flipf(float f) {
    uint32_t b = __float_as_uint(f);
    return (b & 0x80000000u) ? ~b : (b | 0x80000000u);
}
__device__ __forceinline__ float unflipf(uint32_t key) {
    uint32_t b = (key & 0x80000000u) ? (key & 0x7FFFFFFFu) : ~key;
    return __uint_as_float(b);
}

__device__ __forceinline__ void grp_decompose(int g, int& img, int& lvl, int& off, int& cnt) {
    img = g / BPI;
    int r = g % BPI;
    if (r < 48)      { lvl = 0; off = r * 4096; }
    else if (r < 60) { lvl = 1; off = (r - 48) * 4096; }
    else if (r < 63) { lvl = 2; off = (r - 60) * 4096; }
    else if (r < 64) { lvl = 3; off = 0; }
    else             { lvl = 4; off = 0; }
    cnt = c_cnt[lvl];
}

// ---------------------------------------------------------------------------
// Pass 1: 4096-bin histogram of top-12 key bits, per (img,lvl) group.
// ---------------------------------------------------------------------------
__global__ void kHist(Ptrs p, uint32_t* __restrict__ ghist) {
    __shared__ uint32_t lh[NBIN];
    int img, lvl, off, cnt;
    grp_decompose(blockIdx.x, img, lvl, off, cnt);
    const int tid = threadIdx.x;
    const float* lg = p.logits[lvl] + (size_t)img * c_hwa[lvl] + off;

    for (int b = tid; b < NBIN; b += 256) lh[b] = 0u;
    __syncthreads();

    const int nvec = cnt >> 2;
    const float4* lg4 = (const float4*)lg;
    for (int v = tid; v < nvec; v += 256) {
        float4 x = lg4[v];
        atomicAdd(&lh[flipf(x.x) >> 20], 1u);
        atomicAdd(&lh[flipf(x.y) >> 20], 1u);
        atomicAdd(&lh[flipf(x.z) >> 20], 1u);
        atomicAdd(&lh[flipf(x.w) >> 20], 1u);
    }
    __syncthreads();

    uint32_t* gh = ghist + (size_t)(img * NLVL + lvl) * NBIN;
    for (int b = tid; b < NBIN; b += 256)
        if (lh[b]) atomicAdd(&gh[b], lh[b]);
}

// ---------------------------------------------------------------------------
// Pass 2: per group, find threshold bucket d: count(>d) < k <= count(>=d).
// ---------------------------------------------------------------------------
__global__ void kSelect(const uint32_t* __restrict__ ghist, uint32_t* __restrict__ thr) {
    const int grp = blockIdx.x;
    const int k = c_k[grp % NLVL];
    __shared__ uint32_t h[NBIN];
    __shared__ uint32_t ss[256];
    const int tid = threadIdx.x;
    const uint32_t* gh = ghist + (size_t)grp * NBIN;

    for (int b = tid; b < NBIN; b += 256) h[b] = gh[b];
    __syncthreads();

    uint32_t s = 0;
    #pragma unroll
    for (int b = 0; b < 16; ++b) s += h[tid * 16 + b];
    ss[tid] = s;
    __syncthreads();
    for (int off = 1; off < 256; off <<= 1) {
        uint32_t v = (tid + off < 256) ? ss[tid + off] : 0u;
        __syncthreads();
        ss[tid] += v;
        __syncthreads();
    }
    uint32_t running = (tid == 255) ? 0u : ss[tid + 1];
    for (int b = 15; b >= 0; --b) {
        uint32_t c = h[tid * 16 + b];
        running += c;
        if ((running >= (uint32_t)k) && (running - c < (uint32_t)k)) {
            thr[grp] = (uint32_t)(tid * 16 + b) << 20;
        }
    }
}

// ---------------------------------------------------------------------------
// Pass 3: compact keys >= T into per-group packed candidate list.
// ---------------------------------------------------------------------------
__global__ void kCompact(Ptrs p, const uint32_t* __restrict__ thr,
                         uint32_t* __restrict__ cand_cnt,
                         uint64_t* __restrict__ cand_pk) {
    int img, lvl, off, cnt;
    grp_decompose(blockIdx.x, img, lvl, off, cnt);
    const int grp = img * NLVL + lvl;
    const int tid = threadIdx.x;
    const float* lg = p.logits[lvl] + (size_t)img * c_hwa[lvl] + off;
    const uint32_t T = thr[grp];
    uint64_t* pk = cand_pk + (size_t)grp * CAP;

    const int nvec = cnt >> 2;
    const float4* lg4 = (const float4*)lg;
    for (int v = tid; v < nvec; v += 256) {
        float4 x = lg4[v];
        float xs[4] = {x.x, x.y, x.z, x.w};
        #pragma unroll
        for (int c = 0; c < 4; ++c) {
            uint32_t key = flipf(xs[c]);
            if (key >= T) {
                uint32_t pos = atomicAdd(&cand_cnt[grp], 1u);
                if (pos < CAP) {
                    uint32_t eidx = (uint32_t)(off + 4 * v + c);
                    pk[pos] = ((uint64_t)key << 32) | (uint32_t)(~eidx);
                }
            }
        }
    }
}

// ---------------------------------------------------------------------------
// Pass 4: exact rank among candidates; decode boxes for rank < k.
// ---------------------------------------------------------------------------
__global__ void kRankDecode(Ptrs p, const uint32_t* __restrict__ cand_cnt,
                            const uint64_t* __restrict__ cand_pk,
                            float* __restrict__ cand_box,
                            float* __restrict__ cand_score) {
    #pragma clang fp contract(off)
    const int grp = blockIdx.x;
    const int img = grp / NLVL;
    const int lvl = grp % NLVL;
    const int n    = c_hwa[lvl];
    const int k    = c_k[lvl];
    const int base = c_base[lvl];
    const int tid = threadIdx.x;

    __shared__ uint64_t K[CAP];
    const int cc = (int)min(cand_cnt[grp], (uint32_t)CAP);
    const uint64_t* pk = cand_pk + (size_t)grp * CAP;
    for (int i = tid; i < cc; i += 256) K[i] = pk[i];
    __syncthreads();

    uint64_t myK[8];
    int myR[8];
    #pragma unroll
    for (int q = 0; q < 8; ++q) {
        int c = tid + q * 256;
        myK[q] = (c < cc) ? K[c] : 0ULL;
        myR[q] = 0;
    }
    for (int j = 0; j < cc; ++j) {
        uint64_t Kj = K[j];
        #pragma unroll
        for (int q = 0; q < 8; ++q) myR[q] += (int)(Kj > myK[q]);
    }

    #pragma unroll
    for (int q = 0; q < 8; ++q) {
        int c = tid + q * 256;
        if (c >= cc) continue;
        int r = myR[q];
        if (r >= k) continue;
        uint32_t key = (uint32_t)(myK[q] >> 32);
        uint32_t ic  = ~(uint32_t)(myK[q] & 0xFFFFFFFFu);
        const float* an = p.anchors[lvl] + (size_t)ic * 4;
        const float* dl = p.deltas[lvl] + ((size_t)img * n + ic) * 4;
        float a0 = an[0], a1 = an[1], a2 = an[2], a3 = an[3];
        float wa = a2 - a0, ha = a3 - a1;
        float cxa = a0 + 0.5f * wa, cya = a1 + 0.5f * ha;
        float dx = dl[0], dy = dl[1], dw = dl[2], dh = dl[3];
        const float SC = (float)4.135166556742356;  // log(1000/16)
        dw = fminf(dw, SC);
        dh = fminf(dh, SC);
        float cx = dx * wa + cxa, cy = dy * ha + cya;
        float w = wa * expf(dw), h = ha * expf(dh);
        float x1 = cx - 0.5f * w, y1 = cy - 0.5f * h;
        float x2 = cx + 0.5f * w, y2 = cy + 0.5f * h;
        x1 = fminf(fmaxf(x1, 0.0f), 1024.0f);
        y1 = fminf(fmaxf(y1, 0.0f), 1024.0f);
        x2 = fminf(fmaxf(x2, 0.0f), 1024.0f);
        y2 = fminf(fmaxf(y2, 0.0f), 1024.0f);
        float bw = x2 - x1, bh = y2 - y1;
        float score = (bw > 0.0f && bh > 0.0f) ? unflipf(key) : NEGV;
        const int slot = base + r;
        float* ob = cand_box + ((size_t)img * M_TOT + slot) * 4;
        ob[0] = x1; ob[1] = y1; ob[2] = x2; ob[3] = y2;
        cand_score[(size_t)img * M_TOT + slot] = score;
    }
}

// ---------------------------------------------------------------------------
// NMS phase 1: suppression bit-matrix, upper-triangular by 64-wide word.
// Block = (grp, w): rows r in [0, min(64(w+1),k)), word w = boxes j in
// [64w, 64w+64). bit jj set iff j>r && IoU>0.7 (exact ref FP order).
// Diagonal words (q(r)==w) -> diag[], above-diagonal -> packed tri[].
// ---------------------------------------------------------------------------
__global__ void kIou(const float* __restrict__ cand_box,
                     uint64_t* __restrict__ tri, uint64_t* __restrict__ diag) {
    #pragma clang fp contract(off)
    const int blk = blockIdx.x;      // grp*16 + w
    const int grp = blk >> 4;
    const int w   = blk & 15;
    const int img = grp / NLVL;
    const int lvl = grp % NLVL;
    const int k    = c_k[lvl];
    const int base = c_base[lvl];
    if (64 * w >= k) return;
    const int jn = min(64, k - 64 * w);
    const int R  = min(64 * (w + 1), k);
    const float lo = (float)lvl * 2048.0f;

    __shared__ float jx1[64], jy1[64], jx2[64], jy2[64], jar[64];
    const int tid = threadIdx.x;
    if (tid < jn) {
        const float4 b = *(const float4*)(cand_box + ((size_t)img * M_TOT + base + 64 * w + tid) * 4);
        float x1 = b.x + lo, y1 = b.y + lo, x2 = b.z + lo, y2 = b.w + lo;
        jx1[tid] = x1; jy1[tid] = y1; jx2[tid] = x2; jy2[tid] = y2;
        jar[tid] = (x2 - x1) * (y2 - y1);
    }
    __syncthreads();

    for (int r = tid; r < R; r += 256) {
        const float4 b = *(const float4*)(cand_box + ((size_t)img * M_TOT + base + r) * 4);
        float rx1 = b.x + lo, ry1 = b.y + lo, rx2 = b.z + lo, ry2 = b.w + lo;
        float ra = (rx2 - rx1) * (ry2 - ry1);
        uint64_t bits = 0ull;
        #pragma unroll 8
        for (int jj = 0; jj < jn; ++jj) {
            int j = 64 * w + jj;
            if (j > r) {
                float ltx = fmaxf(rx1, jx1[jj]);
                float lty = fmaxf(ry1, jy1[jj]);
                float rbx = fminf(rx2, jx2[jj]);
                float rby = fminf(ry2, jy2[jj]);
                float wx = fmaxf(rbx - ltx, 0.0f);
                float wy = fmaxf(rby - lty, 0.0f);
                float inter = wx * wy;
                float denom = ((ra + jar[jj]) - inter) + 1e-9f;
                if (inter / denom > 0.7f) bits |= (1ull << jj);
            }
        }
        const int q = r >> 6;
        if (q == w) {
            diag[(size_t)grp * 1024 + r] = bits;
        } else {
            const int m = r & 63;
            const int tb = 15 * r - 32 * q * (q - 1) - m * q;  // tri_base(r)
            tri[(size_t)grp * TRI_W + tb + (w - q - 1)] = bits;
        }
    }
}

// ---------------------------------------------------------------------------
// NMS phase 2: greedy scan, one wave per group, no barriers in the loop.
// Per 64-row block q: batched OR of prior kept rows' column-q words (LDS,
// parallel), then a 64-step scalar loop using v_readlane on preloaded
// diagonal words. kept[r] written at the end.
// ---------------------------------------------------------------------------
__global__ void kScan(const float* __restrict__ cand_score,
                      const uint64_t* __restrict__ tri,
                      const uint64_t* __restrict__ diag,
                      uint32_t* __restrict__ kept) {
    const int grp = blockIdx.x;
    const int img = grp / NLVL;
    const int lvl = grp % NLVL;
    const int k    = c_k[lvl];
    const int base = c_base[lvl];
    __shared__ uint64_t tl[TRI_W];
    const int tid = threadIdx.x;
    const uint64_t* tg = tri + (size_t)grp * TRI_W;
    for (int i = tid; i < TRI_W; i += 256) tl[i] = tg[i];
    __syncthreads();
    if (tid >= 64) return;           // wave 0 does the scan; no barriers follow
    const int lane = tid;

    // preload diagonal words: darr[s] = diag row (64s + lane)
    uint64_t darr[16];
    #pragma unroll
    for (int s = 0; s < 16; ++s)
        darr[s] = (64 * s + lane < k) ? diag[(size_t)grp * 1024 + 64 * s + lane] : 0ull;

    // invalid-row words (invalid rows pre-suppressed, never suppress others)
    float sc[16];
    #pragma unroll
    for (int s = 0; s < 16; ++s) {
        int r = 64 * s + lane;
        sc[s] = (r < k) ? cand_score[(size_t)img * M_TOT + base + r] : NEGV;
    }
    uint64_t inv[16];
    #pragma unroll
    for (int s = 0; s < 16; ++s)
        inv[s] = (uint64_t)__ballot(sc[s] <= -5e8f);

    uint64_t keep_w[16];
    #pragma unroll
    for (int s = 0; s < 16; ++s) keep_w[s] = 0ull;

    #pragma unroll
    for (int q = 0; q < 16; ++q) {
        if (64 * q < k) {
            // cur = inv[q] | OR over kept rows r' < 64q of their column-q word
            uint64_t v = 0ull;
            #pragma unroll
            for (int s = 0; s < q; ++s) {
                if ((keep_w[s] >> lane) & 1ull) {
                    const int rp = 64 * s + lane;
                    const int tb = 15 * rp - 32 * s * (s - 1) - lane * s;
                    v |= tl[tb + (q - s - 1)];
                }
            }
            #pragma unroll
            for (int off2 = 32; off2 >= 1; off2 >>= 1)
                v |= (uint64_t)__shfl_xor((unsigned long long)v, off2, 64);
            const uint64_t cur0 = inv[q] | v;
            uint32_t clo = __builtin_amdgcn_readfirstlane((uint32_t)cur0);
            uint32_t chi = __builtin_amdgcn_readfirstlane((uint32_t)(cur0 >> 32));
            uint64_t scur = ((uint64_t)chi << 32) | (uint64_t)clo;
            uint64_t kw = 0ull;
            const int mm = min(64, k - 64 * q);
            const uint32_t dlo = (uint32_t)darr[q];
            const uint32_t dhi = (uint32_t)(darr[q] >> 32);
            for (int m = 0; m < mm; ++m) {
                if (!((scur >> m) & 1ull)) {
                    uint64_t dg = ((uint64_t)(uint32_t)__builtin_amdgcn_readlane((int)dhi, m) << 32)
                                |  (uint64_t)(uint32_t)__builtin_amdgcn_readlane((int)dlo, m);
                    scur |= dg;
                    kw |= (1ull << m);
                }
            }
            keep_w[q] = kw;
        }
    }

    #pragma unroll
    for (int s = 0; s < 16; ++s) {
        int r = 64 * s + lane;
        if (r < k)
            kept[(size_t)img * M_TOT + base + r] = (uint32_t)((keep_w[s] >> lane) & 1ull);
    }
}

// ---------------------------------------------------------------------------
// Per image: exact global sort by (score desc, slot asc). Bitonic 8192 in LDS.
// ---------------------------------------------------------------------------
__global__ void kSort(const float* __restrict__ cand_score,
                      uint32_t* __restrict__ sorted_slot) {
    const int img = blockIdx.x;
    __shared__ uint64_t keys[SORT_N];
    const int tid = threadIdx.x, bs = blockDim.x;

    for (int i = tid; i < SORT_N; i += bs) {
        uint64_t kk;
        if (i < M_TOT) {
            float s = cand_score[(size_t)img * M_TOT + i];
            kk = ((uint64_t)(~flipf(s)) << 32) | (uint32_t)i;
        } else {
            kk = ~0ULL;
        }
        keys[i] = kk;
    }
    __syncthreads();

    for (int size = 2; size <= SORT_N; size <<= 1) {
        for (int stride = size >> 1; stride > 0; stride >>= 1) {
            for (int i = tid; i < SORT_N; i += bs) {
                int j = i ^ stride;
                if (j > i) {
                    uint64_t a = keys[i], b = keys[j];
                    bool asc = ((i & size) == 0);
                    if ((a > b) == asc) { keys[i] = b; keys[j] = a; }
                }
            }
            __syncthreads();
        }
    }

    for (int i = tid; i < M_TOT; i += bs)
        sorted_slot[(size_t)img * M_TOT + i] = (uint32_t)(keys[i] & 0xFFFFFFFFu);
}

// ---------------------------------------------------------------------------
// Stable partition of globally-sorted candidates by kept flag → output.
// ---------------------------------------------------------------------------
__global__ void kOutput(const float* __restrict__ cand_box,
                        const float* __restrict__ cand_score,
                        const uint32_t* __restrict__ sorted_slot,
                        const uint32_t* __restrict__ kept,
                        float* __restrict__ out) {
    const int img = blockIdx.x;
    const int tid = threadIdx.x;  // 1024 threads
    const int PT = 5;

    __shared__ int ssum[1024];

    const int pos0 = tid * PT;
    int flags[PT];
    uint32_t slots[PT];
    int lsum = 0;
    #pragma unroll
    for (int q = 0; q < PT; ++q) {
        int p = pos0 + q;
        int kf = 0; uint32_t sl = 0;
        if (p < M_TOT) {
            sl = sorted_slot[(size_t)img * M_TOT + p];
            kf = (int)kept[(size_t)img * M_TOT + sl];
        }
        flags[q] = kf; slots[q] = sl; lsum += kf;
    }
    ssum[tid] = lsum;
    __syncthreads();
    for (int off = 1; off < 1024; off <<= 1) {
        int v = (tid >= off) ? ssum[tid - off] : 0;
        __syncthreads();
        ssum[tid] += v;
        __syncthreads();
    }
    const int excl = ssum[tid] - lsum;
    const int total = ssum[1023];

    int run = 0;
    #pragma unroll
    for (int q = 0; q < PT; ++q) {
        int p = pos0 + q;
        if (p >= M_TOT) break;
        int kf = flags[q];
        int kbefore = excl + run;
        run += kf;
        int oidx = kf ? kbefore : (total + (p - kbefore));
        if (oidx < POST_K) {
            uint32_t sl = slots[q];
            const float* b = cand_box + ((size_t)img * M_TOT + sl) * 4;
            float* ob = out + ((size_t)img * POST_K + oidx) * 4;
            ob[0] = b[0]; ob[1] = b[1]; ob[2] = b[2]; ob[3] = b[3];
            out[NIMG * POST_K * 4 + (size_t)img * POST_K + oidx] =
                kf ? cand_score[(size_t)img * M_TOT + sl] : NEGV;
        }
    }
}

extern "C" void kernel_launch(void* const* d_in, const int* in_sizes, int n_in,
                              void* d_out, int out_size, void* d_ws, size_t ws_size,
                              hipStream_t stream) {
    Ptrs p;
    for (int l = 0; l < NLVL; ++l) {
        p.logits[l]  = (const float*)d_in[3 * l + 0];
        p.deltas[l]  = (const float*)d_in[3 * l + 1];
        p.anchors[l] = (const float*)d_in[3 * l + 2];
    }

    // workspace layout (~2.6 MB)
    char* w = (char*)d_ws;
    float* cand_box   = (float*)w;        w += (size_t)NIMG * M_TOT * 4 * sizeof(float);
    float* cand_score = (float*)w;        w += (size_t)NIMG * M_TOT * sizeof(float);
    uint32_t* sorted_slot = (uint32_t*)w; w += (size_t)NIMG * M_TOT * sizeof(uint32_t);
    uint32_t* kept        = (uint32_t*)w; w += (size_t)NIMG * M_TOT * sizeof(uint32_t);
    uint32_t* ghist       = (uint32_t*)w; w += (size_t)NGRP * NBIN * sizeof(uint32_t);
    uint32_t* cand_cnt    = (uint32_t*)w; w += 128;   // 20 u32 counters (padded)
    uint32_t* thr         = (uint32_t*)w; w += 128;   // 20 u32 thresholds (padded)
    uint64_t* cand_pk     = (uint64_t*)w; w += (size_t)NGRP * CAP * sizeof(uint64_t);
    uint64_t* tri         = (uint64_t*)w; w += (size_t)NGRP * TRI_W * sizeof(uint64_t);
    uint64_t* diag        = (uint64_t*)w; w += (size_t)NGRP * 1024 * sizeof(uint64_t);

    // zero ghist + cand_cnt + thr (one contiguous region)
    hipMemsetAsync(ghist, 0, (size_t)NGRP * NBIN * sizeof(uint32_t) + 256, stream);

    kHist      <<<NIMG * BPI, 256, 0, stream>>>(p, ghist);
    kSelect    <<<NGRP,       256, 0, stream>>>(ghist, thr);
    kCompact   <<<NIMG * BPI, 256, 0, stream>>>(p, thr, cand_cnt, cand_pk);
    kRankDecode<<<NGRP,       256, 0, stream>>>(p, cand_cnt, cand_pk, cand_box, cand_score);
    kIou       <<<NGRP * 16,  256, 0, stream>>>(cand_box, tri, diag);
    kScan      <<<NGRP,       256, 0, stream>>>(cand_score, tri, diag, kept);
    kSort      <<<NIMG,      1024, 0, stream>>>(cand_score, sorted_slot);
    kOutput    <<<NIMG,      1024, 0, stream>>>(cand_box, cand_score, sorted_slot, kept,
                                                (float*)d_out);
}

// Round 4
// 381.048 us; speedup vs baseline: 4.0716x; 1.2337x over previous
//
#include <hip/hip_runtime.h>
#include <stdint.h>
#include <math.h>

#define NLVL 5
#define NIMG 4
#define NGRP (NIMG * NLVL)
#define M_TOT 4768
#define POST_K 1000
#define NEGV  (-1e9f)
#define CAP 2048
#define NBIN 4096
#define BPI 65          // data-pass blocks per image
#define TRI_W 7680      // upper-triangular word count per group (k<=1000, 16 words)

__constant__ int c_hwa[NLVL]  = {196608, 49152, 12288, 3072, 768};
__constant__ int c_k[NLVL]    = {1000, 1000, 1000, 1000, 768};
__constant__ int c_base[NLVL] = {0, 1000, 2000, 3000, 4000};
__constant__ int c_cnt[NLVL]  = {4096, 4096, 4096, 3072, 768};

struct Ptrs {
    const float* logits[NLVL];
    const float* deltas[NLVL];
    const float* anchors[NLVL];
};

__device__ __forceinline__ uint32_t flipf(float f) {
    uint32_t b = __float_as_uint(f);
    return (b & 0x80000000u) ? ~b : (b | 0x80000000u);
}
__device__ __forceinline__ float unflipf(uint32_t key) {
    uint32_t b = (key & 0x80000000u) ? (key & 0x7FFFFFFFu) : ~key;
    return __uint_as_float(b);
}

__device__ __forceinline__ void grp_decompose(int g, int& img, int& lvl, int& off, int& cnt) {
    img = g / BPI;
    int r = g % BPI;
    if (r < 48)      { lvl = 0; off = r * 4096; }
    else if (r < 60) { lvl = 1; off = (r - 48) * 4096; }
    else if (r < 63) { lvl = 2; off = (r - 60) * 4096; }
    else if (r < 64) { lvl = 3; off = 0; }
    else             { lvl = 4; off = 0; }
    cnt = c_cnt[lvl];
}

// ---------------------------------------------------------------------------
// Pass 1: 4096-bin histogram of top-12 key bits, per (img,lvl) group.
// ---------------------------------------------------------------------------
__global__ void kHist(Ptrs p, uint32_t* __restrict__ ghist) {
    __shared__ uint32_t lh[NBIN];
    int img, lvl, off, cnt;
    grp_decompose(blockIdx.x, img, lvl, off, cnt);
    const int tid = threadIdx.x;
    const float* lg = p.logits[lvl] + (size_t)img * c_hwa[lvl] + off;

    for (int b = tid; b < NBIN; b += 256) lh[b] = 0u;
    __syncthreads();

    const int nvec = cnt >> 2;
    const float4* lg4 = (const float4*)lg;
    for (int v = tid; v < nvec; v += 256) {
        float4 x = lg4[v];
        atomicAdd(&lh[flipf(x.x) >> 20], 1u);
        atomicAdd(&lh[flipf(x.y) >> 20], 1u);
        atomicAdd(&lh[flipf(x.z) >> 20], 1u);
        atomicAdd(&lh[flipf(x.w) >> 20], 1u);
    }
    __syncthreads();

    uint32_t* gh = ghist + (size_t)(img * NLVL + lvl) * NBIN;
    for (int b = tid; b < NBIN; b += 256)
        if (lh[b]) atomicAdd(&gh[b], lh[b]);
}

// ---------------------------------------------------------------------------
// Pass 2: per group, find threshold bucket d: count(>d) < k <= count(>=d).
// ---------------------------------------------------------------------------
__global__ void kSelect(const uint32_t* __restrict__ ghist, uint32_t* __restrict__ thr) {
    const int grp = blockIdx.x;
    const int k = c_k[grp % NLVL];
    __shared__ uint32_t h[NBIN];
    __shared__ uint32_t ss[256];
    const int tid = threadIdx.x;
    const uint32_t* gh = ghist + (size_t)grp * NBIN;

    for (int b = tid; b < NBIN; b += 256) h[b] = gh[b];
    __syncthreads();

    uint32_t s = 0;
    #pragma unroll
    for (int b = 0; b < 16; ++b) s += h[tid * 16 + b];
    ss[tid] = s;
    __syncthreads();
    for (int off = 1; off < 256; off <<= 1) {
        uint32_t v = (tid + off < 256) ? ss[tid + off] : 0u;
        __syncthreads();
        ss[tid] += v;
        __syncthreads();
    }
    uint32_t running = (tid == 255) ? 0u : ss[tid + 1];
    for (int b = 15; b >= 0; --b) {
        uint32_t c = h[tid * 16 + b];
        running += c;
        if ((running >= (uint32_t)k) && (running - c < (uint32_t)k)) {
            thr[grp] = (uint32_t)(tid * 16 + b) << 20;
        }
    }
}

// ---------------------------------------------------------------------------
// Pass 3: compact keys >= T into per-group packed candidate list.
// ---------------------------------------------------------------------------
__global__ void kCompact(Ptrs p, const uint32_t* __restrict__ thr,
                         uint32_t* __restrict__ cand_cnt,
                         uint64_t* __restrict__ cand_pk) {
    int img, lvl, off, cnt;
    grp_decompose(blockIdx.x, img, lvl, off, cnt);
    const int grp = img * NLVL + lvl;
    const int tid = threadIdx.x;
    const float* lg = p.logits[lvl] + (size_t)img * c_hwa[lvl] + off;
    const uint32_t T = thr[grp];
    uint64_t* pk = cand_pk + (size_t)grp * CAP;

    const int nvec = cnt >> 2;
    const float4* lg4 = (const float4*)lg;
    for (int v = tid; v < nvec; v += 256) {
        float4 x = lg4[v];
        float xs[4] = {x.x, x.y, x.z, x.w};
        #pragma unroll
        for (int c = 0; c < 4; ++c) {
            uint32_t key = flipf(xs[c]);
            if (key >= T) {
                uint32_t pos = atomicAdd(&cand_cnt[grp], 1u);
                if (pos < CAP) {
                    uint32_t eidx = (uint32_t)(off + 4 * v + c);
                    pk[pos] = ((uint64_t)key << 32) | (uint32_t)(~eidx);
                }
            }
        }
    }
}

// ---------------------------------------------------------------------------
// Pass 4: exact rank among candidates; decode boxes for rank < k.
// ---------------------------------------------------------------------------
__global__ void kRankDecode(Ptrs p, const uint32_t* __restrict__ cand_cnt,
                            const uint64_t* __restrict__ cand_pk,
                            float* __restrict__ cand_box,
                            float* __restrict__ cand_score) {
    #pragma clang fp contract(off)
    const int grp = blockIdx.x;
    const int img = grp / NLVL;
    const int lvl = grp % NLVL;
    const int n    = c_hwa[lvl];
    const int k    = c_k[lvl];
    const int base = c_base[lvl];
    const int tid = threadIdx.x;

    __shared__ uint64_t K[CAP];
    const int cc = (int)min(cand_cnt[grp], (uint32_t)CAP);
    const uint64_t* pk = cand_pk + (size_t)grp * CAP;
    for (int i = tid; i < cc; i += 256) K[i] = pk[i];
    __syncthreads();

    uint64_t myK[8];
    int myR[8];
    #pragma unroll
    for (int q = 0; q < 8; ++q) {
        int c = tid + q * 256;
        myK[q] = (c < cc) ? K[c] : 0ULL;
        myR[q] = 0;
    }
    for (int j = 0; j < cc; ++j) {
        uint64_t Kj = K[j];
        #pragma unroll
        for (int q = 0; q < 8; ++q) myR[q] += (int)(Kj > myK[q]);
    }

    #pragma unroll
    for (int q = 0; q < 8; ++q) {
        int c = tid + q * 256;
        if (c >= cc) continue;
        int r = myR[q];
        if (r >= k) continue;
        uint32_t key = (uint32_t)(myK[q] >> 32);
        uint32_t ic  = ~(uint32_t)(myK[q] & 0xFFFFFFFFu);
        const float* an = p.anchors[lvl] + (size_t)ic * 4;
        const float* dl = p.deltas[lvl] + ((size_t)img * n + ic) * 4;
        float a0 = an[0], a1 = an[1], a2 = an[2], a3 = an[3];
        float wa = a2 - a0, ha = a3 - a1;
        float cxa = a0 + 0.5f * wa, cya = a1 + 0.5f * ha;
        float dx = dl[0], dy = dl[1], dw = dl[2], dh = dl[3];
        const float SC = (float)4.135166556742356;  // log(1000/16)
        dw = fminf(dw, SC);
        dh = fminf(dh, SC);
        float cx = dx * wa + cxa, cy = dy * ha + cya;
        float w = wa * expf(dw), h = ha * expf(dh);
        float x1 = cx - 0.5f * w, y1 = cy - 0.5f * h;
        float x2 = cx + 0.5f * w, y2 = cy + 0.5f * h;
        x1 = fminf(fmaxf(x1, 0.0f), 1024.0f);
        y1 = fminf(fmaxf(y1, 0.0f), 1024.0f);
        x2 = fminf(fmaxf(x2, 0.0f), 1024.0f);
        y2 = fminf(fmaxf(y2, 0.0f), 1024.0f);
        float bw = x2 - x1, bh = y2 - y1;
        float score = (bw > 0.0f && bh > 0.0f) ? unflipf(key) : NEGV;
        const int slot = base + r;
        float* ob = cand_box + ((size_t)img * M_TOT + slot) * 4;
        ob[0] = x1; ob[1] = y1; ob[2] = x2; ob[3] = y2;
        cand_score[(size_t)img * M_TOT + slot] = score;
    }
}

// ---------------------------------------------------------------------------
// NMS phase 1: suppression bit-matrix, upper-triangular by 64-wide word.
// ---------------------------------------------------------------------------
__global__ void kIou(const float* __restrict__ cand_box,
                     uint64_t* __restrict__ tri, uint64_t* __restrict__ diag) {
    #pragma clang fp contract(off)
    const int blk = blockIdx.x;      // grp*16 + w
    const int grp = blk >> 4;
    const int w   = blk & 15;
    const int img = grp / NLVL;
    const int lvl = grp % NLVL;
    const int k    = c_k[lvl];
    const int base = c_base[lvl];
    if (64 * w >= k) return;
    const int jn = min(64, k - 64 * w);
    const int R  = min(64 * (w + 1), k);
    const float lo = (float)lvl * 2048.0f;

    __shared__ float jx1[64], jy1[64], jx2[64], jy2[64], jar[64];
    const int tid = threadIdx.x;
    if (tid < jn) {
        const float4 b = *(const float4*)(cand_box + ((size_t)img * M_TOT + base + 64 * w + tid) * 4);
        float x1 = b.x + lo, y1 = b.y + lo, x2 = b.z + lo, y2 = b.w + lo;
        jx1[tid] = x1; jy1[tid] = y1; jx2[tid] = x2; jy2[tid] = y2;
        jar[tid] = (x2 - x1) * (y2 - y1);
    }
    __syncthreads();

    for (int r = tid; r < R; r += 256) {
        const float4 b = *(const float4*)(cand_box + ((size_t)img * M_TOT + base + r) * 4);
        float rx1 = b.x + lo, ry1 = b.y + lo, rx2 = b.z + lo, ry2 = b.w + lo;
        float ra = (rx2 - rx1) * (ry2 - ry1);
        uint64_t bits = 0ull;
        #pragma unroll 8
        for (int jj = 0; jj < jn; ++jj) {
            int j = 64 * w + jj;
            if (j > r) {
                float ltx = fmaxf(rx1, jx1[jj]);
                float lty = fmaxf(ry1, jy1[jj]);
                float rbx = fminf(rx2, jx2[jj]);
                float rby = fminf(ry2, jy2[jj]);
                float wx = fmaxf(rbx - ltx, 0.0f);
                float wy = fmaxf(rby - lty, 0.0f);
                float inter = wx * wy;
                float denom = ((ra + jar[jj]) - inter) + 1e-9f;
                if (inter / denom > 0.7f) bits |= (1ull << jj);
            }
        }
        const int q = r >> 6;
        if (q == w) {
            diag[(size_t)grp * 1024 + r] = bits;
        } else {
            const int m = r & 63;
            const int tb = 15 * r - 32 * q * (q - 1) - m * q;  // tri_base(r)
            tri[(size_t)grp * TRI_W + tb + (w - q - 1)] = bits;
        }
    }
}

// ---------------------------------------------------------------------------
// NMS phase 2: greedy scan, one wave per group, no barriers in the loop.
// ---------------------------------------------------------------------------
__global__ void kScan(const float* __restrict__ cand_score,
                      const uint64_t* __restrict__ tri,
                      const uint64_t* __restrict__ diag,
                      uint32_t* __restrict__ kept) {
    const int grp = blockIdx.x;
    const int img = grp / NLVL;
    const int lvl = grp % NLVL;
    const int k    = c_k[lvl];
    const int base = c_base[lvl];
    __shared__ uint64_t tl[TRI_W];
    const int tid = threadIdx.x;
    const uint64_t* tg = tri + (size_t)grp * TRI_W;
    for (int i = tid; i < TRI_W; i += 256) tl[i] = tg[i];
    __syncthreads();
    if (tid >= 64) return;           // wave 0 does the scan; no barriers follow
    const int lane = tid;

    uint64_t darr[16];
    #pragma unroll
    for (int s = 0; s < 16; ++s)
        darr[s] = (64 * s + lane < k) ? diag[(size_t)grp * 1024 + 64 * s + lane] : 0ull;

    float sc[16];
    #pragma unroll
    for (int s = 0; s < 16; ++s) {
        int r = 64 * s + lane;
        sc[s] = (r < k) ? cand_score[(size_t)img * M_TOT + base + r] : NEGV;
    }
    uint64_t inv[16];
    #pragma unroll
    for (int s = 0; s < 16; ++s)
        inv[s] = (uint64_t)__ballot(sc[s] <= -5e8f);

    uint64_t keep_w[16];
    #pragma unroll
    for (int s = 0; s < 16; ++s) keep_w[s] = 0ull;

    #pragma unroll
    for (int q = 0; q < 16; ++q) {
        if (64 * q < k) {
            uint64_t v = 0ull;
            #pragma unroll
            for (int s = 0; s < q; ++s) {
                if ((keep_w[s] >> lane) & 1ull) {
                    const int rp = 64 * s + lane;
                    const int tb = 15 * rp - 32 * s * (s - 1) - lane * s;
                    v |= tl[tb + (q - s - 1)];
                }
            }
            #pragma unroll
            for (int off2 = 32; off2 >= 1; off2 >>= 1)
                v |= (uint64_t)__shfl_xor((unsigned long long)v, off2, 64);
            const uint64_t cur0 = inv[q] | v;
            uint32_t clo = __builtin_amdgcn_readfirstlane((uint32_t)cur0);
            uint32_t chi = __builtin_amdgcn_readfirstlane((uint32_t)(cur0 >> 32));
            uint64_t scur = ((uint64_t)chi << 32) | (uint64_t)clo;
            uint64_t kw = 0ull;
            const int mm = min(64, k - 64 * q);
            const uint32_t dlo = (uint32_t)darr[q];
            const uint32_t dhi = (uint32_t)(darr[q] >> 32);
            for (int m = 0; m < mm; ++m) {
                if (!((scur >> m) & 1ull)) {
                    uint64_t dg = ((uint64_t)(uint32_t)__builtin_amdgcn_readlane((int)dhi, m) << 32)
                                |  (uint64_t)(uint32_t)__builtin_amdgcn_readlane((int)dlo, m);
                    scur |= dg;
                    kw |= (1ull << m);
                }
            }
            keep_w[q] = kw;
        }
    }

    #pragma unroll
    for (int s = 0; s < 16; ++s) {
        int r = 64 * s + lane;
        if (r < k)
            kept[(size_t)img * M_TOT + base + r] = (uint32_t)((keep_w[s] >> lane) & 1ull);
    }
}

// ---------------------------------------------------------------------------
// Merge-rank + stable partition + output, one block (1024 thr) per image.
// Global order (score desc, slot asc) == 5-way merge of per-level sorted
// valid lists, then all invalid (score==NEG) in slot order. Position of each
// element computed by binary search; then prefix-scan partition by kept flag.
// ---------------------------------------------------------------------------
__device__ __forceinline__ int bs_count_ge(const uint32_t* a, int n, uint32_t x) {
    // a non-increasing; count of elements with a[i] >= x
    int lo = 0, hi = n;
    while (lo < hi) { int mid = (lo + hi) >> 1; if (a[mid] >= x) lo = mid + 1; else hi = mid; }
    return lo;
}
__device__ __forceinline__ int bs_count_gt(const uint32_t* a, int n, uint32_t x) {
    // a non-increasing; count of elements with a[i] > x
    int lo = 0, hi = n;
    while (lo < hi) { int mid = (lo + hi) >> 1; if (a[mid] > x) lo = mid + 1; else hi = mid; }
    return lo;
}

__global__ void kMergeOut(const float* __restrict__ cand_box,
                          const float* __restrict__ cand_score,
                          const uint32_t* __restrict__ kept,
                          float* __restrict__ out) {
    const int img = blockIdx.x;
    const int tid = threadIdx.x;   // 1024
    const int lane = tid & 63, wave = tid >> 6;

    __shared__ uint32_t vkey[NLVL * 1024];  // compacted valid keys, desc
    __shared__ uint32_t ord[M_TOT];         // merged order: slot | kept<<31
    __shared__ int ssum[1024];
    __shared__ uint32_t wsum[NLVL][16];

    // ---- Phase 1: per-level valid ballot-scan ----
    uint32_t mykey[NLVL];
    int myvalid[NLVL], mylower[NLVL];
    #pragma unroll
    for (int L = 0; L < NLVL; ++L) {
        const int kL = c_k[L];
        const bool act = tid < kL;
        float s = act ? cand_score[(size_t)img * M_TOT + c_base[L] + tid] : NEGV;
        bool valid = act && (s > -5e8f);
        uint64_t mask = __ballot(valid);
        mylower[L] = (int)__popcll(mask & ((1ull << lane) - 1ull));
        if (lane == 0) wsum[L][wave] = (uint32_t)__popcll(mask);
        mykey[L] = flipf(s);
        myvalid[L] = valid ? 1 : 0;
    }
    __syncthreads();

    int nv[NLVL], myvpre[NLVL];
    #pragma unroll
    for (int L = 0; L < NLVL; ++L) {
        int pw = 0, tot = 0;
        #pragma unroll
        for (int w = 0; w < 16; ++w) {
            if (w < wave) pw += (int)wsum[L][w];
            tot += (int)wsum[L][w];
        }
        nv[L] = tot;
        myvpre[L] = pw + mylower[L];
        if (tid < c_k[L] && myvalid[L])
            vkey[L * 1024 + myvpre[L]] = mykey[L];
    }
    int totalValid = 0;
    #pragma unroll
    for (int L = 0; L < NLVL; ++L) totalValid += nv[L];
    __syncthreads();

    // ---- Phase 2: merge-rank each element, scatter into ord ----
    int invBase = totalValid;
    #pragma unroll
    for (int L = 0; L < NLVL; ++L) {
        const int kL = c_k[L];
        if (tid < kL) {
            const int slot = c_base[L] + tid;
            if (myvalid[L]) {
                const uint32_t x = mykey[L];
                int pos = myvpre[L];
                #pragma unroll
                for (int Lp = 0; Lp < NLVL; ++Lp) {
                    if (Lp == L) continue;
                    pos += (Lp < L) ? bs_count_ge(&vkey[Lp * 1024], nv[Lp], x)
                                    : bs_count_gt(&vkey[Lp * 1024], nv[Lp], x);
                }
                const uint32_t kp = kept[(size_t)img * M_TOT + slot];
                ord[pos] = (uint32_t)slot | (kp << 31);
            } else {
                const int inv_idx = tid - myvpre[L];
                ord[invBase + inv_idx] = (uint32_t)slot;  // kept=0
            }
        }
        invBase += (c_k[L] - nv[L]);
    }
    __syncthreads();

    // ---- Phase 3: stable partition by kept flag, write output ----
    const int PT = 5;
    const int pos0 = tid * PT;
    int flags[PT];
    uint32_t slots[PT];
    int lsum = 0;
    #pragma unroll
    for (int q = 0; q < PT; ++q) {
        int pp = pos0 + q;
        int kf = 0; uint32_t sl = 0;
        if (pp < M_TOT) {
            uint32_t o = ord[pp];
            sl = o & 0x7FFFFFFFu;
            kf = (int)(o >> 31);
        }
        flags[q] = kf; slots[q] = sl; lsum += kf;
    }
    ssum[tid] = lsum;
    __syncthreads();
    for (int off = 1; off < 1024; off <<= 1) {
        int v = (tid >= off) ? ssum[tid - off] : 0;
        __syncthreads();
        ssum[tid] += v;
        __syncthreads();
    }
    const int excl = ssum[tid] - lsum;
    const int total = ssum[1023];

    int run = 0;
    #pragma unroll
    for (int q = 0; q < PT; ++q) {
        int pp = pos0 + q;
        if (pp >= M_TOT) break;
        int kf = flags[q];
        int kbefore = excl + run;
        run += kf;
        int oidx = kf ? kbefore : (total + (pp - kbefore));
        if (oidx < POST_K) {
            uint32_t sl = slots[q];
            const float4 b = *(const float4*)(cand_box + ((size_t)img * M_TOT + sl) * 4);
            float* ob = out + ((size_t)img * POST_K + oidx) * 4;
            ob[0] = b.x; ob[1] = b.y; ob[2] = b.z; ob[3] = b.w;
            out[NIMG * POST_K * 4 + (size_t)img * POST_K + oidx] =
                kf ? cand_score[(size_t)img * M_TOT + sl] : NEGV;
        }
    }
}

extern "C" void kernel_launch(void* const* d_in, const int* in_sizes, int n_in,
                              void* d_out, int out_size, void* d_ws, size_t ws_size,
                              hipStream_t stream) {
    Ptrs p;
    for (int l = 0; l < NLVL; ++l) {
        p.logits[l]  = (const float*)d_in[3 * l + 0];
        p.deltas[l]  = (const float*)d_in[3 * l + 1];
        p.anchors[l] = (const float*)d_in[3 * l + 2];
    }

    // workspace layout (~2.6 MB)
    char* w = (char*)d_ws;
    float* cand_box   = (float*)w;        w += (size_t)NIMG * M_TOT * 4 * sizeof(float);
    float* cand_score = (float*)w;        w += (size_t)NIMG * M_TOT * sizeof(float);
    uint32_t* kept        = (uint32_t*)w; w += (size_t)NIMG * M_TOT * sizeof(uint32_t);
    uint32_t* ghist       = (uint32_t*)w; w += (size_t)NGRP * NBIN * sizeof(uint32_t);
    uint32_t* cand_cnt    = (uint32_t*)w; w += 128;   // 20 u32 counters (padded)
    uint32_t* thr         = (uint32_t*)w; w += 128;   // 20 u32 thresholds (padded)
    uint64_t* cand_pk     = (uint64_t*)w; w += (size_t)NGRP * CAP * sizeof(uint64_t);
    uint64_t* tri         = (uint64_t*)w; w += (size_t)NGRP * TRI_W * sizeof(uint64_t);
    uint64_t* diag        = (uint64_t*)w; w += (size_t)NGRP * 1024 * sizeof(uint64_t);

    // zero ghist + cand_cnt + thr (one contiguous region)
    hipMemsetAsync(ghist, 0, (size_t)NGRP * NBIN * sizeof(uint32_t) + 256, stream);

    kHist      <<<NIMG * BPI, 256, 0, stream>>>(p, ghist);
    kSelect    <<<NGRP,       256, 0, stream>>>(ghist, thr);
    kCompact   <<<NIMG * BPI, 256, 0, stream>>>(p, thr, cand_cnt, cand_pk);
    kRankDecode<<<NGRP,       256, 0, stream>>>(p, cand_cnt, cand_pk, cand_box, cand_score);
    kIou       <<<NGRP * 16,  256, 0, stream>>>(cand_box, tri, diag);
    kScan      <<<NGRP,       256, 0, stream>>>(cand_score, tri, diag, kept);
    kMergeOut  <<<NIMG,      1024, 0, stream>>>(cand_box, cand_score, kept, (float*)d_out);
}

// Round 5
// 326.670 us; speedup vs baseline: 4.7494x; 1.1665x over previous
//
#include <hip/hip_runtime.h>
#include <stdint.h>
#include <math.h>

#define NLVL 5
#define NIMG 4
#define NGRP (NIMG * NLVL)
#define M_TOT 4768
#define POST_K 1000
#define NEGV  (-1e9f)
#define CAP 2048
#define NBIN 4096
#define BPI 65          // data-pass blocks per image
#define TRI_W 7680      // upper-triangular word count per group (k<=1000, 16 words)
#define CNT_STRIDE 32   // cand_cnt counters spread one per 128B line

__constant__ int c_hwa[NLVL]  = {196608, 49152, 12288, 3072, 768};
__constant__ int c_k[NLVL]    = {1000, 1000, 1000, 1000, 768};
__constant__ int c_base[NLVL] = {0, 1000, 2000, 3000, 4000};
__constant__ int c_cnt[NLVL]  = {4096, 4096, 4096, 3072, 768};
// Speculative per-level key thresholds (flipf of score): expected candidate
// count ~1550 per group for N(0,1) logits; validated by kCheck, exact
// fallback path runs for any group where count \notin [k, CAP].
__constant__ uint32_t c_T0[NLVL] = {0xC019999Au, 0xBFECCCCDu, 0xBF933333u, 0x80000000u, 0x00000000u};

struct Ptrs {
    const float* logits[NLVL];
    const float* deltas[NLVL];
    const float* anchors[NLVL];
};

__device__ __forceinline__ uint32_t flipf(float f) {
    uint32_t b = __float_as_uint(f);
    return (b & 0x80000000u) ? ~b : (b | 0x80000000u);
}
__device__ __forceinline__ float unflipf(uint32_t key) {
    uint32_t b = (key & 0x80000000u) ? (key & 0x7FFFFFFFu) : ~key;
    return __uint_as_float(b);
}

__device__ __forceinline__ void grp_decompose(int g, int& img, int& lvl, int& off, int& cnt) {
    img = g / BPI;
    int r = g % BPI;
    if (r < 48)      { lvl = 0; off = r * 4096; }
    else if (r < 60) { lvl = 1; off = (r - 48) * 4096; }
    else if (r < 63) { lvl = 2; off = (r - 60) * 4096; }
    else if (r < 64) { lvl = 3; off = 0; }
    else             { lvl = 4; off = 0; }
    cnt = c_cnt[lvl];
}

// ---------------------------------------------------------------------------
// Speculative single-pass compaction: keys >= c_T0[lvl] staged in LDS, one
// global atomic per block. Exactness guaranteed downstream by kRankDecode
// as long as count(>=T0) ∈ [k, CAP] — validated by kCheck, else fallback.
// ---------------------------------------------------------------------------
__global__ void kCompactSpec(Ptrs p, uint32_t* __restrict__ cand_cnt,
                             uint64_t* __restrict__ cand_pk) {
    int img, lvl, off, cnt;
    grp_decompose(blockIdx.x, img, lvl, off, cnt);
    const int grp = img * NLVL + lvl;
    const int tid = threadIdx.x;
    const float* lg = p.logits[lvl] + (size_t)img * c_hwa[lvl] + off;
    const uint32_t T = c_T0[lvl];
    uint64_t* pk = cand_pk + (size_t)grp * CAP;

    __shared__ uint32_t scnt, sbase;
    __shared__ uint64_t sbuf[4096];
    if (tid == 0) scnt = 0u;
    __syncthreads();

    const int nvec = cnt >> 2;
    const float4* lg4 = (const float4*)lg;
    for (int v = tid; v < nvec; v += 256) {
        float4 x = lg4[v];
        float xs[4] = {x.x, x.y, x.z, x.w};
        #pragma unroll
        for (int c = 0; c < 4; ++c) {
            uint32_t key = flipf(xs[c]);
            if (key >= T) {
                uint32_t pos = atomicAdd(&scnt, 1u);
                uint32_t eidx = (uint32_t)(off + 4 * v + c);
                sbuf[pos] = ((uint64_t)key << 32) | (uint32_t)(~eidx);
            }
        }
    }
    __syncthreads();
    if (tid == 0) sbase = atomicAdd(&cand_cnt[grp * CNT_STRIDE], scnt);
    __syncthreads();
    const uint32_t n = scnt, b0 = sbase;
    for (uint32_t i = tid; i < n; i += 256) {
        uint32_t g = b0 + i;
        if (g < CAP) pk[g] = sbuf[i];
    }
}

// ---------------------------------------------------------------------------
// Validate speculation; flag groups needing the exact fallback path.
// ---------------------------------------------------------------------------
__global__ void kCheck(uint32_t* __restrict__ cand_cnt, uint32_t* __restrict__ need_fb) {
    const int g = threadIdx.x;
    if (g < NGRP) {
        uint32_t c = cand_cnt[g * CNT_STRIDE];
        uint32_t k = (uint32_t)c_k[g % NLVL];
        uint32_t bad = (c < k || c > CAP) ? 1u : 0u;
        need_fb[g] = bad;
        if (bad) cand_cnt[g * CNT_STRIDE] = 0u;   // reset for exact recompaction
    }
}

// ---------------------------------------------------------------------------
// Fallback pass 1: 4096-bin histogram (only for flagged groups).
// ---------------------------------------------------------------------------
__global__ void kHistFB(Ptrs p, const uint32_t* __restrict__ need_fb,
                        uint32_t* __restrict__ ghist) {
    __shared__ uint32_t lh[NBIN];
    int img, lvl, off, cnt;
    grp_decompose(blockIdx.x, img, lvl, off, cnt);
    const int grp = img * NLVL + lvl;
    if (!need_fb[grp]) return;
    const int tid = threadIdx.x;
    const float* lg = p.logits[lvl] + (size_t)img * c_hwa[lvl] + off;

    for (int b = tid; b < NBIN; b += 256) lh[b] = 0u;
    __syncthreads();

    const int nvec = cnt >> 2;
    const float4* lg4 = (const float4*)lg;
    for (int v = tid; v < nvec; v += 256) {
        float4 x = lg4[v];
        atomicAdd(&lh[flipf(x.x) >> 20], 1u);
        atomicAdd(&lh[flipf(x.y) >> 20], 1u);
        atomicAdd(&lh[flipf(x.z) >> 20], 1u);
        atomicAdd(&lh[flipf(x.w) >> 20], 1u);
    }
    __syncthreads();

    uint32_t* gh = ghist + (size_t)grp * NBIN;
    for (int b = tid; b < NBIN; b += 256)
        if (lh[b]) atomicAdd(&gh[b], lh[b]);
}

// ---------------------------------------------------------------------------
// Fallback pass 2: exact threshold bucket from histogram.
// ---------------------------------------------------------------------------
__global__ void kSelectFB(const uint32_t* __restrict__ need_fb,
                          const uint32_t* __restrict__ ghist, uint32_t* __restrict__ thr) {
    const int grp = blockIdx.x;
    if (!need_fb[grp]) return;
    const int k = c_k[grp % NLVL];
    __shared__ uint32_t h[NBIN];
    __shared__ uint32_t ss[256];
    const int tid = threadIdx.x;
    const uint32_t* gh = ghist + (size_t)grp * NBIN;

    for (int b = tid; b < NBIN; b += 256) h[b] = gh[b];
    __syncthreads();

    uint32_t s = 0;
    #pragma unroll
    for (int b = 0; b < 16; ++b) s += h[tid * 16 + b];
    ss[tid] = s;
    __syncthreads();
    for (int off = 1; off < 256; off <<= 1) {
        uint32_t v = (tid + off < 256) ? ss[tid + off] : 0u;
        __syncthreads();
        ss[tid] += v;
        __syncthreads();
    }
    uint32_t running = (tid == 255) ? 0u : ss[tid + 1];
    for (int b = 15; b >= 0; --b) {
        uint32_t c = h[tid * 16 + b];
        running += c;
        if ((running >= (uint32_t)k) && (running - c < (uint32_t)k)) {
            thr[grp] = (uint32_t)(tid * 16 + b) << 20;
        }
    }
}

// ---------------------------------------------------------------------------
// Fallback pass 3: exact compaction for flagged groups (block-staged).
// ---------------------------------------------------------------------------
__global__ void kCompactFB(Ptrs p, const uint32_t* __restrict__ need_fb,
                           const uint32_t* __restrict__ thr,
                           uint32_t* __restrict__ cand_cnt,
                           uint64_t* __restrict__ cand_pk) {
    int img, lvl, off, cnt;
    grp_decompose(blockIdx.x, img, lvl, off, cnt);
    const int grp = img * NLVL + lvl;
    if (!need_fb[grp]) return;
    const int tid = threadIdx.x;
    const float* lg = p.logits[lvl] + (size_t)img * c_hwa[lvl] + off;
    const uint32_t T = thr[grp];
    uint64_t* pk = cand_pk + (size_t)grp * CAP;

    __shared__ uint32_t scnt, sbase;
    __shared__ uint64_t sbuf[4096];
    if (tid == 0) scnt = 0u;
    __syncthreads();

    const int nvec = cnt >> 2;
    const float4* lg4 = (const float4*)lg;
    for (int v = tid; v < nvec; v += 256) {
        float4 x = lg4[v];
        float xs[4] = {x.x, x.y, x.z, x.w};
        #pragma unroll
        for (int c = 0; c < 4; ++c) {
            uint32_t key = flipf(xs[c]);
            if (key >= T) {
                uint32_t pos = atomicAdd(&scnt, 1u);
                uint32_t eidx = (uint32_t)(off + 4 * v + c);
                sbuf[pos] = ((uint64_t)key << 32) | (uint32_t)(~eidx);
            }
        }
    }
    __syncthreads();
    if (tid == 0) sbase = atomicAdd(&cand_cnt[grp * CNT_STRIDE], scnt);
    __syncthreads();
    const uint32_t n = scnt, b0 = sbase;
    for (uint32_t i = tid; i < n; i += 256) {
        uint32_t g = b0 + i;
        if (g < CAP) pk[g] = sbuf[i];
    }
}

// ---------------------------------------------------------------------------
// Exact rank among candidates; decode boxes for rank < k. Bit-exact ref math.
// ---------------------------------------------------------------------------
__global__ void kRankDecode(Ptrs p, const uint32_t* __restrict__ cand_cnt,
                            const uint64_t* __restrict__ cand_pk,
                            float* __restrict__ cand_box,
                            float* __restrict__ cand_score) {
    #pragma clang fp contract(off)
    const int grp = blockIdx.x;
    const int img = grp / NLVL;
    const int lvl = grp % NLVL;
    const int n    = c_hwa[lvl];
    const int k    = c_k[lvl];
    const int base = c_base[lvl];
    const int tid = threadIdx.x;

    __shared__ uint64_t K[CAP];
    const int cc = (int)min(cand_cnt[grp * CNT_STRIDE], (uint32_t)CAP);
    const uint64_t* pk = cand_pk + (size_t)grp * CAP;
    for (int i = tid; i < cc; i += 256) K[i] = pk[i];
    __syncthreads();

    uint64_t myK[8];
    int myR[8];
    #pragma unroll
    for (int q = 0; q < 8; ++q) {
        int c = tid + q * 256;
        myK[q] = (c < cc) ? K[c] : 0ULL;
        myR[q] = 0;
    }
    for (int j = 0; j < cc; ++j) {
        uint64_t Kj = K[j];
        #pragma unroll
        for (int q = 0; q < 8; ++q) myR[q] += (int)(Kj > myK[q]);
    }

    #pragma unroll
    for (int q = 0; q < 8; ++q) {
        int c = tid + q * 256;
        if (c >= cc) continue;
        int r = myR[q];
        if (r >= k) continue;
        uint32_t key = (uint32_t)(myK[q] >> 32);
        uint32_t ic  = ~(uint32_t)(myK[q] & 0xFFFFFFFFu);
        const float* an = p.anchors[lvl] + (size_t)ic * 4;
        const float* dl = p.deltas[lvl] + ((size_t)img * n + ic) * 4;
        float a0 = an[0], a1 = an[1], a2 = an[2], a3 = an[3];
        float wa = a2 - a0, ha = a3 - a1;
        float cxa = a0 + 0.5f * wa, cya = a1 + 0.5f * ha;
        float dx = dl[0], dy = dl[1], dw = dl[2], dh = dl[3];
        const float SC = (float)4.135166556742356;  // log(1000/16)
        dw = fminf(dw, SC);
        dh = fminf(dh, SC);
        float cx = dx * wa + cxa, cy = dy * ha + cya;
        float w = wa * expf(dw), h = ha * expf(dh);
        float x1 = cx - 0.5f * w, y1 = cy - 0.5f * h;
        float x2 = cx + 0.5f * w, y2 = cy + 0.5f * h;
        x1 = fminf(fmaxf(x1, 0.0f), 1024.0f);
        y1 = fminf(fmaxf(y1, 0.0f), 1024.0f);
        x2 = fminf(fmaxf(x2, 0.0f), 1024.0f);
        y2 = fminf(fmaxf(y2, 0.0f), 1024.0f);
        float bw = x2 - x1, bh = y2 - y1;
        float score = (bw > 0.0f && bh > 0.0f) ? unflipf(key) : NEGV;
        const int slot = base + r;
        float* ob = cand_box + ((size_t)img * M_TOT + slot) * 4;
        ob[0] = x1; ob[1] = y1; ob[2] = x2; ob[3] = y2;
        cand_score[(size_t)img * M_TOT + slot] = score;
    }
}

// ---------------------------------------------------------------------------
// NMS phase 1: suppression bit-matrix, upper-triangular by 64-wide word.
// ---------------------------------------------------------------------------
__global__ void kIou(const float* __restrict__ cand_box,
                     uint64_t* __restrict__ tri, uint64_t* __restrict__ diag) {
    #pragma clang fp contract(off)
    const int blk = blockIdx.x;      // grp*16 + w
    const int grp = blk >> 4;
    const int w   = blk & 15;
    const int img = grp / NLVL;
    const int lvl = grp % NLVL;
    const int k    = c_k[lvl];
    const int base = c_base[lvl];
    if (64 * w >= k) return;
    const int jn = min(64, k - 64 * w);
    const int R  = min(64 * (w + 1), k);
    const float lo = (float)lvl * 2048.0f;

    __shared__ float jx1[64], jy1[64], jx2[64], jy2[64], jar[64];
    const int tid = threadIdx.x;
    if (tid < jn) {
        const float4 b = *(const float4*)(cand_box + ((size_t)img * M_TOT + base + 64 * w + tid) * 4);
        float x1 = b.x + lo, y1 = b.y + lo, x2 = b.z + lo, y2 = b.w + lo;
        jx1[tid] = x1; jy1[tid] = y1; jx2[tid] = x2; jy2[tid] = y2;
        jar[tid] = (x2 - x1) * (y2 - y1);
    }
    __syncthreads();

    for (int r = tid; r < R; r += 256) {
        const float4 b = *(const float4*)(cand_box + ((size_t)img * M_TOT + base + r) * 4);
        float rx1 = b.x + lo, ry1 = b.y + lo, rx2 = b.z + lo, ry2 = b.w + lo;
        float ra = (rx2 - rx1) * (ry2 - ry1);
        uint64_t bits = 0ull;
        #pragma unroll 8
        for (int jj = 0; jj < jn; ++jj) {
            int j = 64 * w + jj;
            if (j > r) {
                float ltx = fmaxf(rx1, jx1[jj]);
                float lty = fmaxf(ry1, jy1[jj]);
                float rbx = fminf(rx2, jx2[jj]);
                float rby = fminf(ry2, jy2[jj]);
                float wx = fmaxf(rbx - ltx, 0.0f);
                float wy = fmaxf(rby - lty, 0.0f);
                float inter = wx * wy;
                float denom = ((ra + jar[jj]) - inter) + 1e-9f;
                if (inter / denom > 0.7f) bits |= (1ull << jj);
            }
        }
        const int q = r >> 6;
        if (q == w) {
            diag[(size_t)grp * 1024 + r] = bits;
        } else {
            const int m = r & 63;
            const int tb = 15 * r - 32 * q * (q - 1) - m * q;  // tri_base(r)
            tri[(size_t)grp * TRI_W + tb + (w - q - 1)] = bits;
        }
    }
}

// ---------------------------------------------------------------------------
// NMS phase 2: greedy scan, one wave per group, no barriers in the loop.
// ---------------------------------------------------------------------------
__global__ void kScan(const float* __restrict__ cand_score,
                      const uint64_t* __restrict__ tri,
                      const uint64_t* __restrict__ diag,
                      uint32_t* __restrict__ kept) {
    const int grp = blockIdx.x;
    const int img = grp / NLVL;
    const int lvl = grp % NLVL;
    const int k    = c_k[lvl];
    const int base = c_base[lvl];
    __shared__ uint64_t tl[TRI_W];
    const int tid = threadIdx.x;
    const uint64_t* tg = tri + (size_t)grp * TRI_W;
    for (int i = tid; i < TRI_W; i += 256) tl[i] = tg[i];
    __syncthreads();
    if (tid >= 64) return;           // wave 0 does the scan; no barriers follow
    const int lane = tid;

    uint64_t darr[16];
    #pragma unroll
    for (int s = 0; s < 16; ++s)
        darr[s] = (64 * s + lane < k) ? diag[(size_t)grp * 1024 + 64 * s + lane] : 0ull;

    float sc[16];
    #pragma unroll
    for (int s = 0; s < 16; ++s) {
        int r = 64 * s + lane;
        sc[s] = (r < k) ? cand_score[(size_t)img * M_TOT + base + r] : NEGV;
    }
    uint64_t inv[16];
    #pragma unroll
    for (int s = 0; s < 16; ++s)
        inv[s] = (uint64_t)__ballot(sc[s] <= -5e8f);

    uint64_t keep_w[16];
    #pragma unroll
    for (int s = 0; s < 16; ++s) keep_w[s] = 0ull;

    #pragma unroll
    for (int q = 0; q < 16; ++q) {
        if (64 * q < k) {
            uint64_t v = 0ull;
            #pragma unroll
            for (int s = 0; s < q; ++s) {
                if ((keep_w[s] >> lane) & 1ull) {
                    const int rp = 64 * s + lane;
                    const int tb = 15 * rp - 32 * s * (s - 1) - lane * s;
                    v |= tl[tb + (q - s - 1)];
                }
            }
            #pragma unroll
            for (int off2 = 32; off2 >= 1; off2 >>= 1)
                v |= (uint64_t)__shfl_xor((unsigned long long)v, off2, 64);
            const uint64_t cur0 = inv[q] | v;
            uint32_t clo = __builtin_amdgcn_readfirstlane((uint32_t)cur0);
            uint32_t chi = __builtin_amdgcn_readfirstlane((uint32_t)(cur0 >> 32));
            uint64_t scur = ((uint64_t)chi << 32) | (uint64_t)clo;
            uint64_t kw = 0ull;
            const int mm = min(64, k - 64 * q);
            const uint32_t dlo = (uint32_t)darr[q];
            const uint32_t dhi = (uint32_t)(darr[q] >> 32);
            for (int m = 0; m < mm; ++m) {
                if (!((scur >> m) & 1ull)) {
                    uint64_t dg = ((uint64_t)(uint32_t)__builtin_amdgcn_readlane((int)dhi, m) << 32)
                                |  (uint64_t)(uint32_t)__builtin_amdgcn_readlane((int)dlo, m);
                    scur |= dg;
                    kw |= (1ull << m);
                }
            }
            keep_w[q] = kw;
        }
    }

    #pragma unroll
    for (int s = 0; s < 16; ++s) {
        int r = 64 * s + lane;
        if (r < k)
            kept[(size_t)img * M_TOT + base + r] = (uint32_t)((keep_w[s] >> lane) & 1ull);
    }
}

// ---------------------------------------------------------------------------
// Merge-rank + stable partition + output, one block (1024 thr) per image.
// ---------------------------------------------------------------------------
__device__ __forceinline__ int bs_count_ge(const uint32_t* a, int n, uint32_t x) {
    int lo = 0, hi = n;
    while (lo < hi) { int mid = (lo + hi) >> 1; if (a[mid] >= x) lo = mid + 1; else hi = mid; }
    return lo;
}
__device__ __forceinline__ int bs_count_gt(const uint32_t* a, int n, uint32_t x) {
    int lo = 0, hi = n;
    while (lo < hi) { int mid = (lo + hi) >> 1; if (a[mid] > x) lo = mid + 1; else hi = mid; }
    return lo;
}

__global__ void kMergeOut(const float* __restrict__ cand_box,
                          const float* __restrict__ cand_score,
                          const uint32_t* __restrict__ kept,
                          float* __restrict__ out) {
    const int img = blockIdx.x;
    const int tid = threadIdx.x;   // 1024
    const int lane = tid & 63, wave = tid >> 6;

    __shared__ uint32_t vkey[NLVL * 1024];  // compacted valid keys, desc
    __shared__ uint32_t ord[M_TOT];         // merged order: slot | kept<<31
    __shared__ int ssum[1024];
    __shared__ uint32_t wsum[NLVL][16];

    // ---- Phase 1: per-level valid ballot-scan ----
    uint32_t mykey[NLVL];
    int myvalid[NLVL], mylower[NLVL];
    #pragma unroll
    for (int L = 0; L < NLVL; ++L) {
        const int kL = c_k[L];
        const bool act = tid < kL;
        float s = act ? cand_score[(size_t)img * M_TOT + c_base[L] + tid] : NEGV;
        bool valid = act && (s > -5e8f);
        uint64_t mask = __ballot(valid);
        mylower[L] = (int)__popcll(mask & ((1ull << lane) - 1ull));
        if (lane == 0) wsum[L][wave] = (uint32_t)__popcll(mask);
        mykey[L] = flipf(s);
        myvalid[L] = valid ? 1 : 0;
    }
    __syncthreads();

    int nv[NLVL], myvpre[NLVL];
    #pragma unroll
    for (int L = 0; L < NLVL; ++L) {
        int pw = 0, tot = 0;
        #pragma unroll
        for (int w = 0; w < 16; ++w) {
            if (w < wave) pw += (int)wsum[L][w];
            tot += (int)wsum[L][w];
        }
        nv[L] = tot;
        myvpre[L] = pw + mylower[L];
        if (tid < c_k[L] && myvalid[L])
            vkey[L * 1024 + myvpre[L]] = mykey[L];
    }
    int totalValid = 0;
    #pragma unroll
    for (int L = 0; L < NLVL; ++L) totalValid += nv[L];
    __syncthreads();

    // ---- Phase 2: merge-rank each element, scatter into ord ----
    int invBase = totalValid;
    #pragma unroll
    for (int L = 0; L < NLVL; ++L) {
        const int kL = c_k[L];
        if (tid < kL) {
            const int slot = c_base[L] + tid;
            if (myvalid[L]) {
                const uint32_t x = mykey[L];
                int pos = myvpre[L];
                #pragma unroll
                for (int Lp = 0; Lp < NLVL; ++Lp) {
                    if (Lp == L) continue;
                    pos += (Lp < L) ? bs_count_ge(&vkey[Lp * 1024], nv[Lp], x)
                                    : bs_count_gt(&vkey[Lp * 1024], nv[Lp], x);
                }
                const uint32_t kp = kept[(size_t)img * M_TOT + slot];
                ord[pos] = (uint32_t)slot | (kp << 31);
            } else {
                const int inv_idx = tid - myvpre[L];
                ord[invBase + inv_idx] = (uint32_t)slot;  // kept=0
            }
        }
        invBase += (c_k[L] - nv[L]);
    }
    __syncthreads();

    // ---- Phase 3: stable partition by kept flag, write output ----
    const int PT = 5;
    const int pos0 = tid * PT;
    int flags[PT];
    uint32_t slots[PT];
    int lsum = 0;
    #pragma unroll
    for (int q = 0; q < PT; ++q) {
        int pp = pos0 + q;
        int kf = 0; uint32_t sl = 0;
        if (pp < M_TOT) {
            uint32_t o = ord[pp];
            sl = o & 0x7FFFFFFFu;
            kf = (int)(o >> 31);
        }
        flags[q] = kf; slots[q] = sl; lsum += kf;
    }
    ssum[tid] = lsum;
    __syncthreads();
    for (int off = 1; off < 1024; off <<= 1) {
        int v = (tid >= off) ? ssum[tid - off] : 0;
        __syncthreads();
        ssum[tid] += v;
        __syncthreads();
    }
    const int excl = ssum[tid] - lsum;
    const int total = ssum[1023];

    int run = 0;
    #pragma unroll
    for (int q = 0; q < PT; ++q) {
        int pp = pos0 + q;
        if (pp >= M_TOT) break;
        int kf = flags[q];
        int kbefore = excl + run;
        run += kf;
        int oidx = kf ? kbefore : (total + (pp - kbefore));
        if (oidx < POST_K) {
            uint32_t sl = slots[q];
            const float4 b = *(const float4*)(cand_box + ((size_t)img * M_TOT + sl) * 4);
            float* ob = out + ((size_t)img * POST_K + oidx) * 4;
            ob[0] = b.x; ob[1] = b.y; ob[2] = b.z; ob[3] = b.w;
            out[NIMG * POST_K * 4 + (size_t)img * POST_K + oidx] =
                kf ? cand_score[(size_t)img * M_TOT + sl] : NEGV;
        }
    }
}

extern "C" void kernel_launch(void* const* d_in, const int* in_sizes, int n_in,
                              void* d_out, int out_size, void* d_ws, size_t ws_size,
                              hipStream_t stream) {
    Ptrs p;
    for (int l = 0; l < NLVL; ++l) {
        p.logits[l]  = (const float*)d_in[3 * l + 0];
        p.deltas[l]  = (const float*)d_in[3 * l + 1];
        p.anchors[l] = (const float*)d_in[3 * l + 2];
    }

    // workspace layout (~2.6 MB)
    char* w = (char*)d_ws;
    float* cand_box   = (float*)w;        w += (size_t)NIMG * M_TOT * 4 * sizeof(float);
    float* cand_score = (float*)w;        w += (size_t)NIMG * M_TOT * sizeof(float);
    uint32_t* kept        = (uint32_t*)w; w += (size_t)NIMG * M_TOT * sizeof(uint32_t);
    uint64_t* cand_pk     = (uint64_t*)w; w += (size_t)NGRP * CAP * sizeof(uint64_t);
    uint64_t* tri         = (uint64_t*)w; w += (size_t)NGRP * TRI_W * sizeof(uint64_t);
    uint64_t* diag        = (uint64_t*)w; w += (size_t)NGRP * 1024 * sizeof(uint64_t);
    // zeroed region (one contiguous memset): ghist + counters + flags + thr
    char* zbase = w;
    uint32_t* ghist       = (uint32_t*)w; w += (size_t)NGRP * NBIN * sizeof(uint32_t);
    uint32_t* cand_cnt    = (uint32_t*)w; w += (size_t)NGRP * CNT_STRIDE * sizeof(uint32_t);
    uint32_t* need_fb     = (uint32_t*)w; w += 128;
    uint32_t* thr         = (uint32_t*)w; w += 128;
    size_t zbytes = (size_t)(w - zbase);

    hipMemsetAsync(zbase, 0, zbytes, stream);

    kCompactSpec<<<NIMG * BPI, 256, 0, stream>>>(p, cand_cnt, cand_pk);
    kCheck      <<<1,          64, 0, stream>>>(cand_cnt, need_fb);
    kHistFB     <<<NIMG * BPI, 256, 0, stream>>>(p, need_fb, ghist);
    kSelectFB   <<<NGRP,       256, 0, stream>>>(need_fb, ghist, thr);
    kCompactFB  <<<NIMG * BPI, 256, 0, stream>>>(p, need_fb, thr, cand_cnt, cand_pk);
    kRankDecode <<<NGRP,       256, 0, stream>>>(p, cand_cnt, cand_pk, cand_box, cand_score);
    kIou        <<<NGRP * 16,  256, 0, stream>>>(cand_box, tri, diag);
    kScan       <<<NGRP,       256, 0, stream>>>(cand_score, tri, diag, kept);
    kMergeOut   <<<NIMG,      1024, 0, stream>>>(cand_box, cand_score, kept, (float*)d_out);
}

// Round 6
// 262.519 us; speedup vs baseline: 5.9099x; 1.2444x over previous
//
#include <hip/hip_runtime.h>
#include <stdint.h>
#include <math.h>

#define NLVL 5
#define NIMG 4
#define NGRP (NIMG * NLVL)
#define M_TOT 4768
#define POST_K 1000
#define NEGV  (-1e9f)
#define CAP 2048
#define NBIN 4096
#define BPI 65          // data-pass blocks per image
#define TRI_W 7680      // upper-triangular word count per group (k<=1000, 16 words)
#define CNT_STRIDE 32   // cand_cnt counters spread one per 128B line
#define RD_SPLIT 8      // rank-decode sub-blocks per group

__constant__ int c_hwa[NLVL]  = {196608, 49152, 12288, 3072, 768};
__constant__ int c_k[NLVL]    = {1000, 1000, 1000, 1000, 768};
__constant__ int c_base[NLVL] = {0, 1000, 2000, 3000, 4000};
__constant__ int c_cnt[NLVL]  = {4096, 4096, 4096, 3072, 768};
// Speculative per-level key thresholds (flipf of score): expected candidate
// count ~1550 per group for N(0,1) logits; validated by kCheck, exact
// fallback path runs for any group where count \notin [k, CAP].
__constant__ uint32_t c_T0[NLVL] = {0xC019999Au, 0xBFECCCCDu, 0xBF933333u, 0x80000000u, 0x00000000u};

struct Ptrs {
    const float* logits[NLVL];
    const float* deltas[NLVL];
    const float* anchors[NLVL];
};

__device__ __forceinline__ uint32_t flipf(float f) {
    uint32_t b = __float_as_uint(f);
    return (b & 0x80000000u) ? ~b : (b | 0x80000000u);
}
__device__ __forceinline__ float unflipf(uint32_t key) {
    uint32_t b = (key & 0x80000000u) ? (key & 0x7FFFFFFFu) : ~key;
    return __uint_as_float(b);
}

__device__ __forceinline__ void grp_decompose(int g, int& img, int& lvl, int& off, int& cnt) {
    img = g / BPI;
    int r = g % BPI;
    if (r < 48)      { lvl = 0; off = r * 4096; }
    else if (r < 60) { lvl = 1; off = (r - 48) * 4096; }
    else if (r < 63) { lvl = 2; off = (r - 60) * 4096; }
    else if (r < 64) { lvl = 3; off = 0; }
    else             { lvl = 4; off = 0; }
    cnt = c_cnt[lvl];
}

// ---------------------------------------------------------------------------
// Speculative single-pass compaction: keys >= c_T0[lvl] staged in LDS, one
// global atomic per block. Exactness guaranteed downstream by kRankDecode
// as long as count(>=T0) ∈ [k, CAP] — validated by kCheck, else fallback.
// ---------------------------------------------------------------------------
__global__ void kCompactSpec(Ptrs p, uint32_t* __restrict__ cand_cnt,
                             uint64_t* __restrict__ cand_pk) {
    int img, lvl, off, cnt;
    grp_decompose(blockIdx.x, img, lvl, off, cnt);
    const int grp = img * NLVL + lvl;
    const int tid = threadIdx.x;
    const float* lg = p.logits[lvl] + (size_t)img * c_hwa[lvl] + off;
    const uint32_t T = c_T0[lvl];
    uint64_t* pk = cand_pk + (size_t)grp * CAP;

    __shared__ uint32_t scnt, sbase;
    __shared__ uint64_t sbuf[4096];
    if (tid == 0) scnt = 0u;
    __syncthreads();

    const int nvec = cnt >> 2;
    const float4* lg4 = (const float4*)lg;
    for (int v = tid; v < nvec; v += 256) {
        float4 x = lg4[v];
        float xs[4] = {x.x, x.y, x.z, x.w};
        #pragma unroll
        for (int c = 0; c < 4; ++c) {
            uint32_t key = flipf(xs[c]);
            if (key >= T) {
                uint32_t pos = atomicAdd(&scnt, 1u);
                uint32_t eidx = (uint32_t)(off + 4 * v + c);
                sbuf[pos] = ((uint64_t)key << 32) | (uint32_t)(~eidx);
            }
        }
    }
    __syncthreads();
    if (tid == 0) sbase = atomicAdd(&cand_cnt[grp * CNT_STRIDE], scnt);
    __syncthreads();
    const uint32_t n = scnt, b0 = sbase;
    for (uint32_t i = tid; i < n; i += 256) {
        uint32_t g = b0 + i;
        if (g < CAP) pk[g] = sbuf[i];
    }
}

// ---------------------------------------------------------------------------
// Validate speculation; flag groups needing the exact fallback path.
// ---------------------------------------------------------------------------
__global__ void kCheck(uint32_t* __restrict__ cand_cnt, uint32_t* __restrict__ need_fb) {
    const int g = threadIdx.x;
    if (g < NGRP) {
        uint32_t c = cand_cnt[g * CNT_STRIDE];
        uint32_t k = (uint32_t)c_k[g % NLVL];
        uint32_t bad = (c < k || c > CAP) ? 1u : 0u;
        need_fb[g] = bad;
        if (bad) cand_cnt[g * CNT_STRIDE] = 0u;   // reset for exact recompaction
    }
}

// ---------------------------------------------------------------------------
// Fallback pass 1: 4096-bin histogram (only for flagged groups).
// ---------------------------------------------------------------------------
__global__ void kHistFB(Ptrs p, const uint32_t* __restrict__ need_fb,
                        uint32_t* __restrict__ ghist) {
    __shared__ uint32_t lh[NBIN];
    int img, lvl, off, cnt;
    grp_decompose(blockIdx.x, img, lvl, off, cnt);
    const int grp = img * NLVL + lvl;
    if (!need_fb[grp]) return;
    const int tid = threadIdx.x;
    const float* lg = p.logits[lvl] + (size_t)img * c_hwa[lvl] + off;

    for (int b = tid; b < NBIN; b += 256) lh[b] = 0u;
    __syncthreads();

    const int nvec = cnt >> 2;
    const float4* lg4 = (const float4*)lg;
    for (int v = tid; v < nvec; v += 256) {
        float4 x = lg4[v];
        atomicAdd(&lh[flipf(x.x) >> 20], 1u);
        atomicAdd(&lh[flipf(x.y) >> 20], 1u);
        atomicAdd(&lh[flipf(x.z) >> 20], 1u);
        atomicAdd(&lh[flipf(x.w) >> 20], 1u);
    }
    __syncthreads();

    uint32_t* gh = ghist + (size_t)grp * NBIN;
    for (int b = tid; b < NBIN; b += 256)
        if (lh[b]) atomicAdd(&gh[b], lh[b]);
}

// ---------------------------------------------------------------------------
// Fallback pass 2: exact threshold bucket from histogram.
// ---------------------------------------------------------------------------
__global__ void kSelectFB(const uint32_t* __restrict__ need_fb,
                          const uint32_t* __restrict__ ghist, uint32_t* __restrict__ thr) {
    const int grp = blockIdx.x;
    if (!need_fb[grp]) return;
    const int k = c_k[grp % NLVL];
    __shared__ uint32_t h[NBIN];
    __shared__ uint32_t ss[256];
    const int tid = threadIdx.x;
    const uint32_t* gh = ghist + (size_t)grp * NBIN;

    for (int b = tid; b < NBIN; b += 256) h[b] = gh[b];
    __syncthreads();

    uint32_t s = 0;
    #pragma unroll
    for (int b = 0; b < 16; ++b) s += h[tid * 16 + b];
    ss[tid] = s;
    __syncthreads();
    for (int off = 1; off < 256; off <<= 1) {
        uint32_t v = (tid + off < 256) ? ss[tid + off] : 0u;
        __syncthreads();
        ss[tid] += v;
        __syncthreads();
    }
    uint32_t running = (tid == 255) ? 0u : ss[tid + 1];
    for (int b = 15; b >= 0; --b) {
        uint32_t c = h[tid * 16 + b];
        running += c;
        if ((running >= (uint32_t)k) && (running - c < (uint32_t)k)) {
            thr[grp] = (uint32_t)(tid * 16 + b) << 20;
        }
    }
}

// ---------------------------------------------------------------------------
// Fallback pass 3: exact compaction for flagged groups (block-staged).
// ---------------------------------------------------------------------------
__global__ void kCompactFB(Ptrs p, const uint32_t* __restrict__ need_fb,
                           const uint32_t* __restrict__ thr,
                           uint32_t* __restrict__ cand_cnt,
                           uint64_t* __restrict__ cand_pk) {
    int img, lvl, off, cnt;
    grp_decompose(blockIdx.x, img, lvl, off, cnt);
    const int grp = img * NLVL + lvl;
    if (!need_fb[grp]) return;
    const int tid = threadIdx.x;
    const float* lg = p.logits[lvl] + (size_t)img * c_hwa[lvl] + off;
    const uint32_t T = thr[grp];
    uint64_t* pk = cand_pk + (size_t)grp * CAP;

    __shared__ uint32_t scnt, sbase;
    __shared__ uint64_t sbuf[4096];
    if (tid == 0) scnt = 0u;
    __syncthreads();

    const int nvec = cnt >> 2;
    const float4* lg4 = (const float4*)lg;
    for (int v = tid; v < nvec; v += 256) {
        float4 x = lg4[v];
        float xs[4] = {x.x, x.y, x.z, x.w};
        #pragma unroll
        for (int c = 0; c < 4; ++c) {
            uint32_t key = flipf(xs[c]);
            if (key >= T) {
                uint32_t pos = atomicAdd(&scnt, 1u);
                uint32_t eidx = (uint32_t)(off + 4 * v + c);
                sbuf[pos] = ((uint64_t)key << 32) | (uint32_t)(~eidx);
            }
        }
    }
    __syncthreads();
    if (tid == 0) sbase = atomicAdd(&cand_cnt[grp * CNT_STRIDE], scnt);
    __syncthreads();
    const uint32_t n = scnt, b0 = sbase;
    for (uint32_t i = tid; i < n; i += 256) {
        uint32_t g = b0 + i;
        if (g < CAP) pk[g] = sbuf[i];
    }
}

// ---------------------------------------------------------------------------
// Exact rank among candidates; decode boxes for rank < k. Bit-exact ref math.
// Split RD_SPLIT blocks per group: each block ranks a 256-candidate slice.
// ---------------------------------------------------------------------------
__global__ void kRankDecode(Ptrs p, const uint32_t* __restrict__ cand_cnt,
                            const uint64_t* __restrict__ cand_pk,
                            float* __restrict__ cand_box,
                            float* __restrict__ cand_score) {
    #pragma clang fp contract(off)
    const int blk = blockIdx.x;          // grp * RD_SPLIT + sub
    const int grp = blk / RD_SPLIT;
    const int sub = blk % RD_SPLIT;
    const int img = grp / NLVL;
    const int lvl = grp % NLVL;
    const int n    = c_hwa[lvl];
    const int k    = c_k[lvl];
    const int base = c_base[lvl];
    const int tid = threadIdx.x;

    const int cc = (int)min(cand_cnt[grp * CNT_STRIDE], (uint32_t)CAP);
    const int c0 = sub * (CAP / RD_SPLIT);
    if (c0 >= cc) return;

    __shared__ uint64_t K[CAP];
    const uint64_t* pk = cand_pk + (size_t)grp * CAP;
    for (int i = tid; i < cc; i += 256) K[i] = pk[i];
    __syncthreads();

    const int c = c0 + tid;
    const uint64_t myK = (c < cc) ? K[c] : ~0ull;
    int r = 0;
    int j = 0;
    for (; j + 8 <= cc; j += 8) {
        #pragma unroll
        for (int u = 0; u < 8; ++u) r += (int)(K[j + u] > myK);
    }
    for (; j < cc; ++j) r += (int)(K[j] > myK);

    if (c >= cc || r >= k) return;

    uint32_t key = (uint32_t)(myK >> 32);
    uint32_t ic  = ~(uint32_t)(myK & 0xFFFFFFFFu);
    const float* an = p.anchors[lvl] + (size_t)ic * 4;
    const float* dl = p.deltas[lvl] + ((size_t)img * n + ic) * 4;
    float a0 = an[0], a1 = an[1], a2 = an[2], a3 = an[3];
    float wa = a2 - a0, ha = a3 - a1;
    float cxa = a0 + 0.5f * wa, cya = a1 + 0.5f * ha;
    float dx = dl[0], dy = dl[1], dw = dl[2], dh = dl[3];
    const float SC = (float)4.135166556742356;  // log(1000/16)
    dw = fminf(dw, SC);
    dh = fminf(dh, SC);
    float cx = dx * wa + cxa, cy = dy * ha + cya;
    float w = wa * expf(dw), h = ha * expf(dh);
    float x1 = cx - 0.5f * w, y1 = cy - 0.5f * h;
    float x2 = cx + 0.5f * w, y2 = cy + 0.5f * h;
    x1 = fminf(fmaxf(x1, 0.0f), 1024.0f);
    y1 = fminf(fmaxf(y1, 0.0f), 1024.0f);
    x2 = fminf(fmaxf(x2, 0.0f), 1024.0f);
    y2 = fminf(fmaxf(y2, 0.0f), 1024.0f);
    float bw = x2 - x1, bh = y2 - y1;
    float score = (bw > 0.0f && bh > 0.0f) ? unflipf(key) : NEGV;
    const int slot = base + r;
    float* ob = cand_box + ((size_t)img * M_TOT + slot) * 4;
    ob[0] = x1; ob[1] = y1; ob[2] = x2; ob[3] = y2;
    cand_score[(size_t)img * M_TOT + slot] = score;
}

// ---------------------------------------------------------------------------
// NMS phase 1: suppression bit-matrix, upper-triangular by 64-wide word.
// ---------------------------------------------------------------------------
__global__ void kIou(const float* __restrict__ cand_box,
                     uint64_t* __restrict__ tri, uint64_t* __restrict__ diag) {
    #pragma clang fp contract(off)
    const int blk = blockIdx.x;      // grp*16 + w
    const int grp = blk >> 4;
    const int w   = blk & 15;
    const int img = grp / NLVL;
    const int lvl = grp % NLVL;
    const int k    = c_k[lvl];
    const int base = c_base[lvl];
    if (64 * w >= k) return;
    const int jn = min(64, k - 64 * w);
    const int R  = min(64 * (w + 1), k);
    const float lo = (float)lvl * 2048.0f;

    __shared__ float jx1[64], jy1[64], jx2[64], jy2[64], jar[64];
    const int tid = threadIdx.x;
    if (tid < jn) {
        const float4 b = *(const float4*)(cand_box + ((size_t)img * M_TOT + base + 64 * w + tid) * 4);
        float x1 = b.x + lo, y1 = b.y + lo, x2 = b.z + lo, y2 = b.w + lo;
        jx1[tid] = x1; jy1[tid] = y1; jx2[tid] = x2; jy2[tid] = y2;
        jar[tid] = (x2 - x1) * (y2 - y1);
    }
    __syncthreads();

    for (int r = tid; r < R; r += 256) {
        const float4 b = *(const float4*)(cand_box + ((size_t)img * M_TOT + base + r) * 4);
        float rx1 = b.x + lo, ry1 = b.y + lo, rx2 = b.z + lo, ry2 = b.w + lo;
        float ra = (rx2 - rx1) * (ry2 - ry1);
        uint64_t bits = 0ull;
        #pragma unroll 8
        for (int jj = 0; jj < jn; ++jj) {
            int j = 64 * w + jj;
            if (j > r) {
                float ltx = fmaxf(rx1, jx1[jj]);
                float lty = fmaxf(ry1, jy1[jj]);
                float rbx = fminf(rx2, jx2[jj]);
                float rby = fminf(ry2, jy2[jj]);
                float wx = fmaxf(rbx - ltx, 0.0f);
                float wy = fmaxf(rby - lty, 0.0f);
                float inter = wx * wy;
                float denom = ((ra + jar[jj]) - inter) + 1e-9f;
                if (inter / denom > 0.7f) bits |= (1ull << jj);
            }
        }
        const int q = r >> 6;
        if (q == w) {
            diag[(size_t)grp * 1024 + r] = bits;
        } else {
            const int m = r & 63;
            const int tb = 15 * r - 32 * q * (q - 1) - m * q;  // tri_base(r)
            tri[(size_t)grp * TRI_W + tb + (w - q - 1)] = bits;
        }
    }
}

// ---------------------------------------------------------------------------
// NMS phase 2: greedy scan, one wave per group, no barriers in the loop.
// ---------------------------------------------------------------------------
__global__ void kScan(const float* __restrict__ cand_score,
                      const uint64_t* __restrict__ tri,
                      const uint64_t* __restrict__ diag,
                      uint32_t* __restrict__ kept) {
    const int grp = blockIdx.x;
    const int img = grp / NLVL;
    const int lvl = grp % NLVL;
    const int k    = c_k[lvl];
    const int base = c_base[lvl];
    __shared__ uint64_t tl[TRI_W];
    const int tid = threadIdx.x;
    const uint64_t* tg = tri + (size_t)grp * TRI_W;
    for (int i = tid; i < TRI_W; i += 256) tl[i] = tg[i];
    __syncthreads();
    if (tid >= 64) return;           // wave 0 does the scan; no barriers follow
    const int lane = tid;

    uint64_t darr[16];
    #pragma unroll
    for (int s = 0; s < 16; ++s)
        darr[s] = (64 * s + lane < k) ? diag[(size_t)grp * 1024 + 64 * s + lane] : 0ull;

    float sc[16];
    #pragma unroll
    for (int s = 0; s < 16; ++s) {
        int r = 64 * s + lane;
        sc[s] = (r < k) ? cand_score[(size_t)img * M_TOT + base + r] : NEGV;
    }
    uint64_t inv[16];
    #pragma unroll
    for (int s = 0; s < 16; ++s)
        inv[s] = (uint64_t)__ballot(sc[s] <= -5e8f);

    uint64_t keep_w[16];
    #pragma unroll
    for (int s = 0; s < 16; ++s) keep_w[s] = 0ull;

    #pragma unroll
    for (int q = 0; q < 16; ++q) {
        if (64 * q < k) {
            uint64_t v = 0ull;
            #pragma unroll
            for (int s = 0; s < q; ++s) {
                if ((keep_w[s] >> lane) & 1ull) {
                    const int rp = 64 * s + lane;
                    const int tb = 15 * rp - 32 * s * (s - 1) - lane * s;
                    v |= tl[tb + (q - s - 1)];
                }
            }
            #pragma unroll
            for (int off2 = 32; off2 >= 1; off2 >>= 1)
                v |= (uint64_t)__shfl_xor((unsigned long long)v, off2, 64);
            const uint64_t cur0 = inv[q] | v;
            uint32_t clo = __builtin_amdgcn_readfirstlane((uint32_t)cur0);
            uint32_t chi = __builtin_amdgcn_readfirstlane((uint32_t)(cur0 >> 32));
            uint64_t scur = ((uint64_t)chi << 32) | (uint64_t)clo;
            uint64_t kw = 0ull;
            const int mm = min(64, k - 64 * q);
            const uint32_t dlo = (uint32_t)darr[q];
            const uint32_t dhi = (uint32_t)(darr[q] >> 32);
            for (int m = 0; m < mm; ++m) {
                if (!((scur >> m) & 1ull)) {
                    uint64_t dg = ((uint64_t)(uint32_t)__builtin_amdgcn_readlane((int)dhi, m) << 32)
                                |  (uint64_t)(uint32_t)__builtin_amdgcn_readlane((int)dlo, m);
                    scur |= dg;
                    kw |= (1ull << m);
                }
            }
            keep_w[q] = kw;
        }
    }

    #pragma unroll
    for (int s = 0; s < 16; ++s) {
        int r = 64 * s + lane;
        if (r < k)
            kept[(size_t)img * M_TOT + base + r] = (uint32_t)((keep_w[s] >> lane) & 1ull);
    }
}

// ---------------------------------------------------------------------------
// Merge-rank + stable partition + output, one block (1024 thr) per image.
// ---------------------------------------------------------------------------
__device__ __forceinline__ int bs_count_ge(const uint32_t* a, int n, uint32_t x) {
    int lo = 0, hi = n;
    while (lo < hi) { int mid = (lo + hi) >> 1; if (a[mid] >= x) lo = mid + 1; else hi = mid; }
    return lo;
}
__device__ __forceinline__ int bs_count_gt(const uint32_t* a, int n, uint32_t x) {
    int lo = 0, hi = n;
    while (lo < hi) { int mid = (lo + hi) >> 1; if (a[mid] > x) lo = mid + 1; else hi = mid; }
    return lo;
}

__global__ void kMergeOut(const float* __restrict__ cand_box,
                          const float* __restrict__ cand_score,
                          const uint32_t* __restrict__ kept,
                          float* __restrict__ out) {
    const int img = blockIdx.x;
    const int tid = threadIdx.x;   // 1024
    const int lane = tid & 63, wave = tid >> 6;

    __shared__ uint32_t vkey[NLVL * 1024];  // compacted valid keys, desc
    __shared__ uint32_t ord[M_TOT];         // merged order: slot | kept<<31
    __shared__ int ssum[1024];
    __shared__ uint32_t wsum[NLVL][16];

    // ---- Phase 1: per-level valid ballot-scan ----
    uint32_t mykey[NLVL];
    int myvalid[NLVL], mylower[NLVL];
    #pragma unroll
    for (int L = 0; L < NLVL; ++L) {
        const int kL = c_k[L];
        const bool act = tid < kL;
        float s = act ? cand_score[(size_t)img * M_TOT + c_base[L] + tid] : NEGV;
        bool valid = act && (s > -5e8f);
        uint64_t mask = __ballot(valid);
        mylower[L] = (int)__popcll(mask & ((1ull << lane) - 1ull));
        if (lane == 0) wsum[L][wave] = (uint32_t)__popcll(mask);
        mykey[L] = flipf(s);
        myvalid[L] = valid ? 1 : 0;
    }
    __syncthreads();

    int nv[NLVL], myvpre[NLVL];
    #pragma unroll
    for (int L = 0; L < NLVL; ++L) {
        int pw = 0, tot = 0;
        #pragma unroll
        for (int w = 0; w < 16; ++w) {
            if (w < wave) pw += (int)wsum[L][w];
            tot += (int)wsum[L][w];
        }
        nv[L] = tot;
        myvpre[L] = pw + mylower[L];
        if (tid < c_k[L] && myvalid[L])
            vkey[L * 1024 + myvpre[L]] = mykey[L];
    }
    int totalValid = 0;
    #pragma unroll
    for (int L = 0; L < NLVL; ++L) totalValid += nv[L];
    __syncthreads();

    // ---- Phase 2: merge-rank each element, scatter into ord ----
    int invBase = totalValid;
    #pragma unroll
    for (int L = 0; L < NLVL; ++L) {
        const int kL = c_k[L];
        if (tid < kL) {
            const int slot = c_base[L] + tid;
            if (myvalid[L]) {
                const uint32_t x = mykey[L];
                int pos = myvpre[L];
                #pragma unroll
                for (int Lp = 0; Lp < NLVL; ++Lp) {
                    if (Lp == L) continue;
                    pos += (Lp < L) ? bs_count_ge(&vkey[Lp * 1024], nv[Lp], x)
                                    : bs_count_gt(&vkey[Lp * 1024], nv[Lp], x);
                }
                const uint32_t kp = kept[(size_t)img * M_TOT + slot];
                ord[pos] = (uint32_t)slot | (kp << 31);
            } else {
                const int inv_idx = tid - myvpre[L];
                ord[invBase + inv_idx] = (uint32_t)slot;  // kept=0
            }
        }
        invBase += (c_k[L] - nv[L]);
    }
    __syncthreads();

    // ---- Phase 3: stable partition by kept flag, write output ----
    const int PT = 5;
    const int pos0 = tid * PT;
    int flags[PT];
    uint32_t slots[PT];
    int lsum = 0;
    #pragma unroll
    for (int q = 0; q < PT; ++q) {
        int pp = pos0 + q;
        int kf = 0; uint32_t sl = 0;
        if (pp < M_TOT) {
            uint32_t o = ord[pp];
            sl = o & 0x7FFFFFFFu;
            kf = (int)(o >> 31);
        }
        flags[q] = kf; slots[q] = sl; lsum += kf;
    }
    ssum[tid] = lsum;
    __syncthreads();
    for (int off = 1; off < 1024; off <<= 1) {
        int v = (tid >= off) ? ssum[tid - off] : 0;
        __syncthreads();
        ssum[tid] += v;
        __syncthreads();
    }
    const int excl = ssum[tid] - lsum;
    const int total = ssum[1023];

    int run = 0;
    #pragma unroll
    for (int q = 0; q < PT; ++q) {
        int pp = pos0 + q;
        if (pp >= M_TOT) break;
        int kf = flags[q];
        int kbefore = excl + run;
        run += kf;
        int oidx = kf ? kbefore : (total + (pp - kbefore));
        if (oidx < POST_K) {
            uint32_t sl = slots[q];
            const float4 b = *(const float4*)(cand_box + ((size_t)img * M_TOT + sl) * 4);
            float* ob = out + ((size_t)img * POST_K + oidx) * 4;
            ob[0] = b.x; ob[1] = b.y; ob[2] = b.z; ob[3] = b.w;
            out[NIMG * POST_K * 4 + (size_t)img * POST_K + oidx] =
                kf ? cand_score[(size_t)img * M_TOT + sl] : NEGV;
        }
    }
}

extern "C" void kernel_launch(void* const* d_in, const int* in_sizes, int n_in,
                              void* d_out, int out_size, void* d_ws, size_t ws_size,
                              hipStream_t stream) {
    Ptrs p;
    for (int l = 0; l < NLVL; ++l) {
        p.logits[l]  = (const float*)d_in[3 * l + 0];
        p.deltas[l]  = (const float*)d_in[3 * l + 1];
        p.anchors[l] = (const float*)d_in[3 * l + 2];
    }

    // workspace layout (~2.6 MB)
    char* w = (char*)d_ws;
    float* cand_box   = (float*)w;        w += (size_t)NIMG * M_TOT * 4 * sizeof(float);
    float* cand_score = (float*)w;        w += (size_t)NIMG * M_TOT * sizeof(float);
    uint32_t* kept        = (uint32_t*)w; w += (size_t)NIMG * M_TOT * sizeof(uint32_t);
    uint64_t* cand_pk     = (uint64_t*)w; w += (size_t)NGRP * CAP * sizeof(uint64_t);
    uint64_t* tri         = (uint64_t*)w; w += (size_t)NGRP * TRI_W * sizeof(uint64_t);
    uint64_t* diag        = (uint64_t*)w; w += (size_t)NGRP * 1024 * sizeof(uint64_t);
    // zeroed region (one contiguous memset): ghist + counters + flags + thr
    char* zbase = w;
    uint32_t* ghist       = (uint32_t*)w; w += (size_t)NGRP * NBIN * sizeof(uint32_t);
    uint32_t* cand_cnt    = (uint32_t*)w; w += (size_t)NGRP * CNT_STRIDE * sizeof(uint32_t);
    uint32_t* need_fb     = (uint32_t*)w; w += 128;
    uint32_t* thr         = (uint32_t*)w; w += 128;
    size_t zbytes = (size_t)(w - zbase);

    hipMemsetAsync(zbase, 0, zbytes, stream);

    kCompactSpec<<<NIMG * BPI, 256, 0, stream>>>(p, cand_cnt, cand_pk);
    kCheck      <<<1,          64, 0, stream>>>(cand_cnt, need_fb);
    kHistFB     <<<NIMG * BPI, 256, 0, stream>>>(p, need_fb, ghist);
    kSelectFB   <<<NGRP,       256, 0, stream>>>(need_fb, ghist, thr);
    kCompactFB  <<<NIMG * BPI, 256, 0, stream>>>(p, need_fb, thr, cand_cnt, cand_pk);
    kRankDecode <<<NGRP * RD_SPLIT, 256, 0, stream>>>(p, cand_cnt, cand_pk, cand_box, cand_score);
    kIou        <<<NGRP * 16,  256, 0, stream>>>(cand_box, tri, diag);
    kScan       <<<NGRP,       256, 0, stream>>>(cand_score, tri, diag, kept);
    kMergeOut   <<<NIMG,      1024, 0, stream>>>(cand_box, cand_score, kept, (float*)d_out);
}

// Round 7
// 247.220 us; speedup vs baseline: 6.2757x; 1.0619x over previous
//
#include <hip/hip_runtime.h>
#include <stdint.h>
#include <math.h>

#define NLVL 5
#define NIMG 4
#define NGRP (NIMG * NLVL)
#define M_TOT 4768
#define POST_K 1000
#define NEGV  (-1e9f)
#define CAP 2048
#define NBIN 4096
#define BPI 65          // data-pass blocks per image
#define TRI_W 7680      // upper-triangular word count per group (k<=1000, 16 words)
#define CNT_STRIDE 32   // cand_cnt counters spread one per 128B line
#define RD_SPLIT 8      // rank-decode sub-blocks per group

__constant__ int c_hwa[NLVL]  = {196608, 49152, 12288, 3072, 768};
__constant__ int c_k[NLVL]    = {1000, 1000, 1000, 1000, 768};
__constant__ int c_base[NLVL] = {0, 1000, 2000, 3000, 4000};
__constant__ int c_cnt[NLVL]  = {4096, 4096, 4096, 3072, 768};
// Speculative per-level key thresholds (flipf of score): expected candidate
// count ~1550 per group for N(0,1) logits; validated by kCheck, exact
// fallback path runs for any group where count \notin [k, CAP].
__constant__ uint32_t c_T0[NLVL] = {0xC019999Au, 0xBFECCCCDu, 0xBF933333u, 0x80000000u, 0x00000000u};

struct Ptrs {
    const float* logits[NLVL];
    const float* deltas[NLVL];
    const float* anchors[NLVL];
};

__device__ __forceinline__ uint32_t flipf(float f) {
    uint32_t b = __float_as_uint(f);
    return (b & 0x80000000u) ? ~b : (b | 0x80000000u);
}
__device__ __forceinline__ float unflipf(uint32_t key) {
    uint32_t b = (key & 0x80000000u) ? (key & 0x7FFFFFFFu) : ~key;
    return __uint_as_float(b);
}

__device__ __forceinline__ void grp_decompose(int g, int& img, int& lvl, int& off, int& cnt) {
    img = g / BPI;
    int r = g % BPI;
    if (r < 48)      { lvl = 0; off = r * 4096; }
    else if (r < 60) { lvl = 1; off = (r - 48) * 4096; }
    else if (r < 63) { lvl = 2; off = (r - 60) * 4096; }
    else if (r < 64) { lvl = 3; off = 0; }
    else             { lvl = 4; off = 0; }
    cnt = c_cnt[lvl];
}

// ---------------------------------------------------------------------------
// Speculative single-pass compaction: keys >= c_T0[lvl] staged in LDS, one
// global atomic per block. Exactness guaranteed downstream by kRankDecode
// as long as count(>=T0) ∈ [k, CAP] — validated by kCheck, else fallback.
// ---------------------------------------------------------------------------
__global__ void kCompactSpec(Ptrs p, uint32_t* __restrict__ cand_cnt,
                             uint64_t* __restrict__ cand_pk) {
    int img, lvl, off, cnt;
    grp_decompose(blockIdx.x, img, lvl, off, cnt);
    const int grp = img * NLVL + lvl;
    const int tid = threadIdx.x;
    const float* lg = p.logits[lvl] + (size_t)img * c_hwa[lvl] + off;
    const uint32_t T = c_T0[lvl];
    uint64_t* pk = cand_pk + (size_t)grp * CAP;

    __shared__ uint32_t scnt, sbase;
    __shared__ uint64_t sbuf[4096];
    if (tid == 0) scnt = 0u;
    __syncthreads();

    const int nvec = cnt >> 2;
    const float4* lg4 = (const float4*)lg;
    for (int v = tid; v < nvec; v += 256) {
        float4 x = lg4[v];
        float xs[4] = {x.x, x.y, x.z, x.w};
        #pragma unroll
        for (int c = 0; c < 4; ++c) {
            uint32_t key = flipf(xs[c]);
            if (key >= T) {
                uint32_t pos = atomicAdd(&scnt, 1u);
                uint32_t eidx = (uint32_t)(off + 4 * v + c);
                sbuf[pos] = ((uint64_t)key << 32) | (uint32_t)(~eidx);
            }
        }
    }
    __syncthreads();
    if (tid == 0) sbase = atomicAdd(&cand_cnt[grp * CNT_STRIDE], scnt);
    __syncthreads();
    const uint32_t n = scnt, b0 = sbase;
    for (uint32_t i = tid; i < n; i += 256) {
        uint32_t g = b0 + i;
        if (g < CAP) pk[g] = sbuf[i];
    }
}

// ---------------------------------------------------------------------------
// Validate speculation; flag groups needing the exact fallback path.
// ---------------------------------------------------------------------------
__global__ void kCheck(uint32_t* __restrict__ cand_cnt, uint32_t* __restrict__ need_fb) {
    const int g = threadIdx.x;
    if (g < NGRP) {
        uint32_t c = cand_cnt[g * CNT_STRIDE];
        uint32_t k = (uint32_t)c_k[g % NLVL];
        uint32_t bad = (c < k || c > CAP) ? 1u : 0u;
        need_fb[g] = bad;
        if (bad) cand_cnt[g * CNT_STRIDE] = 0u;   // reset for exact recompaction
    }
}

// ---------------------------------------------------------------------------
// Fallback pass 1: 4096-bin histogram (only for flagged groups).
// ---------------------------------------------------------------------------
__global__ void kHistFB(Ptrs p, const uint32_t* __restrict__ need_fb,
                        uint32_t* __restrict__ ghist) {
    __shared__ uint32_t lh[NBIN];
    int img, lvl, off, cnt;
    grp_decompose(blockIdx.x, img, lvl, off, cnt);
    const int grp = img * NLVL + lvl;
    if (!need_fb[grp]) return;
    const int tid = threadIdx.x;
    const float* lg = p.logits[lvl] + (size_t)img * c_hwa[lvl] + off;

    for (int b = tid; b < NBIN; b += 256) lh[b] = 0u;
    __syncthreads();

    const int nvec = cnt >> 2;
    const float4* lg4 = (const float4*)lg;
    for (int v = tid; v < nvec; v += 256) {
        float4 x = lg4[v];
        atomicAdd(&lh[flipf(x.x) >> 20], 1u);
        atomicAdd(&lh[flipf(x.y) >> 20], 1u);
        atomicAdd(&lh[flipf(x.z) >> 20], 1u);
        atomicAdd(&lh[flipf(x.w) >> 20], 1u);
    }
    __syncthreads();

    uint32_t* gh = ghist + (size_t)grp * NBIN;
    for (int b = tid; b < NBIN; b += 256)
        if (lh[b]) atomicAdd(&gh[b], lh[b]);
}

// ---------------------------------------------------------------------------
// Fallback pass 2: exact threshold bucket from histogram.
// ---------------------------------------------------------------------------
__global__ void kSelectFB(const uint32_t* __restrict__ need_fb,
                          const uint32_t* __restrict__ ghist, uint32_t* __restrict__ thr) {
    const int grp = blockIdx.x;
    if (!need_fb[grp]) return;
    const int k = c_k[grp % NLVL];
    __shared__ uint32_t h[NBIN];
    __shared__ uint32_t ss[256];
    const int tid = threadIdx.x;
    const uint32_t* gh = ghist + (size_t)grp * NBIN;

    for (int b = tid; b < NBIN; b += 256) h[b] = gh[b];
    __syncthreads();

    uint32_t s = 0;
    #pragma unroll
    for (int b = 0; b < 16; ++b) s += h[tid * 16 + b];
    ss[tid] = s;
    __syncthreads();
    for (int off = 1; off < 256; off <<= 1) {
        uint32_t v = (tid + off < 256) ? ss[tid + off] : 0u;
        __syncthreads();
        ss[tid] += v;
        __syncthreads();
    }
    uint32_t running = (tid == 255) ? 0u : ss[tid + 1];
    for (int b = 15; b >= 0; --b) {
        uint32_t c = h[tid * 16 + b];
        running += c;
        if ((running >= (uint32_t)k) && (running - c < (uint32_t)k)) {
            thr[grp] = (uint32_t)(tid * 16 + b) << 20;
        }
    }
}

// ---------------------------------------------------------------------------
// Fallback pass 3: exact compaction for flagged groups (block-staged).
// ---------------------------------------------------------------------------
__global__ void kCompactFB(Ptrs p, const uint32_t* __restrict__ need_fb,
                           const uint32_t* __restrict__ thr,
                           uint32_t* __restrict__ cand_cnt,
                           uint64_t* __restrict__ cand_pk) {
    int img, lvl, off, cnt;
    grp_decompose(blockIdx.x, img, lvl, off, cnt);
    const int grp = img * NLVL + lvl;
    if (!need_fb[grp]) return;
    const int tid = threadIdx.x;
    const float* lg = p.logits[lvl] + (size_t)img * c_hwa[lvl] + off;
    const uint32_t T = thr[grp];
    uint64_t* pk = cand_pk + (size_t)grp * CAP;

    __shared__ uint32_t scnt, sbase;
    __shared__ uint64_t sbuf[4096];
    if (tid == 0) scnt = 0u;
    __syncthreads();

    const int nvec = cnt >> 2;
    const float4* lg4 = (const float4*)lg;
    for (int v = tid; v < nvec; v += 256) {
        float4 x = lg4[v];
        float xs[4] = {x.x, x.y, x.z, x.w};
        #pragma unroll
        for (int c = 0; c < 4; ++c) {
            uint32_t key = flipf(xs[c]);
            if (key >= T) {
                uint32_t pos = atomicAdd(&scnt, 1u);
                uint32_t eidx = (uint32_t)(off + 4 * v + c);
                sbuf[pos] = ((uint64_t)key << 32) | (uint32_t)(~eidx);
            }
        }
    }
    __syncthreads();
    if (tid == 0) sbase = atomicAdd(&cand_cnt[grp * CNT_STRIDE], scnt);
    __syncthreads();
    const uint32_t n = scnt, b0 = sbase;
    for (uint32_t i = tid; i < n; i += 256) {
        uint32_t g = b0 + i;
        if (g < CAP) pk[g] = sbuf[i];
    }
}

// ---------------------------------------------------------------------------
// Exact rank among candidates; decode boxes for rank < k. Bit-exact ref math.
// Split RD_SPLIT blocks per group: each block ranks a 256-candidate slice.
// ---------------------------------------------------------------------------
__global__ void kRankDecode(Ptrs p, const uint32_t* __restrict__ cand_cnt,
                            const uint64_t* __restrict__ cand_pk,
                            float* __restrict__ cand_box,
                            float* __restrict__ cand_score) {
    #pragma clang fp contract(off)
    const int blk = blockIdx.x;          // grp * RD_SPLIT + sub
    const int grp = blk / RD_SPLIT;
    const int sub = blk % RD_SPLIT;
    const int img = grp / NLVL;
    const int lvl = grp % NLVL;
    const int n    = c_hwa[lvl];
    const int k    = c_k[lvl];
    const int base = c_base[lvl];
    const int tid = threadIdx.x;

    const int cc = (int)min(cand_cnt[grp * CNT_STRIDE], (uint32_t)CAP);
    const int c0 = sub * (CAP / RD_SPLIT);
    if (c0 >= cc) return;

    __shared__ uint64_t K[CAP];
    const uint64_t* pk = cand_pk + (size_t)grp * CAP;
    for (int i = tid; i < cc; i += 256) K[i] = pk[i];
    __syncthreads();

    const int c = c0 + tid;
    const uint64_t myK = (c < cc) ? K[c] : ~0ull;
    int r = 0;
    int j = 0;
    for (; j + 8 <= cc; j += 8) {
        #pragma unroll
        for (int u = 0; u < 8; ++u) r += (int)(K[j + u] > myK);
    }
    for (; j < cc; ++j) r += (int)(K[j] > myK);

    if (c >= cc || r >= k) return;

    uint32_t key = (uint32_t)(myK >> 32);
    uint32_t ic  = ~(uint32_t)(myK & 0xFFFFFFFFu);
    const float* an = p.anchors[lvl] + (size_t)ic * 4;
    const float* dl = p.deltas[lvl] + ((size_t)img * n + ic) * 4;
    float a0 = an[0], a1 = an[1], a2 = an[2], a3 = an[3];
    float wa = a2 - a0, ha = a3 - a1;
    float cxa = a0 + 0.5f * wa, cya = a1 + 0.5f * ha;
    float dx = dl[0], dy = dl[1], dw = dl[2], dh = dl[3];
    const float SC = (float)4.135166556742356;  // log(1000/16)
    dw = fminf(dw, SC);
    dh = fminf(dh, SC);
    float cx = dx * wa + cxa, cy = dy * ha + cya;
    float w = wa * expf(dw), h = ha * expf(dh);
    float x1 = cx - 0.5f * w, y1 = cy - 0.5f * h;
    float x2 = cx + 0.5f * w, y2 = cy + 0.5f * h;
    x1 = fminf(fmaxf(x1, 0.0f), 1024.0f);
    y1 = fminf(fmaxf(y1, 0.0f), 1024.0f);
    x2 = fminf(fmaxf(x2, 0.0f), 1024.0f);
    y2 = fminf(fmaxf(y2, 0.0f), 1024.0f);
    float bw = x2 - x1, bh = y2 - y1;
    float score = (bw > 0.0f && bh > 0.0f) ? unflipf(key) : NEGV;
    const int slot = base + r;
    float* ob = cand_box + ((size_t)img * M_TOT + slot) * 4;
    ob[0] = x1; ob[1] = y1; ob[2] = x2; ob[3] = y2;
    cand_score[(size_t)img * M_TOT + slot] = score;
}

// ---------------------------------------------------------------------------
// NMS phase 1: suppression bit-matrix, upper-triangular by 64-wide word.
// ---------------------------------------------------------------------------
__global__ void kIou(const float* __restrict__ cand_box,
                     uint64_t* __restrict__ tri, uint64_t* __restrict__ diag) {
    #pragma clang fp contract(off)
    const int blk = blockIdx.x;      // grp*16 + w
    const int grp = blk >> 4;
    const int w   = blk & 15;
    const int img = grp / NLVL;
    const int lvl = grp % NLVL;
    const int k    = c_k[lvl];
    const int base = c_base[lvl];
    if (64 * w >= k) return;
    const int jn = min(64, k - 64 * w);
    const int R  = min(64 * (w + 1), k);
    const float lo = (float)lvl * 2048.0f;

    __shared__ float jx1[64], jy1[64], jx2[64], jy2[64], jar[64];
    const int tid = threadIdx.x;
    if (tid < jn) {
        const float4 b = *(const float4*)(cand_box + ((size_t)img * M_TOT + base + 64 * w + tid) * 4);
        float x1 = b.x + lo, y1 = b.y + lo, x2 = b.z + lo, y2 = b.w + lo;
        jx1[tid] = x1; jy1[tid] = y1; jx2[tid] = x2; jy2[tid] = y2;
        jar[tid] = (x2 - x1) * (y2 - y1);
    }
    __syncthreads();

    for (int r = tid; r < R; r += 256) {
        const float4 b = *(const float4*)(cand_box + ((size_t)img * M_TOT + base + r) * 4);
        float rx1 = b.x + lo, ry1 = b.y + lo, rx2 = b.z + lo, ry2 = b.w + lo;
        float ra = (rx2 - rx1) * (ry2 - ry1);
        uint64_t bits = 0ull;
        #pragma unroll 8
        for (int jj = 0; jj < jn; ++jj) {
            int j = 64 * w + jj;
            if (j > r) {
                float ltx = fmaxf(rx1, jx1[jj]);
                float lty = fmaxf(ry1, jy1[jj]);
                float rbx = fminf(rx2, jx2[jj]);
                float rby = fminf(ry2, jy2[jj]);
                float wx = fmaxf(rbx - ltx, 0.0f);
                float wy = fmaxf(rby - lty, 0.0f);
                float inter = wx * wy;
                float denom = ((ra + jar[jj]) - inter) + 1e-9f;
                if (inter / denom > 0.7f) bits |= (1ull << jj);
            }
        }
        const int q = r >> 6;
        if (q == w) {
            diag[(size_t)grp * 1024 + r] = bits;
        } else {
            const int m = r & 63;
            const int tb = 15 * r - 32 * q * (q - 1) - m * q;  // tri_base(r)
            tri[(size_t)grp * TRI_W + tb + (w - q - 1)] = bits;
        }
    }
}

// ---------------------------------------------------------------------------
// NMS phase 2: greedy scan, one wave per group, no barriers in the loop.
// Per 64-row block q: parallel OR of prior kept rows' column-q words, then a
// SCALAR work-proportional diagonal scan: rem = candidate bits; repeatedly
// take lowest set bit m (kept), OR away rows it suppresses (readlane of the
// lane-distributed diagonal word). All SALU + uniform readlane — no VALU
// 64-bit chain, no vcc branches.
// ---------------------------------------------------------------------------
__global__ void kScan(const float* __restrict__ cand_score,
                      const uint64_t* __restrict__ tri,
                      const uint64_t* __restrict__ diag,
                      uint32_t* __restrict__ kept) {
    const int grp = blockIdx.x;
    const int img = grp / NLVL;
    const int lvl = grp % NLVL;
    const int k    = c_k[lvl];
    const int base = c_base[lvl];
    __shared__ __align__(16) uint64_t tl[TRI_W];
    const int tid = threadIdx.x;
    // stage tri as uint4 (16B per lane per iter)
    const uint4* tg4 = (const uint4*)(tri + (size_t)grp * TRI_W);
    uint4* tl4 = (uint4*)tl;
    for (int i = tid; i < TRI_W / 2; i += 256) tl4[i] = tg4[i];
    __syncthreads();
    if (tid >= 64) return;           // wave 0 does the scan; no barriers follow
    const int lane = tid;

    // preload diagonal words: darr[s] = diag row (64s + lane)
    uint64_t darr[16];
    #pragma unroll
    for (int s = 0; s < 16; ++s)
        darr[s] = (64 * s + lane < k) ? diag[(size_t)grp * 1024 + 64 * s + lane] : 0ull;

    // invalid-row words (invalid rows pre-suppressed, never suppress others)
    float sc[16];
    #pragma unroll
    for (int s = 0; s < 16; ++s) {
        int r = 64 * s + lane;
        sc[s] = (r < k) ? cand_score[(size_t)img * M_TOT + base + r] : NEGV;
    }
    uint64_t inv[16];
    #pragma unroll
    for (int s = 0; s < 16; ++s)
        inv[s] = (uint64_t)__ballot(sc[s] <= -5e8f);

    uint64_t keep_w[16];
    #pragma unroll
    for (int s = 0; s < 16; ++s) keep_w[s] = 0ull;

    #pragma unroll
    for (int q = 0; q < 16; ++q) {
        if (64 * q < k) {
            // v = OR over kept rows r' < 64q of their column-q word
            uint64_t v = 0ull;
            #pragma unroll
            for (int s = 0; s < q; ++s) {
                if ((keep_w[s] >> lane) & 1ull) {
                    const int rp = 64 * s + lane;
                    const int tb = 15 * rp - 32 * s * (s - 1) - lane * s;
                    v |= tl[tb + (q - s - 1)];
                }
            }
            #pragma unroll
            for (int off2 = 32; off2 >= 1; off2 >>= 1)
                v |= (uint64_t)__shfl_xor((unsigned long long)v, off2, 64);
            const uint64_t cur0 = inv[q] | v;
            // uniform scalar candidate mask: bits not yet suppressed/invalid
            uint32_t clo = __builtin_amdgcn_readfirstlane((uint32_t)cur0);
            uint32_t chi = __builtin_amdgcn_readfirstlane((uint32_t)(cur0 >> 32));
            uint64_t rem = ~(((uint64_t)chi << 32) | (uint64_t)clo);
            const uint32_t dlo = (uint32_t)darr[q];
            const uint32_t dhi = (uint32_t)(darr[q] >> 32);
            uint64_t kw = 0ull;
            // work-proportional scalar greedy: pick lowest candidate, kill
            // the rows it suppresses (diag bits are strictly > m).
            while (rem) {
                const int m = (int)__builtin_ctzll(rem);
                kw |= (1ull << m);
                const uint64_t dg =
                    ((uint64_t)(uint32_t)__builtin_amdgcn_readlane((int)dhi, m) << 32)
                  |  (uint64_t)(uint32_t)__builtin_amdgcn_readlane((int)dlo, m);
                rem &= ~(dg | (1ull << m));
            }
            keep_w[q] = kw;
        }
    }

    #pragma unroll
    for (int s = 0; s < 16; ++s) {
        int r = 64 * s + lane;
        if (r < k)
            kept[(size_t)img * M_TOT + base + r] = (uint32_t)((keep_w[s] >> lane) & 1ull);
    }
}

// ---------------------------------------------------------------------------
// Merge-rank + stable partition + output, one block (1024 thr) per image.
// ---------------------------------------------------------------------------
__device__ __forceinline__ int bs_count_ge(const uint32_t* a, int n, uint32_t x) {
    int lo = 0, hi = n;
    while (lo < hi) { int mid = (lo + hi) >> 1; if (a[mid] >= x) lo = mid + 1; else hi = mid; }
    return lo;
}
__device__ __forceinline__ int bs_count_gt(const uint32_t* a, int n, uint32_t x) {
    int lo = 0, hi = n;
    while (lo < hi) { int mid = (lo + hi) >> 1; if (a[mid] > x) lo = mid + 1; else hi = mid; }
    return lo;
}

__global__ void kMergeOut(const float* __restrict__ cand_box,
                          const float* __restrict__ cand_score,
                          const uint32_t* __restrict__ kept,
                          float* __restrict__ out) {
    const int img = blockIdx.x;
    const int tid = threadIdx.x;   // 1024
    const int lane = tid & 63, wave = tid >> 6;

    __shared__ uint32_t vkey[NLVL * 1024];  // compacted valid keys, desc
    __shared__ uint32_t ord[M_TOT];         // merged order: slot | kept<<31
    __shared__ int ssum[1024];
    __shared__ uint32_t wsum[NLVL][16];

    // ---- Phase 1: per-level valid ballot-scan ----
    uint32_t mykey[NLVL];
    int myvalid[NLVL], mylower[NLVL];
    #pragma unroll
    for (int L = 0; L < NLVL; ++L) {
        const int kL = c_k[L];
        const bool act = tid < kL;
        float s = act ? cand_score[(size_t)img * M_TOT + c_base[L] + tid] : NEGV;
        bool valid = act && (s > -5e8f);
        uint64_t mask = __ballot(valid);
        mylower[L] = (int)__popcll(mask & ((1ull << lane) - 1ull));
        if (lane == 0) wsum[L][wave] = (uint32_t)__popcll(mask);
        mykey[L] = flipf(s);
        myvalid[L] = valid ? 1 : 0;
    }
    __syncthreads();

    int nv[NLVL], myvpre[NLVL];
    #pragma unroll
    for (int L = 0; L < NLVL; ++L) {
        int pw = 0, tot = 0;
        #pragma unroll
        for (int w = 0; w < 16; ++w) {
            if (w < wave) pw += (int)wsum[L][w];
            tot += (int)wsum[L][w];
        }
        nv[L] = tot;
        myvpre[L] = pw + mylower[L];
        if (tid < c_k[L] && myvalid[L])
            vkey[L * 1024 + myvpre[L]] = mykey[L];
    }
    int totalValid = 0;
    #pragma unroll
    for (int L = 0; L < NLVL; ++L) totalValid += nv[L];
    __syncthreads();

    // ---- Phase 2: merge-rank each element, scatter into ord ----
    int invBase = totalValid;
    #pragma unroll
    for (int L = 0; L < NLVL; ++L) {
        const int kL = c_k[L];
        if (tid < kL) {
            const int slot = c_base[L] + tid;
            if (myvalid[L]) {
                const uint32_t x = mykey[L];
                int pos = myvpre[L];
                #pragma unroll
                for (int Lp = 0; Lp < NLVL; ++Lp) {
                    if (Lp == L) continue;
                    pos += (Lp < L) ? bs_count_ge(&vkey[Lp * 1024], nv[Lp], x)
                                    : bs_count_gt(&vkey[Lp * 1024], nv[Lp], x);
                }
                const uint32_t kp = kept[(size_t)img * M_TOT + slot];
                ord[pos] = (uint32_t)slot | (kp << 31);
            } else {
                const int inv_idx = tid - myvpre[L];
                ord[invBase + inv_idx] = (uint32_t)slot;  // kept=0
            }
        }
        invBase += (c_k[L] - nv[L]);
    }
    __syncthreads();

    // ---- Phase 3: stable partition by kept flag, write output ----
    const int PT = 5;
    const int pos0 = tid * PT;
    int flags[PT];
    uint32_t slots[PT];
    int lsum = 0;
    #pragma unroll
    for (int q = 0; q < PT; ++q) {
        int pp = pos0 + q;
        int kf = 0; uint32_t sl = 0;
        if (pp < M_TOT) {
            uint32_t o = ord[pp];
            sl = o & 0x7FFFFFFFu;
            kf = (int)(o >> 31);
        }
        flags[q] = kf; slots[q] = sl; lsum += kf;
    }
    ssum[tid] = lsum;
    __syncthreads();
    for (int off = 1; off < 1024; off <<= 1) {
        int v = (tid >= off) ? ssum[tid - off] : 0;
        __syncthreads();
        ssum[tid] += v;
        __syncthreads();
    }
    const int excl = ssum[tid] - lsum;
    const int total = ssum[1023];

    int run = 0;
    #pragma unroll
    for (int q = 0; q < PT; ++q) {
        int pp = pos0 + q;
        if (pp >= M_TOT) break;
        int kf = flags[q];
        int kbefore = excl + run;
        run += kf;
        int oidx = kf ? kbefore : (total + (pp - kbefore));
        if (oidx < POST_K) {
            uint32_t sl = slots[q];
            const float4 b = *(const float4*)(cand_box + ((size_t)img * M_TOT + sl) * 4);
            float* ob = out + ((size_t)img * POST_K + oidx) * 4;
            ob[0] = b.x; ob[1] = b.y; ob[2] = b.z; ob[3] = b.w;
            out[NIMG * POST_K * 4 + (size_t)img * POST_K + oidx] =
                kf ? cand_score[(size_t)img * M_TOT + sl] : NEGV;
        }
    }
}

extern "C" void kernel_launch(void* const* d_in, const int* in_sizes, int n_in,
                              void* d_out, int out_size, void* d_ws, size_t ws_size,
                              hipStream_t stream) {
    Ptrs p;
    for (int l = 0; l < NLVL; ++l) {
        p.logits[l]  = (const float*)d_in[3 * l + 0];
        p.deltas[l]  = (const float*)d_in[3 * l + 1];
        p.anchors[l] = (const float*)d_in[3 * l + 2];
    }

    // workspace layout (~2.6 MB)
    char* w = (char*)d_ws;
    float* cand_box   = (float*)w;        w += (size_t)NIMG * M_TOT * 4 * sizeof(float);
    float* cand_score = (float*)w;        w += (size_t)NIMG * M_TOT * sizeof(float);
    uint32_t* kept        = (uint32_t*)w; w += (size_t)NIMG * M_TOT * sizeof(uint32_t);
    uint64_t* cand_pk     = (uint64_t*)w; w += (size_t)NGRP * CAP * sizeof(uint64_t);
    uint64_t* tri         = (uint64_t*)w; w += (size_t)NGRP * TRI_W * sizeof(uint64_t);
    uint64_t* diag        = (uint64_t*)w; w += (size_t)NGRP * 1024 * sizeof(uint64_t);
    // zeroed region (one contiguous memset): ghist + counters + flags + thr
    char* zbase = w;
    uint32_t* ghist       = (uint32_t*)w; w += (size_t)NGRP * NBIN * sizeof(uint32_t);
    uint32_t* cand_cnt    = (uint32_t*)w; w += (size_t)NGRP * CNT_STRIDE * sizeof(uint32_t);
    uint32_t* need_fb     = (uint32_t*)w; w += 128;
    uint32_t* thr         = (uint32_t*)w; w += 128;
    size_t zbytes = (size_t)(w - zbase);

    hipMemsetAsync(zbase, 0, zbytes, stream);

    kCompactSpec<<<NIMG * BPI, 256, 0, stream>>>(p, cand_cnt, cand_pk);
    kCheck      <<<1,          64, 0, stream>>>(cand_cnt, need_fb);
    kHistFB     <<<NIMG * BPI, 256, 0, stream>>>(p, need_fb, ghist);
    kSelectFB   <<<NGRP,       256, 0, stream>>>(need_fb, ghist, thr);
    kCompactFB  <<<NIMG * BPI, 256, 0, stream>>>(p, need_fb, thr, cand_cnt, cand_pk);
    kRankDecode <<<NGRP * RD_SPLIT, 256, 0, stream>>>(p, cand_cnt, cand_pk, cand_box, cand_score);
    kIou        <<<NGRP * 16,  256, 0, stream>>>(cand_box, tri, diag);
    kScan       <<<NGRP,       256, 0, stream>>>(cand_score, tri, diag, kept);
    kMergeOut   <<<NIMG,      1024, 0, stream>>>(cand_box, cand_score, kept, (float*)d_out);
}

// Round 8
// 235.019 us; speedup vs baseline: 6.6015x; 1.0519x over previous
//
#include <hip/hip_runtime.h>
#include <stdint.h>
#include <math.h>

#define NLVL 5
#define NIMG 4
#define NGRP (NIMG * NLVL)
#define M_TOT 4768
#define POST_K 1000
#define NEGV  (-1e9f)
#define CAP 2048
#define BPI 65          // data-pass blocks per image
#define TRI_W 7680      // sum over q of 64q words, column-block-major
#define CNT_STRIDE 32   // cand_cnt counters spread one per 128B line
#define RD_SPLIT 8      // rank-decode sub-blocks per group

__constant__ int c_hwa[NLVL]  = {196608, 49152, 12288, 3072, 768};
__constant__ int c_k[NLVL]    = {1000, 1000, 1000, 1000, 768};
__constant__ int c_base[NLVL] = {0, 1000, 2000, 3000, 4000};
__constant__ int c_cnt[NLVL]  = {4096, 4096, 4096, 3072, 768};
// Speculative per-level key thresholds (flipf of score): expected candidate
// count ~1550 per group for N(0,1) logits; validated + repaired by kFixup.
__constant__ uint32_t c_T0[NLVL] = {0xC019999Au, 0xBFECCCCDu, 0xBF933333u, 0x80000000u, 0x00000000u};

struct Ptrs {
    const float* logits[NLVL];
    const float* deltas[NLVL];
    const float* anchors[NLVL];
};

__device__ __forceinline__ uint32_t flipf(float f) {
    uint32_t b = __float_as_uint(f);
    return (b & 0x80000000u) ? ~b : (b | 0x80000000u);
}
__device__ __forceinline__ float unflipf(uint32_t key) {
    uint32_t b = (key & 0x80000000u) ? (key & 0x7FFFFFFFu) : ~key;
    return __uint_as_float(b);
}

__device__ __forceinline__ void grp_decompose(int g, int& img, int& lvl, int& off, int& cnt) {
    img = g / BPI;
    int r = g % BPI;
    if (r < 48)      { lvl = 0; off = r * 4096; }
    else if (r < 60) { lvl = 1; off = (r - 48) * 4096; }
    else if (r < 63) { lvl = 2; off = (r - 60) * 4096; }
    else if (r < 64) { lvl = 3; off = 0; }
    else             { lvl = 4; off = 0; }
    cnt = c_cnt[lvl];
}

// wave64 OR-reduce via DPP (LLVM reduction sequence), result uniform.
__device__ __forceinline__ uint32_t wave_or32(uint32_t v) {
    v |= (uint32_t)__builtin_amdgcn_update_dpp(0, (int)v, 0x111, 0xf, 0xf, true); // row_shr:1
    v |= (uint32_t)__builtin_amdgcn_update_dpp(0, (int)v, 0x112, 0xf, 0xf, true); // row_shr:2
    v |= (uint32_t)__builtin_amdgcn_update_dpp(0, (int)v, 0x114, 0xf, 0xf, true); // row_shr:4
    v |= (uint32_t)__builtin_amdgcn_update_dpp(0, (int)v, 0x118, 0xf, 0xf, true); // row_shr:8
    v |= (uint32_t)__builtin_amdgcn_update_dpp(0, (int)v, 0x142, 0xf, 0xf, true); // row_bcast:15
    v |= (uint32_t)__builtin_amdgcn_update_dpp(0, (int)v, 0x143, 0xf, 0xf, true); // row_bcast:31
    return (uint32_t)__builtin_amdgcn_readlane((int)v, 63);
}

// ---------------------------------------------------------------------------
// Speculative single-pass compaction: keys >= c_T0[lvl] staged in LDS, one
// global atomic per block. Exactness guaranteed downstream by kRankDecode
// as long as count(>=T0) ∈ [k, CAP] — validated/repaired by kFixup.
// ---------------------------------------------------------------------------
__global__ void kCompactSpec(Ptrs p, uint32_t* __restrict__ cand_cnt,
                             uint64_t* __restrict__ cand_pk) {
    int img, lvl, off, cnt;
    grp_decompose(blockIdx.x, img, lvl, off, cnt);
    const int grp = img * NLVL + lvl;
    const int tid = threadIdx.x;
    const float* lg = p.logits[lvl] + (size_t)img * c_hwa[lvl] + off;
    const uint32_t T = c_T0[lvl];
    uint64_t* pk = cand_pk + (size_t)grp * CAP;

    __shared__ uint32_t scnt, sbase;
    __shared__ uint64_t sbuf[4096];
    if (tid == 0) scnt = 0u;
    __syncthreads();

    const int nvec = cnt >> 2;
    const float4* lg4 = (const float4*)lg;
    for (int v = tid; v < nvec; v += 256) {
        float4 x = lg4[v];
        float xs[4] = {x.x, x.y, x.z, x.w};
        #pragma unroll
        for (int c = 0; c < 4; ++c) {
            uint32_t key = flipf(xs[c]);
            if (key >= T) {
                uint32_t pos = atomicAdd(&scnt, 1u);
                uint32_t eidx = (uint32_t)(off + 4 * v + c);
                sbuf[pos] = ((uint64_t)key << 32) | (uint32_t)(~eidx);
            }
        }
    }
    __syncthreads();
    if (tid == 0) sbase = atomicAdd(&cand_cnt[grp * CNT_STRIDE], scnt);
    __syncthreads();
    const uint32_t n = scnt, b0 = sbase;
    for (uint32_t i = tid; i < n; i += 256) {
        uint32_t g = b0 + i;
        if (g < CAP) pk[g] = sbuf[i];
    }
}

// ---------------------------------------------------------------------------
// Fused fallback: one block per group. If speculation failed (count outside
// [k, CAP]), redo an exact 4-pass MSB radix select + recompaction within
// this block. Common path: one load + return (~µs for the whole grid).
// ---------------------------------------------------------------------------
__global__ void kFixup(Ptrs p, uint32_t* __restrict__ cand_cnt,
                       uint64_t* __restrict__ cand_pk) {
    const int grp = blockIdx.x;
    const int lvl = grp % NLVL;
    const int img = grp / NLVL;
    const int k = c_k[lvl];
    {
        uint32_t c = cand_cnt[grp * CNT_STRIDE];
        if (c >= (uint32_t)k && c <= CAP) return;   // speculation OK
    }
    const int n = c_hwa[lvl];
    const float* lg = p.logits[lvl] + (size_t)img * n;
    const int tid = threadIdx.x, bs = blockDim.x;

    __shared__ uint32_t hist[256];
    __shared__ uint32_t sh_pre, sh_rem;
    if (tid == 0) { sh_pre = 0u; sh_rem = (uint32_t)k; cand_cnt[grp * CNT_STRIDE] = 0u; }

    for (int pass = 0; pass < 4; ++pass) {
        for (int i = tid; i < 256; i += bs) hist[i] = 0u;
        __syncthreads();
        const int shift = 24 - 8 * pass;
        const uint32_t pre = sh_pre;
        for (int i = tid; i < n; i += bs) {
            uint32_t key = flipf(lg[i]);
            if (pass == 0 || (key >> (shift + 8)) == pre)
                atomicAdd(&hist[(key >> shift) & 255u], 1u);
        }
        __syncthreads();
        if (tid == 0) {
            uint32_t rem = sh_rem;
            int d = 255;
            for (; d > 0; --d) {
                uint32_t c = hist[d];
                if (rem <= c) break;
                rem -= c;
            }
            sh_rem = rem;
            sh_pre = (pre << 8) | (uint32_t)d;
        }
        __syncthreads();
    }
    const uint32_t T = sh_pre;
    uint64_t* pk = cand_pk + (size_t)grp * CAP;
    for (int i = tid; i < n; i += bs) {
        uint32_t key = flipf(lg[i]);
        if (key >= T) {
            uint32_t pos = atomicAdd(&cand_cnt[grp * CNT_STRIDE], 1u);
            if (pos < CAP) pk[pos] = ((uint64_t)key << 32) | (uint32_t)(~(uint32_t)i);
        }
    }
}

// ---------------------------------------------------------------------------
// Exact rank among candidates; decode boxes for rank < k. Bit-exact ref math.
// RD_SPLIT blocks per group: each block ranks a 256-candidate slice.
// ---------------------------------------------------------------------------
__global__ void kRankDecode(Ptrs p, const uint32_t* __restrict__ cand_cnt,
                            const uint64_t* __restrict__ cand_pk,
                            float* __restrict__ cand_box,
                            float* __restrict__ cand_score) {
    #pragma clang fp contract(off)
    const int blk = blockIdx.x;          // grp * RD_SPLIT + sub
    const int grp = blk / RD_SPLIT;
    const int sub = blk % RD_SPLIT;
    const int img = grp / NLVL;
    const int lvl = grp % NLVL;
    const int n    = c_hwa[lvl];
    const int k    = c_k[lvl];
    const int base = c_base[lvl];
    const int tid = threadIdx.x;

    const int cc = (int)min(cand_cnt[grp * CNT_STRIDE], (uint32_t)CAP);
    const int c0 = sub * (CAP / RD_SPLIT);
    if (c0 >= cc) return;

    __shared__ uint64_t K[CAP];
    const uint64_t* pk = cand_pk + (size_t)grp * CAP;
    for (int i = tid; i < cc; i += 256) K[i] = pk[i];
    __syncthreads();

    const int c = c0 + tid;
    const uint64_t myK = (c < cc) ? K[c] : ~0ull;
    int r = 0;
    int j = 0;
    for (; j + 8 <= cc; j += 8) {
        #pragma unroll
        for (int u = 0; u < 8; ++u) r += (int)(K[j + u] > myK);
    }
    for (; j < cc; ++j) r += (int)(K[j] > myK);

    if (c >= cc || r >= k) return;

    uint32_t key = (uint32_t)(myK >> 32);
    uint32_t ic  = ~(uint32_t)(myK & 0xFFFFFFFFu);
    const float* an = p.anchors[lvl] + (size_t)ic * 4;
    const float* dl = p.deltas[lvl] + ((size_t)img * n + ic) * 4;
    float a0 = an[0], a1 = an[1], a2 = an[2], a3 = an[3];
    float wa = a2 - a0, ha = a3 - a1;
    float cxa = a0 + 0.5f * wa, cya = a1 + 0.5f * ha;
    float dx = dl[0], dy = dl[1], dw = dl[2], dh = dl[3];
    const float SC = (float)4.135166556742356;  // log(1000/16)
    dw = fminf(dw, SC);
    dh = fminf(dh, SC);
    float cx = dx * wa + cxa, cy = dy * ha + cya;
    float w = wa * expf(dw), h = ha * expf(dh);
    float x1 = cx - 0.5f * w, y1 = cy - 0.5f * h;
    float x2 = cx + 0.5f * w, y2 = cy + 0.5f * h;
    x1 = fminf(fmaxf(x1, 0.0f), 1024.0f);
    y1 = fminf(fmaxf(y1, 0.0f), 1024.0f);
    x2 = fminf(fmaxf(x2, 0.0f), 1024.0f);
    y2 = fminf(fmaxf(y2, 0.0f), 1024.0f);
    float bw = x2 - x1, bh = y2 - y1;
    float score = (bw > 0.0f && bh > 0.0f) ? unflipf(key) : NEGV;
    const int slot = base + r;
    float* ob = cand_box + ((size_t)img * M_TOT + slot) * 4;
    ob[0] = x1; ob[1] = y1; ob[2] = x2; ob[3] = y2;
    cand_score[(size_t)img * M_TOT + slot] = score;
}

// ---------------------------------------------------------------------------
// NMS phase 1: suppression bit-matrix. COLUMN-BLOCK-MAJOR layout:
// for column block w, rows r < 64w stored at tri[32*w*(w-1) + r] (coalesced
// for the scan's gather); diagonal rows (r>>6 == w) go to diag[grp][r].
// ---------------------------------------------------------------------------
__global__ void kIou(const float* __restrict__ cand_box,
                     uint64_t* __restrict__ tri, uint64_t* __restrict__ diag) {
    #pragma clang fp contract(off)
    const int blk = blockIdx.x;      // grp*16 + w
    const int grp = blk >> 4;
    const int w   = blk & 15;
    const int img = grp / NLVL;
    const int lvl = grp % NLVL;
    const int k    = c_k[lvl];
    const int base = c_base[lvl];
    if (64 * w >= k) return;
    const int jn = min(64, k - 64 * w);
    const int R  = min(64 * (w + 1), k);
    const float lo = (float)lvl * 2048.0f;

    __shared__ float jx1[64], jy1[64], jx2[64], jy2[64], jar[64];
    const int tid = threadIdx.x;
    if (tid < jn) {
        const float4 b = *(const float4*)(cand_box + ((size_t)img * M_TOT + base + 64 * w + tid) * 4);
        float x1 = b.x + lo, y1 = b.y + lo, x2 = b.z + lo, y2 = b.w + lo;
        jx1[tid] = x1; jy1[tid] = y1; jx2[tid] = x2; jy2[tid] = y2;
        jar[tid] = (x2 - x1) * (y2 - y1);
    }
    __syncthreads();

    uint64_t* triq = tri + (size_t)grp * TRI_W + 32 * w * (w - 1);
    for (int r = tid; r < R; r += 256) {
        const float4 b = *(const float4*)(cand_box + ((size_t)img * M_TOT + base + r) * 4);
        float rx1 = b.x + lo, ry1 = b.y + lo, rx2 = b.z + lo, ry2 = b.w + lo;
        float ra = (rx2 - rx1) * (ry2 - ry1);
        uint64_t bits = 0ull;
        #pragma unroll 8
        for (int jj = 0; jj < jn; ++jj) {
            int j = 64 * w + jj;
            if (j > r) {
                float ltx = fmaxf(rx1, jx1[jj]);
                float lty = fmaxf(ry1, jy1[jj]);
                float rbx = fminf(rx2, jx2[jj]);
                float rby = fminf(ry2, jy2[jj]);
                float wx = fmaxf(rbx - ltx, 0.0f);
                float wy = fmaxf(rby - lty, 0.0f);
                float inter = wx * wy;
                float denom = ((ra + jar[jj]) - inter) + 1e-9f;
                if (inter / denom > 0.7f) bits |= (1ull << jj);
            }
        }
        if ((r >> 6) == w) diag[(size_t)grp * 1024 + r] = bits;
        else               triq[r] = bits;
    }
}

// ---------------------------------------------------------------------------
// NMS phase 2: greedy scan, one wave per group. Per 64-row block q:
// branch-free coalesced LDS gather (mask from per-lane mykept bitmap),
// DPP OR-reduce (no ds_bpermute), scalar work-proportional greedy.
// ---------------------------------------------------------------------------
__global__ void kScan(const float* __restrict__ cand_score,
                      const uint64_t* __restrict__ tri,
                      const uint64_t* __restrict__ diag,
                      uint32_t* __restrict__ kept) {
    const int grp = blockIdx.x;
    const int img = grp / NLVL;
    const int lvl = grp % NLVL;
    const int k    = c_k[lvl];
    const int base = c_base[lvl];
    __shared__ __align__(16) uint64_t tl[TRI_W];
    const int tid = threadIdx.x;
    // stage tri as uint4 (16B per lane per iter)
    const uint4* tg4 = (const uint4*)(tri + (size_t)grp * TRI_W);
    uint4* tl4 = (uint4*)tl;
    for (int i = tid; i < TRI_W / 2; i += 256) tl4[i] = tg4[i];
    __syncthreads();
    if (tid >= 64) return;           // wave 0 does the scan; no barriers follow
    const int lane = tid;

    // preload diagonal words: darr[s] = diag row (64s + lane)
    uint64_t darr[16];
    #pragma unroll
    for (int s = 0; s < 16; ++s)
        darr[s] = (64 * s + lane < k) ? diag[(size_t)grp * 1024 + 64 * s + lane] : 0ull;

    // invalid-row ballots (invalid rows pre-suppressed, never suppress others)
    uint64_t inv[16];
    #pragma unroll
    for (int s = 0; s < 16; ++s) {
        int r = 64 * s + lane;
        float sc = (r < k) ? cand_score[(size_t)img * M_TOT + base + r] : NEGV;
        inv[s] = (uint64_t)__ballot(sc <= -5e8f);
    }

    uint32_t mykept = 0u;   // bit s = row (64s + lane) kept

    #define SCAN_STAGE(Q)                                                        \
    if (64 * (Q) < k) {                                                          \
        uint64_t v = 0ull;                                                       \
        const uint64_t* tq = tl + 32 * (Q) * ((Q) - 1);                          \
        for (int s = 0; s < (Q); ++s) {                                          \
            uint64_t msk = (uint64_t)0 - (uint64_t)((mykept >> s) & 1u);         \
            v |= tq[64 * s + lane] & msk;                                        \
        }                                                                        \
        uint32_t vlo = wave_or32((uint32_t)v);                                   \
        uint32_t vhi = wave_or32((uint32_t)(v >> 32));                           \
        uint64_t rem = ~(inv[Q] | (((uint64_t)vhi << 32) | (uint64_t)vlo));      \
        const uint32_t dlo = (uint32_t)darr[Q], dhi = (uint32_t)(darr[Q] >> 32); \
        uint64_t kw = 0ull;                                                      \
        while (rem) {                                                            \
            int m = (int)__builtin_ctzll(rem);                                   \
            kw |= (1ull << m);                                                   \
            uint64_t dg =                                                        \
                ((uint64_t)(uint32_t)__builtin_amdgcn_readlane((int)dhi, m) << 32)\
              |  (uint64_t)(uint32_t)__builtin_amdgcn_readlane((int)dlo, m);     \
            rem &= ~(dg | (1ull << m));                                          \
        }                                                                        \
        mykept |= (uint32_t)((kw >> lane) & 1ull) << (Q);                        \
    }

    SCAN_STAGE(0)  SCAN_STAGE(1)  SCAN_STAGE(2)  SCAN_STAGE(3)
    SCAN_STAGE(4)  SCAN_STAGE(5)  SCAN_STAGE(6)  SCAN_STAGE(7)
    SCAN_STAGE(8)  SCAN_STAGE(9)  SCAN_STAGE(10) SCAN_STAGE(11)
    SCAN_STAGE(12) SCAN_STAGE(13) SCAN_STAGE(14) SCAN_STAGE(15)
    #undef SCAN_STAGE

    #pragma unroll
    for (int s = 0; s < 16; ++s) {
        int r = 64 * s + lane;
        if (r < k)
            kept[(size_t)img * M_TOT + base + r] = (mykept >> s) & 1u;
    }
}

// ---------------------------------------------------------------------------
// Merge-rank + stable partition + output, one block (1024 thr) per image.
// ---------------------------------------------------------------------------
__device__ __forceinline__ int bs_count_ge(const uint32_t* a, int n, uint32_t x) {
    int lo = 0, hi = n;
    while (lo < hi) { int mid = (lo + hi) >> 1; if (a[mid] >= x) lo = mid + 1; else hi = mid; }
    return lo;
}
__device__ __forceinline__ int bs_count_gt(const uint32_t* a, int n, uint32_t x) {
    int lo = 0, hi = n;
    while (lo < hi) { int mid = (lo + hi) >> 1; if (a[mid] > x) lo = mid + 1; else hi = mid; }
    return lo;
}

__global__ void kMergeOut(const float* __restrict__ cand_box,
                          const float* __restrict__ cand_score,
                          const uint32_t* __restrict__ kept,
                          float* __restrict__ out) {
    const int img = blockIdx.x;
    const int tid = threadIdx.x;   // 1024
    const int lane = tid & 63, wave = tid >> 6;

    __shared__ uint32_t vkey[NLVL * 1024];  // compacted valid keys, desc
    __shared__ uint32_t ord[M_TOT];         // merged order: slot | kept<<31
    __shared__ int ssum[1024];
    __shared__ uint32_t wsum[NLVL][16];

    // ---- Phase 1: per-level valid ballot-scan ----
    uint32_t mykey[NLVL];
    int myvalid[NLVL], mylower[NLVL];
    #pragma unroll
    for (int L = 0; L < NLVL; ++L) {
        const int kL = c_k[L];
        const bool act = tid < kL;
        float s = act ? cand_score[(size_t)img * M_TOT + c_base[L] + tid] : NEGV;
        bool valid = act && (s > -5e8f);
        uint64_t mask = __ballot(valid);
        mylower[L] = (int)__popcll(mask & ((1ull << lane) - 1ull));
        if (lane == 0) wsum[L][wave] = (uint32_t)__popcll(mask);
        mykey[L] = flipf(s);
        myvalid[L] = valid ? 1 : 0;
    }
    __syncthreads();

    int nv[NLVL], myvpre[NLVL];
    #pragma unroll
    for (int L = 0; L < NLVL; ++L) {
        int pw = 0, tot = 0;
        #pragma unroll
        for (int w = 0; w < 16; ++w) {
            if (w < wave) pw += (int)wsum[L][w];
            tot += (int)wsum[L][w];
        }
        nv[L] = tot;
        myvpre[L] = pw + mylower[L];
        if (tid < c_k[L] && myvalid[L])
            vkey[L * 1024 + myvpre[L]] = mykey[L];
    }
    int totalValid = 0;
    #pragma unroll
    for (int L = 0; L < NLVL; ++L) totalValid += nv[L];
    __syncthreads();

    // ---- Phase 2: merge-rank each element, scatter into ord ----
    int invBase = totalValid;
    #pragma unroll
    for (int L = 0; L < NLVL; ++L) {
        const int kL = c_k[L];
        if (tid < kL) {
            const int slot = c_base[L] + tid;
            if (myvalid[L]) {
                const uint32_t x = mykey[L];
                int pos = myvpre[L];
                #pragma unroll
                for (int Lp = 0; Lp < NLVL; ++Lp) {
                    if (Lp == L) continue;
                    pos += (Lp < L) ? bs_count_ge(&vkey[Lp * 1024], nv[Lp], x)
                                    : bs_count_gt(&vkey[Lp * 1024], nv[Lp], x);
                }
                const uint32_t kp = kept[(size_t)img * M_TOT + slot];
                ord[pos] = (uint32_t)slot | (kp << 31);
            } else {
                const int inv_idx = tid - myvpre[L];
                ord[invBase + inv_idx] = (uint32_t)slot;  // kept=0
            }
        }
        invBase += (c_k[L] - nv[L]);
    }
    __syncthreads();

    // ---- Phase 3: stable partition by kept flag, write output ----
    const int PT = 5;
    const int pos0 = tid * PT;
    int flags[PT];
    uint32_t slots[PT];
    int lsum = 0;
    #pragma unroll
    for (int q = 0; q < PT; ++q) {
        int pp = pos0 + q;
        int kf = 0; uint32_t sl = 0;
        if (pp < M_TOT) {
            uint32_t o = ord[pp];
            sl = o & 0x7FFFFFFFu;
            kf = (int)(o >> 31);
        }
        flags[q] = kf; slots[q] = sl; lsum += kf;
    }
    ssum[tid] = lsum;
    __syncthreads();
    for (int off = 1; off < 1024; off <<= 1) {
        int v = (tid >= off) ? ssum[tid - off] : 0;
        __syncthreads();
        ssum[tid] += v;
        __syncthreads();
    }
    const int excl = ssum[tid] - lsum;
    const int total = ssum[1023];

    int run = 0;
    #pragma unroll
    for (int q = 0; q < PT; ++q) {
        int pp = pos0 + q;
        if (pp >= M_TOT) break;
        int kf = flags[q];
        int kbefore = excl + run;
        run += kf;
        int oidx = kf ? kbefore : (total + (pp - kbefore));
        if (oidx < POST_K) {
            uint32_t sl = slots[q];
            const float4 b = *(const float4*)(cand_box + ((size_t)img * M_TOT + sl) * 4);
            float* ob = out + ((size_t)img * POST_K + oidx) * 4;
            ob[0] = b.x; ob[1] = b.y; ob[2] = b.z; ob[3] = b.w;
            out[NIMG * POST_K * 4 + (size_t)img * POST_K + oidx] =
                kf ? cand_score[(size_t)img * M_TOT + sl] : NEGV;
        }
    }
}

extern "C" void kernel_launch(void* const* d_in, const int* in_sizes, int n_in,
                              void* d_out, int out_size, void* d_ws, size_t ws_size,
                              hipStream_t stream) {
    Ptrs p;
    for (int l = 0; l < NLVL; ++l) {
        p.logits[l]  = (const float*)d_in[3 * l + 0];
        p.deltas[l]  = (const float*)d_in[3 * l + 1];
        p.anchors[l] = (const float*)d_in[3 * l + 2];
    }

    // workspace layout (~2.3 MB)
    char* w = (char*)d_ws;
    float* cand_box   = (float*)w;        w += (size_t)NIMG * M_TOT * 4 * sizeof(float);
    float* cand_score = (float*)w;        w += (size_t)NIMG * M_TOT * sizeof(float);
    uint32_t* kept        = (uint32_t*)w; w += (size_t)NIMG * M_TOT * sizeof(uint32_t);
    uint64_t* cand_pk     = (uint64_t*)w; w += (size_t)NGRP * CAP * sizeof(uint64_t);
    uint64_t* tri         = (uint64_t*)w; w += (size_t)NGRP * TRI_W * sizeof(uint64_t);
    uint64_t* diag        = (uint64_t*)w; w += (size_t)NGRP * 1024 * sizeof(uint64_t);
    uint32_t* cand_cnt    = (uint32_t*)w; w += (size_t)NGRP * CNT_STRIDE * sizeof(uint32_t);

    hipMemsetAsync(cand_cnt, 0, (size_t)NGRP * CNT_STRIDE * sizeof(uint32_t), stream);

    kCompactSpec<<<NIMG * BPI,       256, 0, stream>>>(p, cand_cnt, cand_pk);
    kFixup      <<<NGRP,             256, 0, stream>>>(p, cand_cnt, cand_pk);
    kRankDecode <<<NGRP * RD_SPLIT,  256, 0, stream>>>(p, cand_cnt, cand_pk, cand_box, cand_score);
    kIou        <<<NGRP * 16,        256, 0, stream>>>(cand_box, tri, diag);
    kScan       <<<NGRP,             256, 0, stream>>>(cand_score, tri, diag, kept);
    kMergeOut   <<<NIMG,            1024, 0, stream>>>(cand_box, cand_score, kept, (float*)d_out);
}

// Round 9
// 228.307 us; speedup vs baseline: 6.7955x; 1.0294x over previous
//
#include <hip/hip_runtime.h>
#include <stdint.h>
#include <math.h>

#define NLVL 5
#define NIMG 4
#define NGRP (NIMG * NLVL)
#define M_TOT 4768
#define POST_K 1000
#define NEGV  (-1e9f)
#define CAP 2048
#define BPI 65          // data-pass blocks per image
#define TRI_W 7680      // sum over q of 64q words, column-block-major
#define CNT_STRIDE 32   // cand_cnt counters spread one per 128B line
#define RD_SPLIT 8      // rank-decode sub-blocks per group

__constant__ int c_hwa[NLVL]  = {196608, 49152, 12288, 3072, 768};
__constant__ int c_k[NLVL]    = {1000, 1000, 1000, 1000, 768};
__constant__ int c_base[NLVL] = {0, 1000, 2000, 3000, 4000};
__constant__ int c_cnt[NLVL]  = {4096, 4096, 4096, 3072, 768};
// Speculative per-level key thresholds (flipf of score): expected candidate
// count ~1550 per group for N(0,1) logits; validated + repaired by kFixup.
__constant__ uint32_t c_T0[NLVL] = {0xC019999Au, 0xBFECCCCDu, 0xBF933333u, 0x80000000u, 0x00000000u};

struct Ptrs {
    const float* logits[NLVL];
    const float* deltas[NLVL];
    const float* anchors[NLVL];
};

__device__ __forceinline__ uint32_t flipf(float f) {
    uint32_t b = __float_as_uint(f);
    return (b & 0x80000000u) ? ~b : (b | 0x80000000u);
}
__device__ __forceinline__ float unflipf(uint32_t key) {
    uint32_t b = (key & 0x80000000u) ? (key & 0x7FFFFFFFu) : ~key;
    return __uint_as_float(b);
}

__device__ __forceinline__ void grp_decompose(int g, int& img, int& lvl, int& off, int& cnt) {
    img = g / BPI;
    int r = g % BPI;
    if (r < 48)      { lvl = 0; off = r * 4096; }
    else if (r < 60) { lvl = 1; off = (r - 48) * 4096; }
    else if (r < 63) { lvl = 2; off = (r - 60) * 4096; }
    else if (r < 64) { lvl = 3; off = 0; }
    else             { lvl = 4; off = 0; }
    cnt = c_cnt[lvl];
}

// wave64 OR-reduce via DPP (LLVM reduction sequence), result uniform.
__device__ __forceinline__ uint32_t wave_or32(uint32_t v) {
    v |= (uint32_t)__builtin_amdgcn_update_dpp(0, (int)v, 0x111, 0xf, 0xf, true); // row_shr:1
    v |= (uint32_t)__builtin_amdgcn_update_dpp(0, (int)v, 0x112, 0xf, 0xf, true); // row_shr:2
    v |= (uint32_t)__builtin_amdgcn_update_dpp(0, (int)v, 0x114, 0xf, 0xf, true); // row_shr:4
    v |= (uint32_t)__builtin_amdgcn_update_dpp(0, (int)v, 0x118, 0xf, 0xf, true); // row_shr:8
    v |= (uint32_t)__builtin_amdgcn_update_dpp(0, (int)v, 0x142, 0xf, 0xf, true); // row_bcast:15
    v |= (uint32_t)__builtin_amdgcn_update_dpp(0, (int)v, 0x143, 0xf, 0xf, true); // row_bcast:31
    return (uint32_t)__builtin_amdgcn_readlane((int)v, 63);
}

// ---------------------------------------------------------------------------
// Speculative single-pass compaction: keys >= c_T0[lvl] staged in LDS, one
// global atomic per block. Exactness guaranteed downstream by kRankDecode
// as long as count(>=T0) ∈ [k, CAP] — validated/repaired by kFixup.
// ---------------------------------------------------------------------------
__global__ void kCompactSpec(Ptrs p, uint32_t* __restrict__ cand_cnt,
                             uint64_t* __restrict__ cand_pk) {
    int img, lvl, off, cnt;
    grp_decompose(blockIdx.x, img, lvl, off, cnt);
    const int grp = img * NLVL + lvl;
    const int tid = threadIdx.x;
    const float* lg = p.logits[lvl] + (size_t)img * c_hwa[lvl] + off;
    const uint32_t T = c_T0[lvl];
    uint64_t* pk = cand_pk + (size_t)grp * CAP;

    __shared__ uint32_t scnt, sbase;
    __shared__ uint64_t sbuf[4096];
    if (tid == 0) scnt = 0u;
    __syncthreads();

    const int nvec = cnt >> 2;
    const float4* lg4 = (const float4*)lg;
    for (int v = tid; v < nvec; v += 256) {
        float4 x = lg4[v];
        float xs[4] = {x.x, x.y, x.z, x.w};
        #pragma unroll
        for (int c = 0; c < 4; ++c) {
            uint32_t key = flipf(xs[c]);
            if (key >= T) {
                uint32_t pos = atomicAdd(&scnt, 1u);
                uint32_t eidx = (uint32_t)(off + 4 * v + c);
                sbuf[pos] = ((uint64_t)key << 32) | (uint32_t)(~eidx);
            }
        }
    }
    __syncthreads();
    if (tid == 0) sbase = atomicAdd(&cand_cnt[grp * CNT_STRIDE], scnt);
    __syncthreads();
    const uint32_t n = scnt, b0 = sbase;
    for (uint32_t i = tid; i < n; i += 256) {
        uint32_t g = b0 + i;
        if (g < CAP) pk[g] = sbuf[i];
    }
}

// ---------------------------------------------------------------------------
// Fused fallback: one block per group. If speculation failed (count outside
// [k, CAP]), redo an exact 4-pass MSB radix select + recompaction within
// this block. Common path: one load + return.
// ---------------------------------------------------------------------------
__global__ void kFixup(Ptrs p, uint32_t* __restrict__ cand_cnt,
                       uint64_t* __restrict__ cand_pk) {
    const int grp = blockIdx.x;
    const int lvl = grp % NLVL;
    const int img = grp / NLVL;
    const int k = c_k[lvl];
    {
        uint32_t c = cand_cnt[grp * CNT_STRIDE];
        if (c >= (uint32_t)k && c <= CAP) return;   // speculation OK
    }
    const int n = c_hwa[lvl];
    const float* lg = p.logits[lvl] + (size_t)img * n;
    const int tid = threadIdx.x, bs = blockDim.x;

    __shared__ uint32_t hist[256];
    __shared__ uint32_t sh_pre, sh_rem;
    if (tid == 0) { sh_pre = 0u; sh_rem = (uint32_t)k; cand_cnt[grp * CNT_STRIDE] = 0u; }

    for (int pass = 0; pass < 4; ++pass) {
        for (int i = tid; i < 256; i += bs) hist[i] = 0u;
        __syncthreads();
        const int shift = 24 - 8 * pass;
        const uint32_t pre = sh_pre;
        for (int i = tid; i < n; i += bs) {
            uint32_t key = flipf(lg[i]);
            if (pass == 0 || (key >> (shift + 8)) == pre)
                atomicAdd(&hist[(key >> shift) & 255u], 1u);
        }
        __syncthreads();
        if (tid == 0) {
            uint32_t rem = sh_rem;
            int d = 255;
            for (; d > 0; --d) {
                uint32_t c = hist[d];
                if (rem <= c) break;
                rem -= c;
            }
            sh_rem = rem;
            sh_pre = (pre << 8) | (uint32_t)d;
        }
        __syncthreads();
    }
    const uint32_t T = sh_pre;
    uint64_t* pk = cand_pk + (size_t)grp * CAP;
    for (int i = tid; i < n; i += bs) {
        uint32_t key = flipf(lg[i]);
        if (key >= T) {
            uint32_t pos = atomicAdd(&cand_cnt[grp * CNT_STRIDE], 1u);
            if (pos < CAP) pk[pos] = ((uint64_t)key << 32) | (uint32_t)(~(uint32_t)i);
        }
    }
}

// ---------------------------------------------------------------------------
// Exact rank among candidates; decode boxes for rank < k. Bit-exact ref math.
// RD_SPLIT blocks per group: each block ranks a 256-candidate slice.
// ---------------------------------------------------------------------------
__global__ void kRankDecode(Ptrs p, const uint32_t* __restrict__ cand_cnt,
                            const uint64_t* __restrict__ cand_pk,
                            float* __restrict__ cand_box,
                            float* __restrict__ cand_score) {
    #pragma clang fp contract(off)
    const int blk = blockIdx.x;          // grp * RD_SPLIT + sub
    const int grp = blk / RD_SPLIT;
    const int sub = blk % RD_SPLIT;
    const int img = grp / NLVL;
    const int lvl = grp % NLVL;
    const int n    = c_hwa[lvl];
    const int k    = c_k[lvl];
    const int base = c_base[lvl];
    const int tid = threadIdx.x;

    const int cc = (int)min(cand_cnt[grp * CNT_STRIDE], (uint32_t)CAP);
    const int c0 = sub * (CAP / RD_SPLIT);
    if (c0 >= cc) return;

    __shared__ uint64_t K[CAP];
    const uint64_t* pk = cand_pk + (size_t)grp * CAP;
    for (int i = tid; i < cc; i += 256) K[i] = pk[i];
    __syncthreads();

    const int c = c0 + tid;
    const uint64_t myK = (c < cc) ? K[c] : ~0ull;
    int r = 0;
    int j = 0;
    for (; j + 8 <= cc; j += 8) {
        #pragma unroll
        for (int u = 0; u < 8; ++u) r += (int)(K[j + u] > myK);
    }
    for (; j < cc; ++j) r += (int)(K[j] > myK);

    if (c >= cc || r >= k) return;

    uint32_t key = (uint32_t)(myK >> 32);
    uint32_t ic  = ~(uint32_t)(myK & 0xFFFFFFFFu);
    const float* an = p.anchors[lvl] + (size_t)ic * 4;
    const float* dl = p.deltas[lvl] + ((size_t)img * n + ic) * 4;
    float a0 = an[0], a1 = an[1], a2 = an[2], a3 = an[3];
    float wa = a2 - a0, ha = a3 - a1;
    float cxa = a0 + 0.5f * wa, cya = a1 + 0.5f * ha;
    float dx = dl[0], dy = dl[1], dw = dl[2], dh = dl[3];
    const float SC = (float)4.135166556742356;  // log(1000/16)
    dw = fminf(dw, SC);
    dh = fminf(dh, SC);
    float cx = dx * wa + cxa, cy = dy * ha + cya;
    float w = wa * expf(dw), h = ha * expf(dh);
    float x1 = cx - 0.5f * w, y1 = cy - 0.5f * h;
    float x2 = cx + 0.5f * w, y2 = cy + 0.5f * h;
    x1 = fminf(fmaxf(x1, 0.0f), 1024.0f);
    y1 = fminf(fmaxf(y1, 0.0f), 1024.0f);
    x2 = fminf(fmaxf(x2, 0.0f), 1024.0f);
    y2 = fminf(fmaxf(y2, 0.0f), 1024.0f);
    float bw = x2 - x1, bh = y2 - y1;
    float score = (bw > 0.0f && bh > 0.0f) ? unflipf(key) : NEGV;
    const int slot = base + r;
    float* ob = cand_box + ((size_t)img * M_TOT + slot) * 4;
    ob[0] = x1; ob[1] = y1; ob[2] = x2; ob[3] = y2;
    cand_score[(size_t)img * M_TOT + slot] = score;
}

// ---------------------------------------------------------------------------
// NMS phase 1: suppression bit-matrix. COLUMN-BLOCK-MAJOR layout:
// for column block w, rows r < 64w stored at tri[32*w*(w-1) + r] (coalesced
// for the scan's gather); diagonal rows (r>>6 == w) go to diag[grp][r].
// ---------------------------------------------------------------------------
__global__ void kIou(const float* __restrict__ cand_box,
                     uint64_t* __restrict__ tri, uint64_t* __restrict__ diag) {
    #pragma clang fp contract(off)
    const int blk = blockIdx.x;      // grp*16 + w
    const int grp = blk >> 4;
    const int w   = blk & 15;
    const int img = grp / NLVL;
    const int lvl = grp % NLVL;
    const int k    = c_k[lvl];
    const int base = c_base[lvl];
    if (64 * w >= k) return;
    const int jn = min(64, k - 64 * w);
    const int R  = min(64 * (w + 1), k);
    const float lo = (float)lvl * 2048.0f;

    __shared__ float jx1[64], jy1[64], jx2[64], jy2[64], jar[64];
    const int tid = threadIdx.x;
    if (tid < jn) {
        const float4 b = *(const float4*)(cand_box + ((size_t)img * M_TOT + base + 64 * w + tid) * 4);
        float x1 = b.x + lo, y1 = b.y + lo, x2 = b.z + lo, y2 = b.w + lo;
        jx1[tid] = x1; jy1[tid] = y1; jx2[tid] = x2; jy2[tid] = y2;
        jar[tid] = (x2 - x1) * (y2 - y1);
    }
    __syncthreads();

    uint64_t* triq = tri + (size_t)grp * TRI_W + 32 * w * (w - 1);
    for (int r = tid; r < R; r += 256) {
        const float4 b = *(const float4*)(cand_box + ((size_t)img * M_TOT + base + r) * 4);
        float rx1 = b.x + lo, ry1 = b.y + lo, rx2 = b.z + lo, ry2 = b.w + lo;
        float ra = (rx2 - rx1) * (ry2 - ry1);
        uint64_t bits = 0ull;
        #pragma unroll 8
        for (int jj = 0; jj < jn; ++jj) {
            int j = 64 * w + jj;
            if (j > r) {
                float ltx = fmaxf(rx1, jx1[jj]);
                float lty = fmaxf(ry1, jy1[jj]);
                float rbx = fminf(rx2, jx2[jj]);
                float rby = fminf(ry2, jy2[jj]);
                float wx = fmaxf(rbx - ltx, 0.0f);
                float wy = fmaxf(rby - lty, 0.0f);
                float inter = wx * wy;
                float denom = ((ra + jar[jj]) - inter) + 1e-9f;
                if (inter / denom > 0.7f) bits |= (1ull << jj);
            }
        }
        if ((r >> 6) == w) diag[(size_t)grp * 1024 + r] = bits;
        else               triq[r] = bits;
    }
}

// ---------------------------------------------------------------------------
// NMS phase 2: greedy scan, ONE WAVE per group (64 threads), rolled loops
// (small code / warm I-cache). Per 64-row block q: branch-free coalesced
// GLOBAL gather of prior kept rows' column words, DPP OR-reduce, then a
// sparse scalar greedy that only serializes over rows with nonzero diag
// (rows that can actually suppress); zero-diag candidates batch-kept.
// ---------------------------------------------------------------------------
__global__ void kScan(const float* __restrict__ cand_score,
                      const uint64_t* __restrict__ tri,
                      const uint64_t* __restrict__ diag,
                      uint32_t* __restrict__ kept) {
    const int grp = blockIdx.x;
    const int img = grp / NLVL;
    const int lvl = grp % NLVL;
    const int k    = c_k[lvl];
    const int base = c_base[lvl];
    const int lane = threadIdx.x;   // 64 threads = 1 wave

    __shared__ uint64_t sdiag[1024];
    __shared__ uint64_t sinv[16];

    // preload diag rows + invalid ballots (coalesced)
    const uint64_t* dg_g = diag + (size_t)grp * 1024;
    #pragma unroll
    for (int s = 0; s < 16; ++s) {
        const int r = 64 * s + lane;
        uint64_t d = (r < k) ? dg_g[r] : 0ull;
        sdiag[r] = d;
        float sc = (r < k) ? cand_score[(size_t)img * M_TOT + base + r] : NEGV;
        uint64_t iv = __ballot(sc <= -5e8f);
        if (lane == 0) sinv[s] = iv;
    }
    __syncthreads();

    const uint64_t* trig = tri + (size_t)grp * TRI_W;
    uint32_t mykept = 0u;   // bit s = row (64s + lane) kept
    const int nstage = (k + 63) >> 6;

    #pragma unroll 1
    for (int q = 0; q < nstage; ++q) {
        // gather: OR of kept prior rows' column-q words (coalesced global)
        uint64_t v = 0ull;
        const uint64_t* tq = trig + 32 * q * (q - 1);
        #pragma unroll 1
        for (int s = 0; s < q; ++s) {
            uint64_t msk = (uint64_t)0 - (uint64_t)((mykept >> s) & 1u);
            v |= tq[64 * s + lane] & msk;
        }
        const uint32_t vlo = wave_or32((uint32_t)v);
        const uint32_t vhi = wave_or32((uint32_t)(v >> 32));
        const uint64_t invq = sinv[q];
        const uint32_t ivlo = __builtin_amdgcn_readfirstlane((uint32_t)invq);
        const uint32_t ivhi = __builtin_amdgcn_readfirstlane((uint32_t)(invq >> 32));
        uint64_t rem = ~((((uint64_t)ivhi << 32) | (uint64_t)ivlo)
                       | (((uint64_t)vhi  << 32) | (uint64_t)vlo));

        const uint64_t darrq = sdiag[64 * q + lane];
        const uint32_t dlo = (uint32_t)darrq, dhi = (uint32_t)(darrq >> 32);
        const uint64_t nz = __ballot(darrq != 0ull);   // rows that can suppress

        uint64_t kw = 0ull;
        for (;;) {
            uint64_t t = rem & nz;
            if (t == 0ull) { kw |= rem; break; }       // rest can't suppress: all kept
            const int m = (int)__builtin_ctzll(t);
            const uint64_t bm = 1ull << m;
            const uint64_t lowm = bm - 1ull;
            kw |= (rem & lowm) | bm;                   // batch-keep below m, keep m
            const uint64_t dg =
                ((uint64_t)(uint32_t)__builtin_amdgcn_readlane((int)dhi, m) << 32)
              |  (uint64_t)(uint32_t)__builtin_amdgcn_readlane((int)dlo, m);
            rem &= ~(lowm | bm | dg);                  // drop processed + suppressed
        }
        mykept |= ((uint32_t)((kw >> lane) & 1ull)) << q;
    }

    #pragma unroll
    for (int s = 0; s < 16; ++s) {
        const int r = 64 * s + lane;
        if (r < k)
            kept[(size_t)img * M_TOT + base + r] = (mykept >> s) & 1u;
    }
}

// ---------------------------------------------------------------------------
// Merge-rank + stable partition + output, one block (1024 thr) per image.
// ---------------------------------------------------------------------------
__device__ __forceinline__ int bs_count_ge(const uint32_t* a, int n, uint32_t x) {
    int lo = 0, hi = n;
    while (lo < hi) { int mid = (lo + hi) >> 1; if (a[mid] >= x) lo = mid + 1; else hi = mid; }
    return lo;
}
__device__ __forceinline__ int bs_count_gt(const uint32_t* a, int n, uint32_t x) {
    int lo = 0, hi = n;
    while (lo < hi) { int mid = (lo + hi) >> 1; if (a[mid] > x) lo = mid + 1; else hi = mid; }
    return lo;
}

__global__ void kMergeOut(const float* __restrict__ cand_box,
                          const float* __restrict__ cand_score,
                          const uint32_t* __restrict__ kept,
                          float* __restrict__ out) {
    const int img = blockIdx.x;
    const int tid = threadIdx.x;   // 1024
    const int lane = tid & 63, wave = tid >> 6;

    __shared__ uint32_t vkey[NLVL * 1024];  // compacted valid keys, desc
    __shared__ uint32_t ord[M_TOT];         // merged order: slot | kept<<31
    __shared__ int ssum[1024];
    __shared__ uint32_t wsum[NLVL][16];

    // ---- Phase 1: per-level valid ballot-scan ----
    uint32_t mykey[NLVL];
    int myvalid[NLVL], mylower[NLVL];
    #pragma unroll
    for (int L = 0; L < NLVL; ++L) {
        const int kL = c_k[L];
        const bool act = tid < kL;
        float s = act ? cand_score[(size_t)img * M_TOT + c_base[L] + tid] : NEGV;
        bool valid = act && (s > -5e8f);
        uint64_t mask = __ballot(valid);
        mylower[L] = (int)__popcll(mask & ((1ull << lane) - 1ull));
        if (lane == 0) wsum[L][wave] = (uint32_t)__popcll(mask);
        mykey[L] = flipf(s);
        myvalid[L] = valid ? 1 : 0;
    }
    __syncthreads();

    int nv[NLVL], myvpre[NLVL];
    #pragma unroll
    for (int L = 0; L < NLVL; ++L) {
        int pw = 0, tot = 0;
        #pragma unroll
        for (int w = 0; w < 16; ++w) {
            if (w < wave) pw += (int)wsum[L][w];
            tot += (int)wsum[L][w];
        }
        nv[L] = tot;
        myvpre[L] = pw + mylower[L];
        if (tid < c_k[L] && myvalid[L])
            vkey[L * 1024 + myvpre[L]] = mykey[L];
    }
    int totalValid = 0;
    #pragma unroll
    for (int L = 0; L < NLVL; ++L) totalValid += nv[L];
    __syncthreads();

    // ---- Phase 2: merge-rank each element, scatter into ord ----
    int invBase = totalValid;
    #pragma unroll
    for (int L = 0; L < NLVL; ++L) {
        const int kL = c_k[L];
        if (tid < kL) {
            const int slot = c_base[L] + tid;
            if (myvalid[L]) {
                const uint32_t x = mykey[L];
                int pos = myvpre[L];
                #pragma unroll
                for (int Lp = 0; Lp < NLVL; ++Lp) {
                    if (Lp == L) continue;
                    pos += (Lp < L) ? bs_count_ge(&vkey[Lp * 1024], nv[Lp], x)
                                    : bs_count_gt(&vkey[Lp * 1024], nv[Lp], x);
                }
                const uint32_t kp = kept[(size_t)img * M_TOT + slot];
                ord[pos] = (uint32_t)slot | (kp << 31);
            } else {
                const int inv_idx = tid - myvpre[L];
                ord[invBase + inv_idx] = (uint32_t)slot;  // kept=0
            }
        }
        invBase += (c_k[L] - nv[L]);
    }
    __syncthreads();

    // ---- Phase 3: stable partition by kept flag, write output ----
    const int PT = 5;
    const int pos0 = tid * PT;
    int flags[PT];
    uint32_t slots[PT];
    int lsum = 0;
    #pragma unroll
    for (int q = 0; q < PT; ++q) {
        int pp = pos0 + q;
        int kf = 0; uint32_t sl = 0;
        if (pp < M_TOT) {
            uint32_t o = ord[pp];
            sl = o & 0x7FFFFFFFu;
            kf = (int)(o >> 31);
        }
        flags[q] = kf; slots[q] = sl; lsum += kf;
    }
    ssum[tid] = lsum;
    __syncthreads();
    for (int off = 1; off < 1024; off <<= 1) {
        int v = (tid >= off) ? ssum[tid - off] : 0;
        __syncthreads();
        ssum[tid] += v;
        __syncthreads();
    }
    const int excl = ssum[tid] - lsum;
    const int total = ssum[1023];

    int run = 0;
    #pragma unroll
    for (int q = 0; q < PT; ++q) {
        int pp = pos0 + q;
        if (pp >= M_TOT) break;
        int kf = flags[q];
        int kbefore = excl + run;
        run += kf;
        int oidx = kf ? kbefore : (total + (pp - kbefore));
        if (oidx < POST_K) {
            uint32_t sl = slots[q];
            const float4 b = *(const float4*)(cand_box + ((size_t)img * M_TOT + sl) * 4);
            float* ob = out + ((size_t)img * POST_K + oidx) * 4;
            ob[0] = b.x; ob[1] = b.y; ob[2] = b.z; ob[3] = b.w;
            out[NIMG * POST_K * 4 + (size_t)img * POST_K + oidx] =
                kf ? cand_score[(size_t)img * M_TOT + sl] : NEGV;
        }
    }
}

extern "C" void kernel_launch(void* const* d_in, const int* in_sizes, int n_in,
                              void* d_out, int out_size, void* d_ws, size_t ws_size,
                              hipStream_t stream) {
    Ptrs p;
    for (int l = 0; l < NLVL; ++l) {
        p.logits[l]  = (const float*)d_in[3 * l + 0];
        p.deltas[l]  = (const float*)d_in[3 * l + 1];
        p.anchors[l] = (const float*)d_in[3 * l + 2];
    }

    // workspace layout (~2.3 MB)
    char* w = (char*)d_ws;
    float* cand_box   = (float*)w;        w += (size_t)NIMG * M_TOT * 4 * sizeof(float);
    float* cand_score = (float*)w;        w += (size_t)NIMG * M_TOT * sizeof(float);
    uint32_t* kept        = (uint32_t*)w; w += (size_t)NIMG * M_TOT * sizeof(uint32_t);
    uint64_t* cand_pk     = (uint64_t*)w; w += (size_t)NGRP * CAP * sizeof(uint64_t);
    uint64_t* tri         = (uint64_t*)w; w += (size_t)NGRP * TRI_W * sizeof(uint64_t);
    uint64_t* diag        = (uint64_t*)w; w += (size_t)NGRP * 1024 * sizeof(uint64_t);
    uint32_t* cand_cnt    = (uint32_t*)w; w += (size_t)NGRP * CNT_STRIDE * sizeof(uint32_t);

    hipMemsetAsync(cand_cnt, 0, (size_t)NGRP * CNT_STRIDE * sizeof(uint32_t), stream);

    kCompactSpec<<<NIMG * BPI,       256, 0, stream>>>(p, cand_cnt, cand_pk);
    kFixup      <<<NGRP,             256, 0, stream>>>(p, cand_cnt, cand_pk);
    kRankDecode <<<NGRP * RD_SPLIT,  256, 0, stream>>>(p, cand_cnt, cand_pk, cand_box, cand_score);
    kIou        <<<NGRP * 16,        256, 0, stream>>>(cand_box, tri, diag);
    kScan       <<<NGRP,              64, 0, stream>>>(cand_score, tri, diag, kept);
    kMergeOut   <<<NIMG,            1024, 0, stream>>>(cand_box, cand_score, kept, (float*)d_out);
}

// Round 10
// 209.134 us; speedup vs baseline: 7.4185x; 1.0917x over previous
//
#include <hip/hip_runtime.h>
#include <stdint.h>
#include <math.h>

#define NLVL 5
#define NIMG 4
#define NGRP (NIMG * NLVL)
#define M_TOT 4768
#define POST_K 1000
#define NEGV  (-1e9f)
#define CAP 2048
#define BPI 65          // data-pass blocks per image
#define TRI_W 7680      // sum over q of 64q words, column-block-major
#define CNT_STRIDE 32   // cand_cnt counters spread one per 128B line
#define RD_SPLIT 8      // rank-decode sub-blocks per group

__constant__ int c_hwa[NLVL]  = {196608, 49152, 12288, 3072, 768};
__constant__ int c_k[NLVL]    = {1000, 1000, 1000, 1000, 768};
__constant__ int c_base[NLVL] = {0, 1000, 2000, 3000, 4000};
__constant__ int c_cnt[NLVL]  = {4096, 4096, 4096, 3072, 768};
// Speculative per-level key thresholds (flipf of score): expected candidate
// count ~1550 per group for N(0,1) logits; validated + repaired by kFixup.
__constant__ uint32_t c_T0[NLVL] = {0xC019999Au, 0xBFECCCCDu, 0xBF933333u, 0x80000000u, 0x00000000u};

struct Ptrs {
    const float* logits[NLVL];
    const float* deltas[NLVL];
    const float* anchors[NLVL];
};

__device__ __forceinline__ uint32_t flipf(float f) {
    uint32_t b = __float_as_uint(f);
    return (b & 0x80000000u) ? ~b : (b | 0x80000000u);
}
__device__ __forceinline__ float unflipf(uint32_t key) {
    uint32_t b = (key & 0x80000000u) ? (key & 0x7FFFFFFFu) : ~key;
    return __uint_as_float(b);
}

__device__ __forceinline__ void grp_decompose(int g, int& img, int& lvl, int& off, int& cnt) {
    img = g / BPI;
    int r = g % BPI;
    if (r < 48)      { lvl = 0; off = r * 4096; }
    else if (r < 60) { lvl = 1; off = (r - 48) * 4096; }
    else if (r < 63) { lvl = 2; off = (r - 60) * 4096; }
    else if (r < 64) { lvl = 3; off = 0; }
    else             { lvl = 4; off = 0; }
    cnt = c_cnt[lvl];
}

// wave64 OR-reduce via DPP (LLVM reduction sequence), result uniform.
__device__ __forceinline__ uint32_t wave_or32(uint32_t v) {
    v |= (uint32_t)__builtin_amdgcn_update_dpp(0, (int)v, 0x111, 0xf, 0xf, true); // row_shr:1
    v |= (uint32_t)__builtin_amdgcn_update_dpp(0, (int)v, 0x112, 0xf, 0xf, true); // row_shr:2
    v |= (uint32_t)__builtin_amdgcn_update_dpp(0, (int)v, 0x114, 0xf, 0xf, true); // row_shr:4
    v |= (uint32_t)__builtin_amdgcn_update_dpp(0, (int)v, 0x118, 0xf, 0xf, true); // row_shr:8
    v |= (uint32_t)__builtin_amdgcn_update_dpp(0, (int)v, 0x142, 0xf, 0xf, true); // row_bcast:15
    v |= (uint32_t)__builtin_amdgcn_update_dpp(0, (int)v, 0x143, 0xf, 0xf, true); // row_bcast:31
    return (uint32_t)__builtin_amdgcn_readlane((int)v, 63);
}

// ---------------------------------------------------------------------------
// Speculative single-pass compaction: keys >= c_T0[lvl] staged in LDS, one
// global atomic per block. Exactness guaranteed downstream by kRankDecode
// as long as count(>=T0) ∈ [k, CAP] — validated/repaired by kFixup.
// ---------------------------------------------------------------------------
__global__ void kCompactSpec(Ptrs p, uint32_t* __restrict__ cand_cnt,
                             uint64_t* __restrict__ cand_pk) {
    int img, lvl, off, cnt;
    grp_decompose(blockIdx.x, img, lvl, off, cnt);
    const int grp = img * NLVL + lvl;
    const int tid = threadIdx.x;
    const float* lg = p.logits[lvl] + (size_t)img * c_hwa[lvl] + off;
    const uint32_t T = c_T0[lvl];
    uint64_t* pk = cand_pk + (size_t)grp * CAP;

    __shared__ uint32_t scnt, sbase;
    __shared__ uint64_t sbuf[4096];
    if (tid == 0) scnt = 0u;
    __syncthreads();

    const int nvec = cnt >> 2;
    const float4* lg4 = (const float4*)lg;
    for (int v = tid; v < nvec; v += 256) {
        float4 x = lg4[v];
        float xs[4] = {x.x, x.y, x.z, x.w};
        #pragma unroll
        for (int c = 0; c < 4; ++c) {
            uint32_t key = flipf(xs[c]);
            if (key >= T) {
                uint32_t pos = atomicAdd(&scnt, 1u);
                uint32_t eidx = (uint32_t)(off + 4 * v + c);
                sbuf[pos] = ((uint64_t)key << 32) | (uint32_t)(~eidx);
            }
        }
    }
    __syncthreads();
    if (tid == 0) sbase = atomicAdd(&cand_cnt[grp * CNT_STRIDE], scnt);
    __syncthreads();
    const uint32_t n = scnt, b0 = sbase;
    for (uint32_t i = tid; i < n; i += 256) {
        uint32_t g = b0 + i;
        if (g < CAP) pk[g] = sbuf[i];
    }
}

// ---------------------------------------------------------------------------
// Fused fallback: one block per group. If speculation failed (count outside
// [k, CAP]), redo an exact 4-pass MSB radix select + recompaction within
// this block. Common path: one load + return.
// ---------------------------------------------------------------------------
__global__ void kFixup(Ptrs p, uint32_t* __restrict__ cand_cnt,
                       uint64_t* __restrict__ cand_pk) {
    const int grp = blockIdx.x;
    const int lvl = grp % NLVL;
    const int img = grp / NLVL;
    const int k = c_k[lvl];
    {
        uint32_t c = cand_cnt[grp * CNT_STRIDE];
        if (c >= (uint32_t)k && c <= CAP) return;   // speculation OK
    }
    const int n = c_hwa[lvl];
    const float* lg = p.logits[lvl] + (size_t)img * n;
    const int tid = threadIdx.x, bs = blockDim.x;

    __shared__ uint32_t hist[256];
    __shared__ uint32_t sh_pre, sh_rem;
    if (tid == 0) { sh_pre = 0u; sh_rem = (uint32_t)k; cand_cnt[grp * CNT_STRIDE] = 0u; }

    for (int pass = 0; pass < 4; ++pass) {
        for (int i = tid; i < 256; i += bs) hist[i] = 0u;
        __syncthreads();
        const int shift = 24 - 8 * pass;
        const uint32_t pre = sh_pre;
        for (int i = tid; i < n; i += bs) {
            uint32_t key = flipf(lg[i]);
            if (pass == 0 || (key >> (shift + 8)) == pre)
                atomicAdd(&hist[(key >> shift) & 255u], 1u);
        }
        __syncthreads();
        if (tid == 0) {
            uint32_t rem = sh_rem;
            int d = 255;
            for (; d > 0; --d) {
                uint32_t c = hist[d];
                if (rem <= c) break;
                rem -= c;
            }
            sh_rem = rem;
            sh_pre = (pre << 8) | (uint32_t)d;
        }
        __syncthreads();
    }
    const uint32_t T = sh_pre;
    uint64_t* pk = cand_pk + (size_t)grp * CAP;
    for (int i = tid; i < n; i += bs) {
        uint32_t key = flipf(lg[i]);
        if (key >= T) {
            uint32_t pos = atomicAdd(&cand_cnt[grp * CNT_STRIDE], 1u);
            if (pos < CAP) pk[pos] = ((uint64_t)key << 32) | (uint32_t)(~(uint32_t)i);
        }
    }
}

// ---------------------------------------------------------------------------
// Exact rank among candidates; decode boxes for rank < k. Bit-exact ref math.
// RD_SPLIT blocks per group: each block ranks a 256-candidate slice.
// ---------------------------------------------------------------------------
__global__ void kRankDecode(Ptrs p, const uint32_t* __restrict__ cand_cnt,
                            const uint64_t* __restrict__ cand_pk,
                            float* __restrict__ cand_box,
                            float* __restrict__ cand_score) {
    #pragma clang fp contract(off)
    const int blk = blockIdx.x;          // grp * RD_SPLIT + sub
    const int grp = blk / RD_SPLIT;
    const int sub = blk % RD_SPLIT;
    const int img = grp / NLVL;
    const int lvl = grp % NLVL;
    const int n    = c_hwa[lvl];
    const int k    = c_k[lvl];
    const int base = c_base[lvl];
    const int tid = threadIdx.x;

    const int cc = (int)min(cand_cnt[grp * CNT_STRIDE], (uint32_t)CAP);
    const int c0 = sub * (CAP / RD_SPLIT);
    if (c0 >= cc) return;

    __shared__ uint64_t K[CAP];
    const uint64_t* pk = cand_pk + (size_t)grp * CAP;
    for (int i = tid; i < cc; i += 256) K[i] = pk[i];
    __syncthreads();

    const int c = c0 + tid;
    const uint64_t myK = (c < cc) ? K[c] : ~0ull;
    int r = 0;
    int j = 0;
    for (; j + 8 <= cc; j += 8) {
        #pragma unroll
        for (int u = 0; u < 8; ++u) r += (int)(K[j + u] > myK);
    }
    for (; j < cc; ++j) r += (int)(K[j] > myK);

    if (c >= cc || r >= k) return;

    uint32_t key = (uint32_t)(myK >> 32);
    uint32_t ic  = ~(uint32_t)(myK & 0xFFFFFFFFu);
    const float* an = p.anchors[lvl] + (size_t)ic * 4;
    const float* dl = p.deltas[lvl] + ((size_t)img * n + ic) * 4;
    float a0 = an[0], a1 = an[1], a2 = an[2], a3 = an[3];
    float wa = a2 - a0, ha = a3 - a1;
    float cxa = a0 + 0.5f * wa, cya = a1 + 0.5f * ha;
    float dx = dl[0], dy = dl[1], dw = dl[2], dh = dl[3];
    const float SC = (float)4.135166556742356;  // log(1000/16)
    dw = fminf(dw, SC);
    dh = fminf(dh, SC);
    float cx = dx * wa + cxa, cy = dy * ha + cya;
    float w = wa * expf(dw), h = ha * expf(dh);
    float x1 = cx - 0.5f * w, y1 = cy - 0.5f * h;
    float x2 = cx + 0.5f * w, y2 = cy + 0.5f * h;
    x1 = fminf(fmaxf(x1, 0.0f), 1024.0f);
    y1 = fminf(fmaxf(y1, 0.0f), 1024.0f);
    x2 = fminf(fmaxf(x2, 0.0f), 1024.0f);
    y2 = fminf(fmaxf(y2, 0.0f), 1024.0f);
    float bw = x2 - x1, bh = y2 - y1;
    float score = (bw > 0.0f && bh > 0.0f) ? unflipf(key) : NEGV;
    const int slot = base + r;
    float* ob = cand_box + ((size_t)img * M_TOT + slot) * 4;
    ob[0] = x1; ob[1] = y1; ob[2] = x2; ob[3] = y2;
    cand_score[(size_t)img * M_TOT + slot] = score;
}

// ---------------------------------------------------------------------------
// NMS phase 1: suppression bit-matrix. COLUMN-BLOCK-MAJOR layout:
// for column block w, rows r < 64w stored at tri[32*w*(w-1) + r] (coalesced
// for the scan's gather); diagonal rows (r>>6 == w) go to diag[grp][r].
// ---------------------------------------------------------------------------
__global__ void kIou(const float* __restrict__ cand_box,
                     uint64_t* __restrict__ tri, uint64_t* __restrict__ diag) {
    #pragma clang fp contract(off)
    const int blk = blockIdx.x;      // grp*16 + w
    const int grp = blk >> 4;
    const int w   = blk & 15;
    const int img = grp / NLVL;
    const int lvl = grp % NLVL;
    const int k    = c_k[lvl];
    const int base = c_base[lvl];
    if (64 * w >= k) return;
    const int jn = min(64, k - 64 * w);
    const int R  = min(64 * (w + 1), k);
    const float lo = (float)lvl * 2048.0f;

    __shared__ float jx1[64], jy1[64], jx2[64], jy2[64], jar[64];
    const int tid = threadIdx.x;
    if (tid < jn) {
        const float4 b = *(const float4*)(cand_box + ((size_t)img * M_TOT + base + 64 * w + tid) * 4);
        float x1 = b.x + lo, y1 = b.y + lo, x2 = b.z + lo, y2 = b.w + lo;
        jx1[tid] = x1; jy1[tid] = y1; jx2[tid] = x2; jy2[tid] = y2;
        jar[tid] = (x2 - x1) * (y2 - y1);
    }
    __syncthreads();

    uint64_t* triq = tri + (size_t)grp * TRI_W + 32 * w * (w - 1);
    for (int r = tid; r < R; r += 256) {
        const float4 b = *(const float4*)(cand_box + ((size_t)img * M_TOT + base + r) * 4);
        float rx1 = b.x + lo, ry1 = b.y + lo, rx2 = b.z + lo, ry2 = b.w + lo;
        float ra = (rx2 - rx1) * (ry2 - ry1);
        uint64_t bits = 0ull;
        #pragma unroll 8
        for (int jj = 0; jj < jn; ++jj) {
            int j = 64 * w + jj;
            if (j > r) {
                float ltx = fmaxf(rx1, jx1[jj]);
                float lty = fmaxf(ry1, jy1[jj]);
                float rbx = fminf(rx2, jx2[jj]);
                float rby = fminf(ry2, jy2[jj]);
                float wx = fmaxf(rbx - ltx, 0.0f);
                float wy = fmaxf(rby - lty, 0.0f);
                float inter = wx * wy;
                float denom = ((ra + jar[jj]) - inter) + 1e-9f;
                if (inter / denom > 0.7f) bits |= (1ull << jj);
            }
        }
        if ((r >> 6) == w) diag[(size_t)grp * 1024 + r] = bits;
        else               triq[r] = bits;
    }
}

// ---------------------------------------------------------------------------
// NMS phase 2: greedy scan, ONE WAVE per group. Per 64-row block q:
// LATENCY-BATCHED gather — all <=15 column words loaded into a register
// array first (independent, one vmcnt wait), then masked OR; DPP OR-reduce;
// sparse scalar greedy over rows with nonzero diag only.
// ---------------------------------------------------------------------------
__global__ void kScan(const float* __restrict__ cand_score,
                      const uint64_t* __restrict__ tri,
                      const uint64_t* __restrict__ diag,
                      uint32_t* __restrict__ kept) {
    const int grp = blockIdx.x;
    const int img = grp / NLVL;
    const int lvl = grp % NLVL;
    const int k    = c_k[lvl];
    const int base = c_base[lvl];
    const int lane = threadIdx.x;   // 64 threads = 1 wave

    __shared__ uint64_t sdiag[1024];
    __shared__ uint64_t sinv[16];

    // preload diag rows + invalid ballots (coalesced, batched by unroll)
    const uint64_t* dg_g = diag + (size_t)grp * 1024;
    #pragma unroll
    for (int s = 0; s < 16; ++s) {
        const int r = 64 * s + lane;
        uint64_t d = (r < k) ? dg_g[r] : 0ull;
        sdiag[r] = d;
        float sc = (r < k) ? cand_score[(size_t)img * M_TOT + base + r] : NEGV;
        uint64_t iv = __ballot(sc <= -5e8f);
        if (lane == 0) sinv[s] = iv;
    }
    __syncthreads();

    const uint64_t* trig = tri + (size_t)grp * TRI_W;
    uint32_t mykept = 0u;   // bit s = row (64s + lane) kept
    const int nstage = (k + 63) >> 6;

    #pragma unroll 1
    for (int q = 0; q < nstage; ++q) {
        const uint64_t* tq = trig + 32 * q * (q - 1);
        // phase A: issue all gather loads (independent — stay in flight)
        uint64_t vals[15];
        #pragma unroll
        for (int s = 0; s < 15; ++s)
            if (s < q) vals[s] = tq[64 * s + lane];
        // phase B: masked OR (single wait before first use)
        uint64_t v = 0ull;
        #pragma unroll
        for (int s = 0; s < 15; ++s)
            if (s < q) {
                uint64_t msk = (uint64_t)0 - (uint64_t)((mykept >> s) & 1u);
                v |= vals[s] & msk;
            }
        const uint32_t vlo = wave_or32((uint32_t)v);
        const uint32_t vhi = wave_or32((uint32_t)(v >> 32));
        const uint64_t invq = sinv[q];
        const uint32_t ivlo = __builtin_amdgcn_readfirstlane((uint32_t)invq);
        const uint32_t ivhi = __builtin_amdgcn_readfirstlane((uint32_t)(invq >> 32));
        uint64_t rem = ~((((uint64_t)ivhi << 32) | (uint64_t)ivlo)
                       | (((uint64_t)vhi  << 32) | (uint64_t)vlo));

        const uint64_t darrq = sdiag[64 * q + lane];
        const uint32_t dlo = (uint32_t)darrq, dhi = (uint32_t)(darrq >> 32);
        const uint64_t nz = __ballot(darrq != 0ull);   // rows that can suppress

        uint64_t kw = 0ull;
        for (;;) {
            uint64_t t = rem & nz;
            if (t == 0ull) { kw |= rem; break; }       // rest can't suppress: all kept
            const int m = (int)__builtin_ctzll(t);
            const uint64_t bm = 1ull << m;
            const uint64_t lowm = bm - 1ull;
            kw |= (rem & lowm) | bm;                   // batch-keep below m, keep m
            const uint64_t dg =
                ((uint64_t)(uint32_t)__builtin_amdgcn_readlane((int)dhi, m) << 32)
              |  (uint64_t)(uint32_t)__builtin_amdgcn_readlane((int)dlo, m);
            rem &= ~(lowm | bm | dg);                  // drop processed + suppressed
        }
        mykept |= ((uint32_t)((kw >> lane) & 1ull)) << q;
    }

    #pragma unroll
    for (int s = 0; s < 16; ++s) {
        const int r = 64 * s + lane;
        if (r < k)
            kept[(size_t)img * M_TOT + base + r] = (mykept >> s) & 1u;
    }
}

// ---------------------------------------------------------------------------
// Merge-rank + stable partition + output, one block (1024 thr) per image.
// ---------------------------------------------------------------------------
__device__ __forceinline__ int bs_count_ge(const uint32_t* a, int n, uint32_t x) {
    int lo = 0, hi = n;
    while (lo < hi) { int mid = (lo + hi) >> 1; if (a[mid] >= x) lo = mid + 1; else hi = mid; }
    return lo;
}
__device__ __forceinline__ int bs_count_gt(const uint32_t* a, int n, uint32_t x) {
    int lo = 0, hi = n;
    while (lo < hi) { int mid = (lo + hi) >> 1; if (a[mid] > x) lo = mid + 1; else hi = mid; }
    return lo;
}

__global__ void kMergeOut(const float* __restrict__ cand_box,
                          const float* __restrict__ cand_score,
                          const uint32_t* __restrict__ kept,
                          float* __restrict__ out) {
    const int img = blockIdx.x;
    const int tid = threadIdx.x;   // 1024
    const int lane = tid & 63, wave = tid >> 6;

    __shared__ uint32_t vkey[NLVL * 1024];  // compacted valid keys, desc
    __shared__ uint32_t ord[M_TOT];         // merged order: slot | kept<<31
    __shared__ int ssum[1024];
    __shared__ uint32_t wsum[NLVL][16];

    // ---- Phase 1: per-level valid ballot-scan ----
    uint32_t mykey[NLVL];
    int myvalid[NLVL], mylower[NLVL];
    #pragma unroll
    for (int L = 0; L < NLVL; ++L) {
        const int kL = c_k[L];
        const bool act = tid < kL;
        float s = act ? cand_score[(size_t)img * M_TOT + c_base[L] + tid] : NEGV;
        bool valid = act && (s > -5e8f);
        uint64_t mask = __ballot(valid);
        mylower[L] = (int)__popcll(mask & ((1ull << lane) - 1ull));
        if (lane == 0) wsum[L][wave] = (uint32_t)__popcll(mask);
        mykey[L] = flipf(s);
        myvalid[L] = valid ? 1 : 0;
    }
    __syncthreads();

    int nv[NLVL], myvpre[NLVL];
    #pragma unroll
    for (int L = 0; L < NLVL; ++L) {
        int pw = 0, tot = 0;
        #pragma unroll
        for (int w = 0; w < 16; ++w) {
            if (w < wave) pw += (int)wsum[L][w];
            tot += (int)wsum[L][w];
        }
        nv[L] = tot;
        myvpre[L] = pw + mylower[L];
        if (tid < c_k[L] && myvalid[L])
            vkey[L * 1024 + myvpre[L]] = mykey[L];
    }
    int totalValid = 0;
    #pragma unroll
    for (int L = 0; L < NLVL; ++L) totalValid += nv[L];
    __syncthreads();

    // ---- Phase 2: merge-rank each element, scatter into ord ----
    int invBase = totalValid;
    #pragma unroll
    for (int L = 0; L < NLVL; ++L) {
        const int kL = c_k[L];
        if (tid < kL) {
            const int slot = c_base[L] + tid;
            if (myvalid[L]) {
                const uint32_t x = mykey[L];
                int pos = myvpre[L];
                #pragma unroll
                for (int Lp = 0; Lp < NLVL; ++Lp) {
                    if (Lp == L) continue;
                    pos += (Lp < L) ? bs_count_ge(&vkey[Lp * 1024], nv[Lp], x)
                                    : bs_count_gt(&vkey[Lp * 1024], nv[Lp], x);
                }
                const uint32_t kp = kept[(size_t)img * M_TOT + slot];
                ord[pos] = (uint32_t)slot | (kp << 31);
            } else {
                const int inv_idx = tid - myvpre[L];
                ord[invBase + inv_idx] = (uint32_t)slot;  // kept=0
            }
        }
        invBase += (c_k[L] - nv[L]);
    }
    __syncthreads();

    // ---- Phase 3: stable partition by kept flag, write output ----
    const int PT = 5;
    const int pos0 = tid * PT;
    int flags[PT];
    uint32_t slots[PT];
    int lsum = 0;
    #pragma unroll
    for (int q = 0; q < PT; ++q) {
        int pp = pos0 + q;
        int kf = 0; uint32_t sl = 0;
        if (pp < M_TOT) {
            uint32_t o = ord[pp];
            sl = o & 0x7FFFFFFFu;
            kf = (int)(o >> 31);
        }
        flags[q] = kf; slots[q] = sl; lsum += kf;
    }
    ssum[tid] = lsum;
    __syncthreads();
    for (int off = 1; off < 1024; off <<= 1) {
        int v = (tid >= off) ? ssum[tid - off] : 0;
        __syncthreads();
        ssum[tid] += v;
        __syncthreads();
    }
    const int excl = ssum[tid] - lsum;
    const int total = ssum[1023];

    int run = 0;
    #pragma unroll
    for (int q = 0; q < PT; ++q) {
        int pp = pos0 + q;
        if (pp >= M_TOT) break;
        int kf = flags[q];
        int kbefore = excl + run;
        run += kf;
        int oidx = kf ? kbefore : (total + (pp - kbefore));
        if (oidx < POST_K) {
            uint32_t sl = slots[q];
            const float4 b = *(const float4*)(cand_box + ((size_t)img * M_TOT + sl) * 4);
            float* ob = out + ((size_t)img * POST_K + oidx) * 4;
            ob[0] = b.x; ob[1] = b.y; ob[2] = b.z; ob[3] = b.w;
            out[NIMG * POST_K * 4 + (size_t)img * POST_K + oidx] =
                kf ? cand_score[(size_t)img * M_TOT + sl] : NEGV;
        }
    }
}

extern "C" void kernel_launch(void* const* d_in, const int* in_sizes, int n_in,
                              void* d_out, int out_size, void* d_ws, size_t ws_size,
                              hipStream_t stream) {
    Ptrs p;
    for (int l = 0; l < NLVL; ++l) {
        p.logits[l]  = (const float*)d_in[3 * l + 0];
        p.deltas[l]  = (const float*)d_in[3 * l + 1];
        p.anchors[l] = (const float*)d_in[3 * l + 2];
    }

    // workspace layout (~2.3 MB)
    char* w = (char*)d_ws;
    float* cand_box   = (float*)w;        w += (size_t)NIMG * M_TOT * 4 * sizeof(float);
    float* cand_score = (float*)w;        w += (size_t)NIMG * M_TOT * sizeof(float);
    uint32_t* kept        = (uint32_t*)w; w += (size_t)NIMG * M_TOT * sizeof(uint32_t);
    uint64_t* cand_pk     = (uint64_t*)w; w += (size_t)NGRP * CAP * sizeof(uint64_t);
    uint64_t* tri         = (uint64_t*)w; w += (size_t)NGRP * TRI_W * sizeof(uint64_t);
    uint64_t* diag        = (uint64_t*)w; w += (size_t)NGRP * 1024 * sizeof(uint64_t);
    uint32_t* cand_cnt    = (uint32_t*)w; w += (size_t)NGRP * CNT_STRIDE * sizeof(uint32_t);

    hipMemsetAsync(cand_cnt, 0, (size_t)NGRP * CNT_STRIDE * sizeof(uint32_t), stream);

    kCompactSpec<<<NIMG * BPI,       256, 0, stream>>>(p, cand_cnt, cand_pk);
    kFixup      <<<NGRP,             256, 0, stream>>>(p, cand_cnt, cand_pk);
    kRankDecode <<<NGRP * RD_SPLIT,  256, 0, stream>>>(p, cand_cnt, cand_pk, cand_box, cand_score);
    kIou        <<<NGRP * 16,        256, 0, stream>>>(cand_box, tri, diag);
    kScan       <<<NGRP,              64, 0, stream>>>(cand_score, tri, diag, kept);
    kMergeOut   <<<NIMG,            1024, 0, stream>>>(cand_box, cand_score, kept, (float*)d_out);
}

// Round 11
// 203.326 us; speedup vs baseline: 7.6305x; 1.0286x over previous
//
#include <hip/hip_runtime.h>
#include <stdint.h>
#include <math.h>

#define NLVL 5
#define NIMG 4
#define NGRP (NIMG * NLVL)
#define M_TOT 4768
#define POST_K 1000
#define NEGV  (-1e9f)
#define CAP 2048
#define BPI 65          // data-pass blocks per image
#define TRI_W 7680      // sum over q of 64q words, column-block-major
#define CNT_STRIDE 32   // cand_cnt counters spread one per 128B line
#define RD_SPLIT 8      // rank-decode sub-blocks per group

__constant__ int c_hwa[NLVL]  = {196608, 49152, 12288, 3072, 768};
__constant__ int c_k[NLVL]    = {1000, 1000, 1000, 1000, 768};
__constant__ int c_base[NLVL] = {0, 1000, 2000, 3000, 4000};
__constant__ int c_cnt[NLVL]  = {4096, 4096, 4096, 3072, 768};
// Speculative per-level key thresholds (flipf of score): expected candidate
// count ~1550 per group for N(0,1) logits; validated + repaired by kFixup.
__constant__ uint32_t c_T0[NLVL] = {0xC019999Au, 0xBFECCCCDu, 0xBF933333u, 0x80000000u, 0x00000000u};

struct Ptrs {
    const float* logits[NLVL];
    const float* deltas[NLVL];
    const float* anchors[NLVL];
};

__device__ __forceinline__ uint32_t flipf(float f) {
    uint32_t b = __float_as_uint(f);
    return (b & 0x80000000u) ? ~b : (b | 0x80000000u);
}
__device__ __forceinline__ float unflipf(uint32_t key) {
    uint32_t b = (key & 0x80000000u) ? (key & 0x7FFFFFFFu) : ~key;
    return __uint_as_float(b);
}

__device__ __forceinline__ void grp_decompose(int g, int& img, int& lvl, int& off, int& cnt) {
    img = g / BPI;
    int r = g % BPI;
    if (r < 48)      { lvl = 0; off = r * 4096; }
    else if (r < 60) { lvl = 1; off = (r - 48) * 4096; }
    else if (r < 63) { lvl = 2; off = (r - 60) * 4096; }
    else if (r < 64) { lvl = 3; off = 0; }
    else             { lvl = 4; off = 0; }
    cnt = c_cnt[lvl];
}

// wave64 OR-reduce via DPP (LLVM reduction sequence), result uniform.
__device__ __forceinline__ uint32_t wave_or32(uint32_t v) {
    v |= (uint32_t)__builtin_amdgcn_update_dpp(0, (int)v, 0x111, 0xf, 0xf, true); // row_shr:1
    v |= (uint32_t)__builtin_amdgcn_update_dpp(0, (int)v, 0x112, 0xf, 0xf, true); // row_shr:2
    v |= (uint32_t)__builtin_amdgcn_update_dpp(0, (int)v, 0x114, 0xf, 0xf, true); // row_shr:4
    v |= (uint32_t)__builtin_amdgcn_update_dpp(0, (int)v, 0x118, 0xf, 0xf, true); // row_shr:8
    v |= (uint32_t)__builtin_amdgcn_update_dpp(0, (int)v, 0x142, 0xf, 0xf, true); // row_bcast:15
    v |= (uint32_t)__builtin_amdgcn_update_dpp(0, (int)v, 0x143, 0xf, 0xf, true); // row_bcast:31
    return (uint32_t)__builtin_amdgcn_readlane((int)v, 63);
}

// ---------------------------------------------------------------------------
// Speculative single-pass compaction: keys >= c_T0[lvl] staged in LDS, one
// global atomic per block. Exactness guaranteed downstream by kRankDecode
// as long as count(>=T0) ∈ [k, CAP] — validated/repaired by kFixup.
// ---------------------------------------------------------------------------
__global__ void kCompactSpec(Ptrs p, uint32_t* __restrict__ cand_cnt,
                             uint64_t* __restrict__ cand_pk) {
    int img, lvl, off, cnt;
    grp_decompose(blockIdx.x, img, lvl, off, cnt);
    const int grp = img * NLVL + lvl;
    const int tid = threadIdx.x;
    const float* lg = p.logits[lvl] + (size_t)img * c_hwa[lvl] + off;
    const uint32_t T = c_T0[lvl];
    uint64_t* pk = cand_pk + (size_t)grp * CAP;

    __shared__ uint32_t scnt, sbase;
    __shared__ uint64_t sbuf[4096];
    if (tid == 0) scnt = 0u;
    __syncthreads();

    const int nvec = cnt >> 2;
    const float4* lg4 = (const float4*)lg;
    for (int v = tid; v < nvec; v += 256) {
        float4 x = lg4[v];
        float xs[4] = {x.x, x.y, x.z, x.w};
        #pragma unroll
        for (int c = 0; c < 4; ++c) {
            uint32_t key = flipf(xs[c]);
            if (key >= T) {
                uint32_t pos = atomicAdd(&scnt, 1u);
                uint32_t eidx = (uint32_t)(off + 4 * v + c);
                sbuf[pos] = ((uint64_t)key << 32) | (uint32_t)(~eidx);
            }
        }
    }
    __syncthreads();
    if (tid == 0) sbase = atomicAdd(&cand_cnt[grp * CNT_STRIDE], scnt);
    __syncthreads();
    const uint32_t n = scnt, b0 = sbase;
    for (uint32_t i = tid; i < n; i += 256) {
        uint32_t g = b0 + i;
        if (g < CAP) pk[g] = sbuf[i];
    }
}

// ---------------------------------------------------------------------------
// Fused fallback: one block per group. If speculation failed (count outside
// [k, CAP]), redo an exact 4-pass MSB radix select + recompaction within
// this block. Common path: one load + return.
// ---------------------------------------------------------------------------
__global__ void kFixup(Ptrs p, uint32_t* __restrict__ cand_cnt,
                       uint64_t* __restrict__ cand_pk) {
    const int grp = blockIdx.x;
    const int lvl = grp % NLVL;
    const int img = grp / NLVL;
    const int k = c_k[lvl];
    {
        uint32_t c = cand_cnt[grp * CNT_STRIDE];
        if (c >= (uint32_t)k && c <= CAP) return;   // speculation OK
    }
    const int n = c_hwa[lvl];
    const float* lg = p.logits[lvl] + (size_t)img * n;
    const int tid = threadIdx.x, bs = blockDim.x;

    __shared__ uint32_t hist[256];
    __shared__ uint32_t sh_pre, sh_rem;
    if (tid == 0) { sh_pre = 0u; sh_rem = (uint32_t)k; cand_cnt[grp * CNT_STRIDE] = 0u; }

    for (int pass = 0; pass < 4; ++pass) {
        for (int i = tid; i < 256; i += bs) hist[i] = 0u;
        __syncthreads();
        const int shift = 24 - 8 * pass;
        const uint32_t pre = sh_pre;
        for (int i = tid; i < n; i += bs) {
            uint32_t key = flipf(lg[i]);
            if (pass == 0 || (key >> (shift + 8)) == pre)
                atomicAdd(&hist[(key >> shift) & 255u], 1u);
        }
        __syncthreads();
        if (tid == 0) {
            uint32_t rem = sh_rem;
            int d = 255;
            for (; d > 0; --d) {
                uint32_t c = hist[d];
                if (rem <= c) break;
                rem -= c;
            }
            sh_rem = rem;
            sh_pre = (pre << 8) | (uint32_t)d;
        }
        __syncthreads();
    }
    const uint32_t T = sh_pre;
    uint64_t* pk = cand_pk + (size_t)grp * CAP;
    for (int i = tid; i < n; i += bs) {
        uint32_t key = flipf(lg[i]);
        if (key >= T) {
            uint32_t pos = atomicAdd(&cand_cnt[grp * CNT_STRIDE], 1u);
            if (pos < CAP) pk[pos] = ((uint64_t)key << 32) | (uint32_t)(~(uint32_t)i);
        }
    }
}

// ---------------------------------------------------------------------------
// Exact rank among candidates; decode boxes for rank < k. Bit-exact ref math.
// RD_SPLIT blocks per group: each block ranks a 256-candidate slice.
// ---------------------------------------------------------------------------
__global__ void kRankDecode(Ptrs p, const uint32_t* __restrict__ cand_cnt,
                            const uint64_t* __restrict__ cand_pk,
                            float* __restrict__ cand_box,
                            float* __restrict__ cand_score) {
    #pragma clang fp contract(off)
    const int blk = blockIdx.x;          // grp * RD_SPLIT + sub
    const int grp = blk / RD_SPLIT;
    const int sub = blk % RD_SPLIT;
    const int img = grp / NLVL;
    const int lvl = grp % NLVL;
    const int n    = c_hwa[lvl];
    const int k    = c_k[lvl];
    const int base = c_base[lvl];
    const int tid = threadIdx.x;

    const int cc = (int)min(cand_cnt[grp * CNT_STRIDE], (uint32_t)CAP);
    const int c0 = sub * (CAP / RD_SPLIT);
    if (c0 >= cc) return;

    __shared__ uint64_t K[CAP];
    const uint64_t* pk = cand_pk + (size_t)grp * CAP;
    for (int i = tid; i < cc; i += 256) K[i] = pk[i];
    __syncthreads();

    const int c = c0 + tid;
    const uint64_t myK = (c < cc) ? K[c] : ~0ull;
    int r = 0;
    int j = 0;
    for (; j + 8 <= cc; j += 8) {
        #pragma unroll
        for (int u = 0; u < 8; ++u) r += (int)(K[j + u] > myK);
    }
    for (; j < cc; ++j) r += (int)(K[j] > myK);

    if (c >= cc || r >= k) return;

    uint32_t key = (uint32_t)(myK >> 32);
    uint32_t ic  = ~(uint32_t)(myK & 0xFFFFFFFFu);
    const float* an = p.anchors[lvl] + (size_t)ic * 4;
    const float* dl = p.deltas[lvl] + ((size_t)img * n + ic) * 4;
    float a0 = an[0], a1 = an[1], a2 = an[2], a3 = an[3];
    float wa = a2 - a0, ha = a3 - a1;
    float cxa = a0 + 0.5f * wa, cya = a1 + 0.5f * ha;
    float dx = dl[0], dy = dl[1], dw = dl[2], dh = dl[3];
    const float SC = (float)4.135166556742356;  // log(1000/16)
    dw = fminf(dw, SC);
    dh = fminf(dh, SC);
    float cx = dx * wa + cxa, cy = dy * ha + cya;
    float w = wa * expf(dw), h = ha * expf(dh);
    float x1 = cx - 0.5f * w, y1 = cy - 0.5f * h;
    float x2 = cx + 0.5f * w, y2 = cy + 0.5f * h;
    x1 = fminf(fmaxf(x1, 0.0f), 1024.0f);
    y1 = fminf(fmaxf(y1, 0.0f), 1024.0f);
    x2 = fminf(fmaxf(x2, 0.0f), 1024.0f);
    y2 = fminf(fmaxf(y2, 0.0f), 1024.0f);
    float bw = x2 - x1, bh = y2 - y1;
    float score = (bw > 0.0f && bh > 0.0f) ? unflipf(key) : NEGV;
    const int slot = base + r;
    float* ob = cand_box + ((size_t)img * M_TOT + slot) * 4;
    ob[0] = x1; ob[1] = y1; ob[2] = x2; ob[3] = y2;
    cand_score[(size_t)img * M_TOT + slot] = score;
}

// ---------------------------------------------------------------------------
// NMS phase 1: suppression bit-matrix. COLUMN-BLOCK-MAJOR layout:
// for column block w, rows r < 64w stored at tri[32*w*(w-1) + r] (coalesced
// for the scan's gather); diagonal rows (r>>6 == w) go to diag[grp][r].
// ---------------------------------------------------------------------------
__global__ void kIou(const float* __restrict__ cand_box,
                     uint64_t* __restrict__ tri, uint64_t* __restrict__ diag) {
    #pragma clang fp contract(off)
    const int blk = blockIdx.x;      // grp*16 + w
    const int grp = blk >> 4;
    const int w   = blk & 15;
    const int img = grp / NLVL;
    const int lvl = grp % NLVL;
    const int k    = c_k[lvl];
    const int base = c_base[lvl];
    if (64 * w >= k) return;
    const int jn = min(64, k - 64 * w);
    const int R  = min(64 * (w + 1), k);
    const float lo = (float)lvl * 2048.0f;

    __shared__ float jx1[64], jy1[64], jx2[64], jy2[64], jar[64];
    const int tid = threadIdx.x;
    if (tid < jn) {
        const float4 b = *(const float4*)(cand_box + ((size_t)img * M_TOT + base + 64 * w + tid) * 4);
        float x1 = b.x + lo, y1 = b.y + lo, x2 = b.z + lo, y2 = b.w + lo;
        jx1[tid] = x1; jy1[tid] = y1; jx2[tid] = x2; jy2[tid] = y2;
        jar[tid] = (x2 - x1) * (y2 - y1);
    }
    __syncthreads();

    uint64_t* triq = tri + (size_t)grp * TRI_W + 32 * w * (w - 1);
    for (int r = tid; r < R; r += 256) {
        const float4 b = *(const float4*)(cand_box + ((size_t)img * M_TOT + base + r) * 4);
        float rx1 = b.x + lo, ry1 = b.y + lo, rx2 = b.z + lo, ry2 = b.w + lo;
        float ra = (rx2 - rx1) * (ry2 - ry1);
        uint64_t bits = 0ull;
        #pragma unroll 8
        for (int jj = 0; jj < jn; ++jj) {
            int j = 64 * w + jj;
            if (j > r) {
                float ltx = fmaxf(rx1, jx1[jj]);
                float lty = fmaxf(ry1, jy1[jj]);
                float rbx = fminf(rx2, jx2[jj]);
                float rby = fminf(ry2, jy2[jj]);
                float wx = fmaxf(rbx - ltx, 0.0f);
                float wy = fmaxf(rby - lty, 0.0f);
                float inter = wx * wy;
                float denom = ((ra + jar[jj]) - inter) + 1e-9f;
                if (inter / denom > 0.7f) bits |= (1ull << jj);
            }
        }
        if ((r >> 6) == w) diag[(size_t)grp * 1024 + r] = bits;
        else               triq[r] = bits;
    }
}

// ---------------------------------------------------------------------------
// NMS phase 2: greedy scan, ONE WAVE per group. Per 64-row block q:
// LATENCY-BATCHED gather — all <=15 column words loaded into a register
// array first (independent, one vmcnt wait), then masked OR; DPP OR-reduce;
// sparse scalar greedy over rows with nonzero diag only.
// ---------------------------------------------------------------------------
__global__ void kScan(const float* __restrict__ cand_score,
                      const uint64_t* __restrict__ tri,
                      const uint64_t* __restrict__ diag,
                      uint32_t* __restrict__ kept) {
    const int grp = blockIdx.x;
    const int img = grp / NLVL;
    const int lvl = grp % NLVL;
    const int k    = c_k[lvl];
    const int base = c_base[lvl];
    const int lane = threadIdx.x;   // 64 threads = 1 wave

    __shared__ uint64_t sdiag[1024];
    __shared__ uint64_t sinv[16];

    // preload diag rows + invalid ballots (coalesced, batched by unroll)
    const uint64_t* dg_g = diag + (size_t)grp * 1024;
    #pragma unroll
    for (int s = 0; s < 16; ++s) {
        const int r = 64 * s + lane;
        uint64_t d = (r < k) ? dg_g[r] : 0ull;
        sdiag[r] = d;
        float sc = (r < k) ? cand_score[(size_t)img * M_TOT + base + r] : NEGV;
        uint64_t iv = __ballot(sc <= -5e8f);
        if (lane == 0) sinv[s] = iv;
    }
    __syncthreads();

    const uint64_t* trig = tri + (size_t)grp * TRI_W;
    uint32_t mykept = 0u;   // bit s = row (64s + lane) kept
    const int nstage = (k + 63) >> 6;

    #pragma unroll 1
    for (int q = 0; q < nstage; ++q) {
        const uint64_t* tq = trig + 32 * q * (q - 1);
        // phase A: issue all gather loads (independent — stay in flight)
        uint64_t vals[15];
        #pragma unroll
        for (int s = 0; s < 15; ++s)
            if (s < q) vals[s] = tq[64 * s + lane];
        // phase B: masked OR (single wait before first use)
        uint64_t v = 0ull;
        #pragma unroll
        for (int s = 0; s < 15; ++s)
            if (s < q) {
                uint64_t msk = (uint64_t)0 - (uint64_t)((mykept >> s) & 1u);
                v |= vals[s] & msk;
            }
        const uint32_t vlo = wave_or32((uint32_t)v);
        const uint32_t vhi = wave_or32((uint32_t)(v >> 32));
        const uint64_t invq = sinv[q];
        const uint32_t ivlo = __builtin_amdgcn_readfirstlane((uint32_t)invq);
        const uint32_t ivhi = __builtin_amdgcn_readfirstlane((uint32_t)(invq >> 32));
        uint64_t rem = ~((((uint64_t)ivhi << 32) | (uint64_t)ivlo)
                       | (((uint64_t)vhi  << 32) | (uint64_t)vlo));

        const uint64_t darrq = sdiag[64 * q + lane];
        const uint32_t dlo = (uint32_t)darrq, dhi = (uint32_t)(darrq >> 32);
        const uint64_t nz = __ballot(darrq != 0ull);   // rows that can suppress

        uint64_t kw = 0ull;
        for (;;) {
            uint64_t t = rem & nz;
            if (t == 0ull) { kw |= rem; break; }       // rest can't suppress: all kept
            const int m = (int)__builtin_ctzll(t);
            const uint64_t bm = 1ull << m;
            const uint64_t lowm = bm - 1ull;
            kw |= (rem & lowm) | bm;                   // batch-keep below m, keep m
            const uint64_t dg =
                ((uint64_t)(uint32_t)__builtin_amdgcn_readlane((int)dhi, m) << 32)
              |  (uint64_t)(uint32_t)__builtin_amdgcn_readlane((int)dlo, m);
            rem &= ~(lowm | bm | dg);                  // drop processed + suppressed
        }
        mykept |= ((uint32_t)((kw >> lane) & 1ull)) << q;
    }

    #pragma unroll
    for (int s = 0; s < 16; ++s) {
        const int r = 64 * s + lane;
        if (r < k)
            kept[(size_t)img * M_TOT + base + r] = (mykept >> s) & 1u;
    }
}

// ---------------------------------------------------------------------------
// Merge-rank + stable partition + output, one block (1024 thr) per image.
// Phase 3 uses a wave-shuffle scan + single cross-wave LDS stage (1 barrier)
// instead of Hillis-Steele over 1024 threads (20 barriers).
// ---------------------------------------------------------------------------
__device__ __forceinline__ int bs_count_ge(const uint32_t* a, int n, uint32_t x) {
    int lo = 0, hi = n;
    while (lo < hi) { int mid = (lo + hi) >> 1; if (a[mid] >= x) lo = mid + 1; else hi = mid; }
    return lo;
}
__device__ __forceinline__ int bs_count_gt(const uint32_t* a, int n, uint32_t x) {
    int lo = 0, hi = n;
    while (lo < hi) { int mid = (lo + hi) >> 1; if (a[mid] > x) lo = mid + 1; else hi = mid; }
    return lo;
}

__global__ void kMergeOut(const float* __restrict__ cand_box,
                          const float* __restrict__ cand_score,
                          const uint32_t* __restrict__ kept,
                          float* __restrict__ out) {
    const int img = blockIdx.x;
    const int tid = threadIdx.x;   // 1024
    const int lane = tid & 63, wave = tid >> 6;

    __shared__ uint32_t vkey[NLVL * 1024];  // compacted valid keys, desc
    __shared__ uint32_t ord[M_TOT];         // merged order: slot | kept<<31
    __shared__ uint32_t wsum[NLVL][16];
    __shared__ int wtot[16];

    // ---- Phase 1: per-level valid ballot-scan ----
    uint32_t mykey[NLVL];
    int myvalid[NLVL], mylower[NLVL];
    #pragma unroll
    for (int L = 0; L < NLVL; ++L) {
        const int kL = c_k[L];
        const bool act = tid < kL;
        float s = act ? cand_score[(size_t)img * M_TOT + c_base[L] + tid] : NEGV;
        bool valid = act && (s > -5e8f);
        uint64_t mask = __ballot(valid);
        mylower[L] = (int)__popcll(mask & ((1ull << lane) - 1ull));
        if (lane == 0) wsum[L][wave] = (uint32_t)__popcll(mask);
        mykey[L] = flipf(s);
        myvalid[L] = valid ? 1 : 0;
    }
    __syncthreads();

    int nv[NLVL], myvpre[NLVL];
    #pragma unroll
    for (int L = 0; L < NLVL; ++L) {
        int pw = 0, tot = 0;
        #pragma unroll
        for (int w = 0; w < 16; ++w) {
            if (w < wave) pw += (int)wsum[L][w];
            tot += (int)wsum[L][w];
        }
        nv[L] = tot;
        myvpre[L] = pw + mylower[L];
        if (tid < c_k[L] && myvalid[L])
            vkey[L * 1024 + myvpre[L]] = mykey[L];
    }
    int totalValid = 0;
    #pragma unroll
    for (int L = 0; L < NLVL; ++L) totalValid += nv[L];
    __syncthreads();

    // ---- Phase 2: merge-rank each element, scatter into ord ----
    int invBase = totalValid;
    #pragma unroll
    for (int L = 0; L < NLVL; ++L) {
        const int kL = c_k[L];
        if (tid < kL) {
            const int slot = c_base[L] + tid;
            if (myvalid[L]) {
                const uint32_t x = mykey[L];
                int pos = myvpre[L];
                #pragma unroll
                for (int Lp = 0; Lp < NLVL; ++Lp) {
                    if (Lp == L) continue;
                    pos += (Lp < L) ? bs_count_ge(&vkey[Lp * 1024], nv[Lp], x)
                                    : bs_count_gt(&vkey[Lp * 1024], nv[Lp], x);
                }
                const uint32_t kp = kept[(size_t)img * M_TOT + slot];
                ord[pos] = (uint32_t)slot | (kp << 31);
            } else {
                const int inv_idx = tid - myvpre[L];
                ord[invBase + inv_idx] = (uint32_t)slot;  // kept=0
            }
        }
        invBase += (c_k[L] - nv[L]);
    }
    __syncthreads();

    // ---- Phase 3: stable partition by kept flag, write output ----
    const int PT = 5;
    const int pos0 = tid * PT;
    int flags[PT];
    uint32_t slots[PT];
    int lsum = 0;
    #pragma unroll
    for (int q = 0; q < PT; ++q) {
        int pp = pos0 + q;
        int kf = 0; uint32_t sl = 0;
        if (pp < M_TOT) {
            uint32_t o = ord[pp];
            sl = o & 0x7FFFFFFFu;
            kf = (int)(o >> 31);
        }
        flags[q] = kf; slots[q] = sl; lsum += kf;
    }
    // wave-level inclusive scan (shuffle, no barriers)
    int incl = lsum;
    #pragma unroll
    for (int off = 1; off < 64; off <<= 1) {
        int t = __shfl_up(incl, off, 64);
        if (lane >= off) incl += t;
    }
    if (lane == 63) wtot[wave] = incl;
    __syncthreads();
    int wpre = 0, total = 0;
    #pragma unroll
    for (int w = 0; w < 16; ++w) {
        int v = wtot[w];
        if (w < wave) wpre += v;
        total += v;
    }
    const int excl = wpre + (incl - lsum);

    int run = 0;
    #pragma unroll
    for (int q = 0; q < PT; ++q) {
        int pp = pos0 + q;
        if (pp >= M_TOT) break;
        int kf = flags[q];
        int kbefore = excl + run;
        run += kf;
        int oidx = kf ? kbefore : (total + (pp - kbefore));
        if (oidx < POST_K) {
            uint32_t sl = slots[q];
            const float4 b = *(const float4*)(cand_box + ((size_t)img * M_TOT + sl) * 4);
            float* ob = out + ((size_t)img * POST_K + oidx) * 4;
            ob[0] = b.x; ob[1] = b.y; ob[2] = b.z; ob[3] = b.w;
            out[NIMG * POST_K * 4 + (size_t)img * POST_K + oidx] =
                kf ? cand_score[(size_t)img * M_TOT + sl] : NEGV;
        }
    }
}

extern "C" void kernel_launch(void* const* d_in, const int* in_sizes, int n_in,
                              void* d_out, int out_size, void* d_ws, size_t ws_size,
                              hipStream_t stream) {
    Ptrs p;
    for (int l = 0; l < NLVL; ++l) {
        p.logits[l]  = (const float*)d_in[3 * l + 0];
        p.deltas[l]  = (const float*)d_in[3 * l + 1];
        p.anchors[l] = (const float*)d_in[3 * l + 2];
    }

    // workspace layout (~2.3 MB)
    char* w = (char*)d_ws;
    float* cand_box   = (float*)w;        w += (size_t)NIMG * M_TOT * 4 * sizeof(float);
    float* cand_score = (float*)w;        w += (size_t)NIMG * M_TOT * sizeof(float);
    uint32_t* kept        = (uint32_t*)w; w += (size_t)NIMG * M_TOT * sizeof(uint32_t);
    uint64_t* cand_pk     = (uint64_t*)w; w += (size_t)NGRP * CAP * sizeof(uint64_t);
    uint64_t* tri         = (uint64_t*)w; w += (size_t)NGRP * TRI_W * sizeof(uint64_t);
    uint64_t* diag        = (uint64_t*)w; w += (size_t)NGRP * 1024 * sizeof(uint64_t);
    uint32_t* cand_cnt    = (uint32_t*)w; w += (size_t)NGRP * CNT_STRIDE * sizeof(uint32_t);

    hipMemsetAsync(cand_cnt, 0, (size_t)NGRP * CNT_STRIDE * sizeof(uint32_t), stream);

    kCompactSpec<<<NIMG * BPI,       256, 0, stream>>>(p, cand_cnt, cand_pk);
    kFixup      <<<NGRP,             256, 0, stream>>>(p, cand_cnt, cand_pk);
    kRankDecode <<<NGRP * RD_SPLIT,  256, 0, stream>>>(p, cand_cnt, cand_pk, cand_box, cand_score);
    kIou        <<<NGRP * 16,        256, 0, stream>>>(cand_box, tri, diag);
    kScan       <<<NGRP,              64, 0, stream>>>(cand_score, tri, diag, kept);
    kMergeOut   <<<NIMG,            1024, 0, stream>>>(cand_box, cand_score, kept, (float*)d_out);
}

// Round 12
// 192.341 us; speedup vs baseline: 8.0662x; 1.0571x over previous
//
#include <hip/hip_runtime.h>
#include <stdint.h>
#include <math.h>

#define NLVL 5
#define NIMG 4
#define NGRP (NIMG * NLVL)
#define M_TOT 4768
#define POST_K 1000
#define NEGV  (-1e9f)
#define CAP 2048
#define BPI 65          // data-pass blocks per image
#define TRI_W 7680      // sum over q of 64q words, column-block-major
#define CNT_STRIDE 32   // cand_cnt counters spread one per 128B line
#define RD_SPLIT 8      // rank-decode sub-blocks per group

__constant__ int c_hwa[NLVL]  = {196608, 49152, 12288, 3072, 768};
__constant__ int c_k[NLVL]    = {1000, 1000, 1000, 1000, 768};
__constant__ int c_base[NLVL] = {0, 1000, 2000, 3000, 4000};
__constant__ int c_cnt[NLVL]  = {4096, 4096, 4096, 3072, 768};
// Speculative per-level key thresholds (flipf of score): expected candidate
// count ~1550 per group for N(0,1) logits; validated + repaired by kFixup.
__constant__ uint32_t c_T0[NLVL] = {0xC019999Au, 0xBFECCCCDu, 0xBF933333u, 0x80000000u, 0x00000000u};

struct Ptrs {
    const float* logits[NLVL];
    const float* deltas[NLVL];
    const float* anchors[NLVL];
};

__device__ __forceinline__ uint32_t flipf(float f) {
    uint32_t b = __float_as_uint(f);
    return (b & 0x80000000u) ? ~b : (b | 0x80000000u);
}
__device__ __forceinline__ float unflipf(uint32_t key) {
    uint32_t b = (key & 0x80000000u) ? (key & 0x7FFFFFFFu) : ~key;
    return __uint_as_float(b);
}
__device__ __forceinline__ float rdlane_f(float v, int l) {
    return __uint_as_float((uint32_t)__builtin_amdgcn_readlane((int)__float_as_uint(v), l));
}

__device__ __forceinline__ void grp_decompose(int g, int& img, int& lvl, int& off, int& cnt) {
    img = g / BPI;
    int r = g % BPI;
    if (r < 48)      { lvl = 0; off = r * 4096; }
    else if (r < 60) { lvl = 1; off = (r - 48) * 4096; }
    else if (r < 63) { lvl = 2; off = (r - 60) * 4096; }
    else if (r < 64) { lvl = 3; off = 0; }
    else             { lvl = 4; off = 0; }
    cnt = c_cnt[lvl];
}

// wave64 OR-reduce via DPP (LLVM reduction sequence), result uniform.
__device__ __forceinline__ uint32_t wave_or32(uint32_t v) {
    v |= (uint32_t)__builtin_amdgcn_update_dpp(0, (int)v, 0x111, 0xf, 0xf, true); // row_shr:1
    v |= (uint32_t)__builtin_amdgcn_update_dpp(0, (int)v, 0x112, 0xf, 0xf, true); // row_shr:2
    v |= (uint32_t)__builtin_amdgcn_update_dpp(0, (int)v, 0x114, 0xf, 0xf, true); // row_shr:4
    v |= (uint32_t)__builtin_amdgcn_update_dpp(0, (int)v, 0x118, 0xf, 0xf, true); // row_shr:8
    v |= (uint32_t)__builtin_amdgcn_update_dpp(0, (int)v, 0x142, 0xf, 0xf, true); // row_bcast:15
    v |= (uint32_t)__builtin_amdgcn_update_dpp(0, (int)v, 0x143, 0xf, 0xf, true); // row_bcast:31
    return (uint32_t)__builtin_amdgcn_readlane((int)v, 63);
}

// ---------------------------------------------------------------------------
// Speculative single-pass compaction: keys >= c_T0[lvl] staged in LDS, one
// global atomic per block. Exactness guaranteed downstream by kRankDecode
// as long as count(>=T0) ∈ [k, CAP] — validated/repaired by kFixup.
// ---------------------------------------------------------------------------
__global__ void kCompactSpec(Ptrs p, uint32_t* __restrict__ cand_cnt,
                             uint64_t* __restrict__ cand_pk) {
    int img, lvl, off, cnt;
    grp_decompose(blockIdx.x, img, lvl, off, cnt);
    const int grp = img * NLVL + lvl;
    const int tid = threadIdx.x;
    const float* lg = p.logits[lvl] + (size_t)img * c_hwa[lvl] + off;
    const uint32_t T = c_T0[lvl];
    uint64_t* pk = cand_pk + (size_t)grp * CAP;

    __shared__ uint32_t scnt, sbase;
    __shared__ uint64_t sbuf[4096];
    if (tid == 0) scnt = 0u;
    __syncthreads();

    const int nvec = cnt >> 2;
    const float4* lg4 = (const float4*)lg;
    for (int v = tid; v < nvec; v += 256) {
        float4 x = lg4[v];
        float xs[4] = {x.x, x.y, x.z, x.w};
        #pragma unroll
        for (int c = 0; c < 4; ++c) {
            uint32_t key = flipf(xs[c]);
            if (key >= T) {
                uint32_t pos = atomicAdd(&scnt, 1u);
                uint32_t eidx = (uint32_t)(off + 4 * v + c);
                sbuf[pos] = ((uint64_t)key << 32) | (uint32_t)(~eidx);
            }
        }
    }
    __syncthreads();
    if (tid == 0) sbase = atomicAdd(&cand_cnt[grp * CNT_STRIDE], scnt);
    __syncthreads();
    const uint32_t n = scnt, b0 = sbase;
    for (uint32_t i = tid; i < n; i += 256) {
        uint32_t g = b0 + i;
        if (g < CAP) pk[g] = sbuf[i];
    }
}

// ---------------------------------------------------------------------------
// Fused fallback: one block per group. If speculation failed (count outside
// [k, CAP]), redo an exact 4-pass MSB radix select + recompaction within
// this block. Common path: one load + return.
// ---------------------------------------------------------------------------
__global__ void kFixup(Ptrs p, uint32_t* __restrict__ cand_cnt,
                       uint64_t* __restrict__ cand_pk) {
    const int grp = blockIdx.x;
    const int lvl = grp % NLVL;
    const int img = grp / NLVL;
    const int k = c_k[lvl];
    {
        uint32_t c = cand_cnt[grp * CNT_STRIDE];
        if (c >= (uint32_t)k && c <= CAP) return;   // speculation OK
    }
    const int n = c_hwa[lvl];
    const float* lg = p.logits[lvl] + (size_t)img * n;
    const int tid = threadIdx.x, bs = blockDim.x;

    __shared__ uint32_t hist[256];
    __shared__ uint32_t sh_pre, sh_rem;
    if (tid == 0) { sh_pre = 0u; sh_rem = (uint32_t)k; cand_cnt[grp * CNT_STRIDE] = 0u; }

    for (int pass = 0; pass < 4; ++pass) {
        for (int i = tid; i < 256; i += bs) hist[i] = 0u;
        __syncthreads();
        const int shift = 24 - 8 * pass;
        const uint32_t pre = sh_pre;
        for (int i = tid; i < n; i += bs) {
            uint32_t key = flipf(lg[i]);
            if (pass == 0 || (key >> (shift + 8)) == pre)
                atomicAdd(&hist[(key >> shift) & 255u], 1u);
        }
        __syncthreads();
        if (tid == 0) {
            uint32_t rem = sh_rem;
            int d = 255;
            for (; d > 0; --d) {
                uint32_t c = hist[d];
                if (rem <= c) break;
                rem -= c;
            }
            sh_rem = rem;
            sh_pre = (pre << 8) | (uint32_t)d;
        }
        __syncthreads();
    }
    const uint32_t T = sh_pre;
    uint64_t* pk = cand_pk + (size_t)grp * CAP;
    for (int i = tid; i < n; i += bs) {
        uint32_t key = flipf(lg[i]);
        if (key >= T) {
            uint32_t pos = atomicAdd(&cand_cnt[grp * CNT_STRIDE], 1u);
            if (pos < CAP) pk[pos] = ((uint64_t)key << 32) | (uint32_t)(~(uint32_t)i);
        }
    }
}

// ---------------------------------------------------------------------------
// Exact rank among candidates; decode boxes for rank < k. Bit-exact ref math.
// RD_SPLIT blocks per group: each block ranks a 256-candidate slice.
// ---------------------------------------------------------------------------
__global__ void kRankDecode(Ptrs p, const uint32_t* __restrict__ cand_cnt,
                            const uint64_t* __restrict__ cand_pk,
                            float* __restrict__ cand_box,
                            float* __restrict__ cand_score) {
    #pragma clang fp contract(off)
    const int blk = blockIdx.x;          // grp * RD_SPLIT + sub
    const int grp = blk / RD_SPLIT;
    const int sub = blk % RD_SPLIT;
    const int img = grp / NLVL;
    const int lvl = grp % NLVL;
    const int n    = c_hwa[lvl];
    const int k    = c_k[lvl];
    const int base = c_base[lvl];
    const int tid = threadIdx.x;

    const int cc = (int)min(cand_cnt[grp * CNT_STRIDE], (uint32_t)CAP);
    const int c0 = sub * (CAP / RD_SPLIT);
    if (c0 >= cc) return;

    __shared__ uint64_t K[CAP];
    const uint64_t* pk = cand_pk + (size_t)grp * CAP;
    for (int i = tid; i < cc; i += 256) K[i] = pk[i];
    __syncthreads();

    const int c = c0 + tid;
    const uint64_t myK = (c < cc) ? K[c] : ~0ull;
    int r = 0;
    int j = 0;
    for (; j + 8 <= cc; j += 8) {
        #pragma unroll
        for (int u = 0; u < 8; ++u) r += (int)(K[j + u] > myK);
    }
    for (; j < cc; ++j) r += (int)(K[j] > myK);

    if (c >= cc || r >= k) return;

    uint32_t key = (uint32_t)(myK >> 32);
    uint32_t ic  = ~(uint32_t)(myK & 0xFFFFFFFFu);
    const float* an = p.anchors[lvl] + (size_t)ic * 4;
    const float* dl = p.deltas[lvl] + ((size_t)img * n + ic) * 4;
    float a0 = an[0], a1 = an[1], a2 = an[2], a3 = an[3];
    float wa = a2 - a0, ha = a3 - a1;
    float cxa = a0 + 0.5f * wa, cya = a1 + 0.5f * ha;
    float dx = dl[0], dy = dl[1], dw = dl[2], dh = dl[3];
    const float SC = (float)4.135166556742356;  // log(1000/16)
    dw = fminf(dw, SC);
    dh = fminf(dh, SC);
    float cx = dx * wa + cxa, cy = dy * ha + cya;
    float w = wa * expf(dw), h = ha * expf(dh);
    float x1 = cx - 0.5f * w, y1 = cy - 0.5f * h;
    float x2 = cx + 0.5f * w, y2 = cy + 0.5f * h;
    x1 = fminf(fmaxf(x1, 0.0f), 1024.0f);
    y1 = fminf(fmaxf(y1, 0.0f), 1024.0f);
    x2 = fminf(fmaxf(x2, 0.0f), 1024.0f);
    y2 = fminf(fmaxf(y2, 0.0f), 1024.0f);
    float bw = x2 - x1, bh = y2 - y1;
    float score = (bw > 0.0f && bh > 0.0f) ? unflipf(key) : NEGV;
    const int slot = base + r;
    float* ob = cand_box + ((size_t)img * M_TOT + slot) * 4;
    ob[0] = x1; ob[1] = y1; ob[2] = x2; ob[3] = y2;
    cand_score[(size_t)img * M_TOT + slot] = score;
}

// ---------------------------------------------------------------------------
// NMS phase 1: suppression bit-matrix, COLUMN-BLOCK-MAJOR. Grid is
// (grp, w, chunk-of-256-rows) so every block does <=1 row-iteration/thread
// (4x shorter critical path, ~5 blocks/CU occupancy). The 64 j-boxes live in
// each wave's lanes (5 VGPRs); per-jj operands come from v_readlane SGPR
// broadcasts — the inner loop is pure VALU, no LDS, no memory waits.
// ---------------------------------------------------------------------------
__global__ void kIou(const float* __restrict__ cand_box,
                     uint64_t* __restrict__ tri, uint64_t* __restrict__ diag) {
    #pragma clang fp contract(off)
    const int blk = blockIdx.x;      // grp*64 + w*4 + c
    const int grp = blk >> 6;
    const int w   = (blk >> 2) & 15;
    const int ch  = blk & 3;
    const int img = grp / NLVL;
    const int lvl = grp % NLVL;
    const int k    = c_k[lvl];
    const int base = c_base[lvl];
    if (64 * w >= k) return;
    const int R  = min(64 * (w + 1), k);
    const int r0 = ch * 256;
    if (r0 >= R) return;
    const int jn = min(64, k - 64 * w);
    const float lo = (float)lvl * 2048.0f;
    const int tid = threadIdx.x;
    const int lane = tid & 63;

    // each wave's lane L holds j-box L (clamped load; unused lanes harmless)
    const int jl = (lane < jn) ? lane : 0;
    const float4 jb = *(const float4*)(cand_box + ((size_t)img * M_TOT + base + 64 * w + jl) * 4);
    const float jx1r = jb.x + lo, jy1r = jb.y + lo;
    const float jx2r = jb.z + lo, jy2r = jb.w + lo;
    const float jarr = (jx2r - jx1r) * (jy2r - jy1r);

    const int r = r0 + tid;
    const bool act = r < R;
    float rx1 = 0, ry1 = 0, rx2 = 0, ry2 = 0, ra = 0;
    if (act) {
        const float4 b = *(const float4*)(cand_box + ((size_t)img * M_TOT + base + r) * 4);
        rx1 = b.x + lo; ry1 = b.y + lo; rx2 = b.z + lo; ry2 = b.w + lo;
        ra = (rx2 - rx1) * (ry2 - ry1);
    }

    uint64_t bits = 0ull;
    #pragma unroll 4
    for (int jj = 0; jj < jn; ++jj) {
        const float bx1 = rdlane_f(jx1r, jj);
        const float by1 = rdlane_f(jy1r, jj);
        const float bx2 = rdlane_f(jx2r, jj);
        const float by2 = rdlane_f(jy2r, jj);
        const float bar = rdlane_f(jarr, jj);
        const int j = 64 * w + jj;
        if (j > r) {
            float ltx = fmaxf(rx1, bx1);
            float lty = fmaxf(ry1, by1);
            float rbx = fminf(rx2, bx2);
            float rby = fminf(ry2, by2);
            float wx = fmaxf(rbx - ltx, 0.0f);
            float wy = fmaxf(rby - lty, 0.0f);
            float inter = wx * wy;
            float denom = ((ra + bar) - inter) + 1e-9f;
            if (inter / denom > 0.7f) bits |= (1ull << jj);
        }
    }

    if (act) {
        if ((r >> 6) == w) diag[(size_t)grp * 1024 + r] = bits;
        else               tri[(size_t)grp * TRI_W + 32 * w * (w - 1) + r] = bits;
    }
}

// ---------------------------------------------------------------------------
// NMS phase 2: greedy scan, ONE WAVE per group. Per 64-row block q:
// LATENCY-BATCHED gather — all <=15 column words loaded into a register
// array first (independent, one vmcnt wait), then masked OR; DPP OR-reduce;
// sparse scalar greedy over rows with nonzero diag only.
// ---------------------------------------------------------------------------
__global__ void kScan(const float* __restrict__ cand_score,
                      const uint64_t* __restrict__ tri,
                      const uint64_t* __restrict__ diag,
                      uint32_t* __restrict__ kept) {
    const int grp = blockIdx.x;
    const int img = grp / NLVL;
    const int lvl = grp % NLVL;
    const int k    = c_k[lvl];
    const int base = c_base[lvl];
    const int lane = threadIdx.x;   // 64 threads = 1 wave

    __shared__ uint64_t sdiag[1024];
    __shared__ uint64_t sinv[16];

    // preload diag rows + invalid ballots (coalesced, batched by unroll)
    const uint64_t* dg_g = diag + (size_t)grp * 1024;
    #pragma unroll
    for (int s = 0; s < 16; ++s) {
        const int r = 64 * s + lane;
        uint64_t d = (r < k) ? dg_g[r] : 0ull;
        sdiag[r] = d;
        float sc = (r < k) ? cand_score[(size_t)img * M_TOT + base + r] : NEGV;
        uint64_t iv = __ballot(sc <= -5e8f);
        if (lane == 0) sinv[s] = iv;
    }
    __syncthreads();

    const uint64_t* trig = tri + (size_t)grp * TRI_W;
    uint32_t mykept = 0u;   // bit s = row (64s + lane) kept
    const int nstage = (k + 63) >> 6;

    #pragma unroll 1
    for (int q = 0; q < nstage; ++q) {
        const uint64_t* tq = trig + 32 * q * (q - 1);
        // phase A: issue all gather loads (independent — stay in flight)
        uint64_t vals[15];
        #pragma unroll
        for (int s = 0; s < 15; ++s)
            if (s < q) vals[s] = tq[64 * s + lane];
        // phase B: masked OR (single wait before first use)
        uint64_t v = 0ull;
        #pragma unroll
        for (int s = 0; s < 15; ++s)
            if (s < q) {
                uint64_t msk = (uint64_t)0 - (uint64_t)((mykept >> s) & 1u);
                v |= vals[s] & msk;
            }
        const uint32_t vlo = wave_or32((uint32_t)v);
        const uint32_t vhi = wave_or32((uint32_t)(v >> 32));
        const uint64_t invq = sinv[q];
        const uint32_t ivlo = __builtin_amdgcn_readfirstlane((uint32_t)invq);
        const uint32_t ivhi = __builtin_amdgcn_readfirstlane((uint32_t)(invq >> 32));
        uint64_t rem = ~((((uint64_t)ivhi << 32) | (uint64_t)ivlo)
                       | (((uint64_t)vhi  << 32) | (uint64_t)vlo));

        const uint64_t darrq = sdiag[64 * q + lane];
        const uint32_t dlo = (uint32_t)darrq, dhi = (uint32_t)(darrq >> 32);
        const uint64_t nz = __ballot(darrq != 0ull);   // rows that can suppress

        uint64_t kw = 0ull;
        for (;;) {
            uint64_t t = rem & nz;
            if (t == 0ull) { kw |= rem; break; }       // rest can't suppress: all kept
            const int m = (int)__builtin_ctzll(t);
            const uint64_t bm = 1ull << m;
            const uint64_t lowm = bm - 1ull;
            kw |= (rem & lowm) | bm;                   // batch-keep below m, keep m
            const uint64_t dg =
                ((uint64_t)(uint32_t)__builtin_amdgcn_readlane((int)dhi, m) << 32)
              |  (uint64_t)(uint32_t)__builtin_amdgcn_readlane((int)dlo, m);
            rem &= ~(lowm | bm | dg);                  // drop processed + suppressed
        }
        mykept |= ((uint32_t)((kw >> lane) & 1ull)) << q;
    }

    #pragma unroll
    for (int s = 0; s < 16; ++s) {
        const int r = 64 * s + lane;
        if (r < k)
            kept[(size_t)img * M_TOT + base + r] = (mykept >> s) & 1u;
    }
}

// ---------------------------------------------------------------------------
// Merge-rank + stable partition + output, one block (1024 thr) per image.
// Phase 3 uses a wave-shuffle scan + single cross-wave LDS stage (1 barrier).
// ---------------------------------------------------------------------------
__device__ __forceinline__ int bs_count_ge(const uint32_t* a, int n, uint32_t x) {
    int lo = 0, hi = n;
    while (lo < hi) { int mid = (lo + hi) >> 1; if (a[mid] >= x) lo = mid + 1; else hi = mid; }
    return lo;
}
__device__ __forceinline__ int bs_count_gt(const uint32_t* a, int n, uint32_t x) {
    int lo = 0, hi = n;
    while (lo < hi) { int mid = (lo + hi) >> 1; if (a[mid] > x) lo = mid + 1; else hi = mid; }
    return lo;
}

__global__ void kMergeOut(const float* __restrict__ cand_box,
                          const float* __restrict__ cand_score,
                          const uint32_t* __restrict__ kept,
                          float* __restrict__ out) {
    const int img = blockIdx.x;
    const int tid = threadIdx.x;   // 1024
    const int lane = tid & 63, wave = tid >> 6;

    __shared__ uint32_t vkey[NLVL * 1024];  // compacted valid keys, desc
    __shared__ uint32_t ord[M_TOT];         // merged order: slot | kept<<31
    __shared__ uint32_t wsum[NLVL][16];
    __shared__ int wtot[16];

    // ---- Phase 1: per-level valid ballot-scan ----
    uint32_t mykey[NLVL];
    int myvalid[NLVL], mylower[NLVL];
    #pragma unroll
    for (int L = 0; L < NLVL; ++L) {
        const int kL = c_k[L];
        const bool act = tid < kL;
        float s = act ? cand_score[(size_t)img * M_TOT + c_base[L] + tid] : NEGV;
        bool valid = act && (s > -5e8f);
        uint64_t mask = __ballot(valid);
        mylower[L] = (int)__popcll(mask & ((1ull << lane) - 1ull));
        if (lane == 0) wsum[L][wave] = (uint32_t)__popcll(mask);
        mykey[L] = flipf(s);
        myvalid[L] = valid ? 1 : 0;
    }
    __syncthreads();

    int nv[NLVL], myvpre[NLVL];
    #pragma unroll
    for (int L = 0; L < NLVL; ++L) {
        int pw = 0, tot = 0;
        #pragma unroll
        for (int w = 0; w < 16; ++w) {
            if (w < wave) pw += (int)wsum[L][w];
            tot += (int)wsum[L][w];
        }
        nv[L] = tot;
        myvpre[L] = pw + mylower[L];
        if (tid < c_k[L] && myvalid[L])
            vkey[L * 1024 + myvpre[L]] = mykey[L];
    }
    int totalValid = 0;
    #pragma unroll
    for (int L = 0; L < NLVL; ++L) totalValid += nv[L];
    __syncthreads();

    // ---- Phase 2: merge-rank each element, scatter into ord ----
    int invBase = totalValid;
    #pragma unroll
    for (int L = 0; L < NLVL; ++L) {
        const int kL = c_k[L];
        if (tid < kL) {
            const int slot = c_base[L] + tid;
            if (myvalid[L]) {
                const uint32_t x = mykey[L];
                int pos = myvpre[L];
                #pragma unroll
                for (int Lp = 0; Lp < NLVL; ++Lp) {
                    if (Lp == L) continue;
                    pos += (Lp < L) ? bs_count_ge(&vkey[Lp * 1024], nv[Lp], x)
                                    : bs_count_gt(&vkey[Lp * 1024], nv[Lp], x);
                }
                const uint32_t kp = kept[(size_t)img * M_TOT + slot];
                ord[pos] = (uint32_t)slot | (kp << 31);
            } else {
                const int inv_idx = tid - myvpre[L];
                ord[invBase + inv_idx] = (uint32_t)slot;  // kept=0
            }
        }
        invBase += (c_k[L] - nv[L]);
    }
    __syncthreads();

    // ---- Phase 3: stable partition by kept flag, write output ----
    const int PT = 5;
    const int pos0 = tid * PT;
    int flags[PT];
    uint32_t slots[PT];
    int lsum = 0;
    #pragma unroll
    for (int q = 0; q < PT; ++q) {
        int pp = pos0 + q;
        int kf = 0; uint32_t sl = 0;
        if (pp < M_TOT) {
            uint32_t o = ord[pp];
            sl = o & 0x7FFFFFFFu;
            kf = (int)(o >> 31);
        }
        flags[q] = kf; slots[q] = sl; lsum += kf;
    }
    // wave-level inclusive scan (shuffle, no barriers)
    int incl = lsum;
    #pragma unroll
    for (int off = 1; off < 64; off <<= 1) {
        int t = __shfl_up(incl, off, 64);
        if (lane >= off) incl += t;
    }
    if (lane == 63) wtot[wave] = incl;
    __syncthreads();
    int wpre = 0, total = 0;
    #pragma unroll
    for (int w = 0; w < 16; ++w) {
        int v = wtot[w];
        if (w < wave) wpre += v;
        total += v;
    }
    const int excl = wpre + (incl - lsum);

    int run = 0;
    #pragma unroll
    for (int q = 0; q < PT; ++q) {
        int pp = pos0 + q;
        if (pp >= M_TOT) break;
        int kf = flags[q];
        int kbefore = excl + run;
        run += kf;
        int oidx = kf ? kbefore : (total + (pp - kbefore));
        if (oidx < POST_K) {
            uint32_t sl = slots[q];
            const float4 b = *(const float4*)(cand_box + ((size_t)img * M_TOT + sl) * 4);
            float* ob = out + ((size_t)img * POST_K + oidx) * 4;
            ob[0] = b.x; ob[1] = b.y; ob[2] = b.z; ob[3] = b.w;
            out[NIMG * POST_K * 4 + (size_t)img * POST_K + oidx] =
                kf ? cand_score[(size_t)img * M_TOT + sl] : NEGV;
        }
    }
}

extern "C" void kernel_launch(void* const* d_in, const int* in_sizes, int n_in,
                              void* d_out, int out_size, void* d_ws, size_t ws_size,
                              hipStream_t stream) {
    Ptrs p;
    for (int l = 0; l < NLVL; ++l) {
        p.logits[l]  = (const float*)d_in[3 * l + 0];
        p.deltas[l]  = (const float*)d_in[3 * l + 1];
        p.anchors[l] = (const float*)d_in[3 * l + 2];
    }

    // workspace layout (~2.3 MB)
    char* w = (char*)d_ws;
    float* cand_box   = (float*)w;        w += (size_t)NIMG * M_TOT * 4 * sizeof(float);
    float* cand_score = (float*)w;        w += (size_t)NIMG * M_TOT * sizeof(float);
    uint32_t* kept        = (uint32_t*)w; w += (size_t)NIMG * M_TOT * sizeof(uint32_t);
    uint64_t* cand_pk     = (uint64_t*)w; w += (size_t)NGRP * CAP * sizeof(uint64_t);
    uint64_t* tri         = (uint64_t*)w; w += (size_t)NGRP * TRI_W * sizeof(uint64_t);
    uint64_t* diag        = (uint64_t*)w; w += (size_t)NGRP * 1024 * sizeof(uint64_t);
    uint32_t* cand_cnt    = (uint32_t*)w; w += (size_t)NGRP * CNT_STRIDE * sizeof(uint32_t);

    hipMemsetAsync(cand_cnt, 0, (size_t)NGRP * CNT_STRIDE * sizeof(uint32_t), stream);

    kCompactSpec<<<NIMG * BPI,       256, 0, stream>>>(p, cand_cnt, cand_pk);
    kFixup      <<<NGRP,             256, 0, stream>>>(p, cand_cnt, cand_pk);
    kRankDecode <<<NGRP * RD_SPLIT,  256, 0, stream>>>(p, cand_cnt, cand_pk, cand_box, cand_score);
    kIou        <<<NGRP * 64,        256, 0, stream>>>(cand_box, tri, diag);
    kScan       <<<NGRP,              64, 0, stream>>>(cand_score, tri, diag, kept);
    kMergeOut   <<<NIMG,            1024, 0, stream>>>(cand_box, cand_score, kept, (float*)d_out);
}